// Round 1
// baseline (5057.203 us; speedup 1.0000x reference)
//
#include <hip/hip_runtime.h>
#include <math.h>

#define TQ 100
#define SS 4096
#define BB 32
#define EE 256
#define HH 8
#define FF 2048
#define DHH 32
#define LNEPS 1e-5f

#define BM 64
#define BN 64
#define BKT 16
#define APAD 4

// C[m][n] = act((sum_k A(m,k) * W[n*K+k] + bias[n]) * scale)
// GATHER=1: A row m -> offset ((m%SD)*Bdim + m/SD)*K  (seq-first [SD,Bdim,K] -> [Bdim,SD,K])
// A2 (optional) is added elementwise to A1 (same layout).
template<int GATHER>
__global__ __launch_bounds__(256)
void gemm_nt(const float* __restrict__ A1, const float* __restrict__ A2,
             const float* __restrict__ W, const float* __restrict__ bias,
             float* __restrict__ C, int M, int N, int K,
             int SD, int Bdim, float scale, int relu)
{
    __shared__ float As[BKT][BM + APAD];
    __shared__ float Bs[BKT][BN + APAD];
    const int tid = threadIdx.x;
    const int tx = tid & 15, ty = tid >> 4;
    const int m0 = blockIdx.y * BM, n0 = blockIdx.x * BN;
    const int lr = tid >> 2;          // 0..63: row within tile
    const int lc = (tid & 3) << 2;    // 0,4,8,12: k offset (float4)

    long long arow;
    {
        int m = m0 + lr;
        if (GATHER) {
            int b = m / SD, s = m - b * SD;
            arow = ((long long)s * Bdim + b) * (long long)K;
        } else {
            arow = (long long)m * K;
        }
    }
    const long long wrow = (long long)(n0 + lr) * K;

    float acc[4][4] = {};

    for (int k0 = 0; k0 < K; k0 += BKT) {
        float4 av = *(const float4*)(A1 + arow + k0 + lc);
        if (A2) {
            float4 a2 = *(const float4*)(A2 + arow + k0 + lc);
            av.x += a2.x; av.y += a2.y; av.z += a2.z; av.w += a2.w;
        }
        float4 wv = *(const float4*)(W + wrow + k0 + lc);
        __syncthreads();
        As[lc+0][lr] = av.x; As[lc+1][lr] = av.y; As[lc+2][lr] = av.z; As[lc+3][lr] = av.w;
        Bs[lc+0][lr] = wv.x; Bs[lc+1][lr] = wv.y; Bs[lc+2][lr] = wv.z; Bs[lc+3][lr] = wv.w;
        __syncthreads();
        #pragma unroll
        for (int kk = 0; kk < BKT; ++kk) {
            float a4[4], b4[4];
            #pragma unroll
            for (int i = 0; i < 4; ++i) a4[i] = As[kk][ty*4 + i];
            #pragma unroll
            for (int j = 0; j < 4; ++j) b4[j] = Bs[kk][tx*4 + j];
            #pragma unroll
            for (int i = 0; i < 4; ++i)
                #pragma unroll
                for (int j = 0; j < 4; ++j)
                    acc[i][j] += a4[i] * b4[j];
        }
    }

    #pragma unroll
    for (int i = 0; i < 4; ++i) {
        int m = m0 + ty*4 + i;
        float vv[4];
        #pragma unroll
        for (int j = 0; j < 4; ++j) {
            float v = (acc[i][j] + bias[n0 + tx*4 + j]) * scale;
            if (relu) v = fmaxf(v, 0.f);
            vv[j] = v;
        }
        *(float4*)(C + (long long)m * N + n0 + tx*4) = make_float4(vv[0], vv[1], vv[2], vv[3]);
    }
}

// One block per (b,h,t). Q,K,V laid out [B, rows, E] with head h at columns h*DH..
__global__ __launch_bounds__(256)
void attn_kernel(const float* __restrict__ Q, const float* __restrict__ K,
                 const float* __restrict__ V, const float* __restrict__ mask,
                 float* __restrict__ O, int Skv)
{
    __shared__ float sc[SS];
    __shared__ float qs[DHH];
    __shared__ float red[16];
    __shared__ float ored[8][DHH];
    const int tid = threadIdx.x;
    const int blk = blockIdx.x;
    const int t = blk % TQ;
    const int bh = blk / TQ;
    const int h = bh & (HH - 1);
    const int b = bh / HH;

    const long long qoff = ((long long)(b * TQ + t)) * EE + h * DHH;
    if (tid < DHH) qs[tid] = Q[qoff + tid];
    __syncthreads();

    const long long kvbase = (long long)b * Skv * EE + h * DHH;
    const float* mrow = mask ? (mask + ((long long)bh * TQ + t) * Skv) : nullptr;

    float lmax = -INFINITY;
    for (int s = tid; s < Skv; s += 256) {
        const float4* kp = (const float4*)(K + kvbase + (long long)s * EE);
        float a = 0.f;
        #pragma unroll
        for (int c = 0; c < 8; ++c) {
            float4 kv = kp[c];
            a += qs[c*4+0]*kv.x + qs[c*4+1]*kv.y + qs[c*4+2]*kv.z + qs[c*4+3]*kv.w;
        }
        if (mrow) a += mrow[s];
        sc[s] = a;
        lmax = fmaxf(lmax, a);
    }
    #pragma unroll
    for (int off = 32; off; off >>= 1) lmax = fmaxf(lmax, __shfl_down(lmax, off));
    if ((tid & 63) == 0) red[tid >> 6] = lmax;
    __syncthreads();
    const float rmax = fmaxf(fmaxf(red[0], red[1]), fmaxf(red[2], red[3]));

    float lsum = 0.f;
    for (int s = tid; s < Skv; s += 256) {
        float e = __expf(sc[s] - rmax);
        sc[s] = e;
        lsum += e;
    }
    #pragma unroll
    for (int off = 32; off; off >>= 1) lsum += __shfl_down(lsum, off);
    if ((tid & 63) == 0) red[8 + (tid >> 6)] = lsum;
    __syncthreads();
    const float rinv = 1.f / (red[8] + red[9] + red[10] + red[11]);

    const int d = tid & 31, g = tid >> 5;  // 8 groups x 32 dims
    float acc = 0.f;
    for (int s = g; s < Skv; s += 8)
        acc += sc[s] * V[kvbase + (long long)s * EE + d];
    ored[g][d] = acc;
    __syncthreads();
    if (g == 0) {
        float o = 0.f;
        #pragma unroll
        for (int gg = 0; gg < 8; ++gg) o += ored[gg][d];
        O[qoff + d] = o * rinv;
    }
}

// LayerNorm over E=256: out = LN(res + x) * gamma + beta.
// GATHER_RES: res is seq-first [T,B,E]. OUT_T: write output seq-first [T,B,E].
template<int GATHER_RES, int OUT_T>
__global__ __launch_bounds__(256)
void ln_kernel(const float* __restrict__ res, const float* __restrict__ x,
               const float* __restrict__ gam, const float* __restrict__ bet,
               float* __restrict__ out)
{
    __shared__ float r1[4], r2[4];
    const int m = blockIdx.x;
    const int k = threadIdx.x;
    const int b = m / TQ, t = m - b * TQ;
    const long long roff = GATHER_RES ? ((long long)(t * BB + b)) * EE : (long long)m * EE;
    float v = res[roff + k] + x[(long long)m * EE + k];
    float s = v;
    #pragma unroll
    for (int off = 32; off; off >>= 1) s += __shfl_down(s, off);
    if ((k & 63) == 0) r1[k >> 6] = s;
    __syncthreads();
    const float mu = (r1[0] + r1[1] + r1[2] + r1[3]) * (1.0f / EE);
    const float d = v - mu;
    float s2 = d * d;
    #pragma unroll
    for (int off = 32; off; off >>= 1) s2 += __shfl_down(s2, off);
    if ((k & 63) == 0) r2[k >> 6] = s2;
    __syncthreads();
    const float var = (r2[0] + r2[1] + r2[2] + r2[3]) * (1.0f / EE);
    const float o = d * rsqrtf(var + LNEPS) * gam[k] + bet[k];
    const long long ooff = OUT_T ? ((long long)(t * BB + b)) * EE : (long long)m * EE;
    out[ooff + k] = o;
}

// out[b,t,:] = a[b,t,:] + qp[t,b,:]   (a is [B,T,E] contiguous, qp is [T,B,E])
__global__ __launch_bounds__(256)
void add_qp_kernel(const float* __restrict__ a, const float* __restrict__ qp,
                   float* __restrict__ out)
{
    const int idx = blockIdx.x * 256 + threadIdx.x;
    const int m = idx >> 8;
    const int k = idx & 255;
    const int b = m / TQ, t = m - b * TQ;
    out[idx] = a[idx] + qp[((long long)(t * BB + b)) * EE + k];
}

extern "C" void kernel_launch(void* const* d_in, const int* in_sizes, int n_in,
                              void* d_out, int out_size, void* d_ws, size_t ws_size,
                              hipStream_t stream)
{
    const float* hs    = (const float*)d_in[0];
    const float* qp    = (const float*)d_in[1];
    const float* enc   = (const float*)d_in[2];
    const float* ep    = (const float*)d_in[3];
    const float* mask  = (const float*)d_in[4];
    const float* ca_wq = (const float*)d_in[5];  const float* ca_bq = (const float*)d_in[6];
    const float* ca_wk = (const float*)d_in[7];  const float* ca_bk = (const float*)d_in[8];
    const float* ca_wv = (const float*)d_in[9];  const float* ca_bv = (const float*)d_in[10];
    const float* ca_wo = (const float*)d_in[11]; const float* ca_bo = (const float*)d_in[12];
    const float* sa_wq = (const float*)d_in[13]; const float* sa_bq = (const float*)d_in[14];
    const float* sa_wk = (const float*)d_in[15]; const float* sa_bk = (const float*)d_in[16];
    const float* sa_wv = (const float*)d_in[17]; const float* sa_bv = (const float*)d_in[18];
    const float* sa_wo = (const float*)d_in[19]; const float* sa_bo = (const float*)d_in[20];
    const float* ln1_g = (const float*)d_in[21]; const float* ln1_b = (const float*)d_in[22];
    const float* ln2_g = (const float*)d_in[23]; const float* ln2_b = (const float*)d_in[24];
    const float* ln3_g = (const float*)d_in[25]; const float* ln3_b = (const float*)d_in[26];
    const float* fc1_w = (const float*)d_in[27]; const float* fc1_b = (const float*)d_in[28];
    const float* fc2_w = (const float*)d_in[29]; const float* fc2_b = (const float*)d_in[30];

    float* ws = (float*)d_ws;
    float* Kc    = ws; ws += (size_t)BB * SS * EE;   // 134 MB
    float* Vc    = ws; ws += (size_t)BB * SS * EE;   // 134 MB
    float* Qc    = ws; ws += (size_t)BB * TQ * EE;
    float* attO  = ws; ws += (size_t)BB * TQ * EE;
    float* xproj = ws; ws += (size_t)BB * TQ * EE;
    float* hs1   = ws; ws += (size_t)BB * TQ * EE;
    float* xqsa  = ws; ws += (size_t)BB * TQ * EE;
    float* Qs    = ws; ws += (size_t)BB * TQ * EE;
    float* Ks    = ws; ws += (size_t)BB * TQ * EE;
    float* Vs    = ws; ws += (size_t)BB * TQ * EE;
    float* attO2 = ws; ws += (size_t)BB * TQ * EE;
    float* xpro2 = ws; ws += (size_t)BB * TQ * EE;
    float* hs2   = ws; ws += (size_t)BB * TQ * EE;
    float* h1    = ws; ws += (size_t)BB * TQ * FF;   // 26 MB
    float* xffn  = ws; ws += (size_t)BB * TQ * EE;

    const float qscale = 0.17677669529663687f; // 32^-0.5
    dim3 blk(256);
    const int MQ = BB * TQ;   // 3200
    const int MK = BB * SS;   // 131072

    // ---- cross-attention ----
    gemm_nt<1><<<dim3(EE/BN, MQ/BM), blk, 0, stream>>>(hs,  qp,      ca_wq, ca_bq, Qc, MQ, EE, EE, TQ, BB, qscale, 0);
    gemm_nt<1><<<dim3(EE/BN, MK/BM), blk, 0, stream>>>(enc, ep,      ca_wk, ca_bk, Kc, MK, EE, EE, SS, BB, 1.f,    0);
    gemm_nt<1><<<dim3(EE/BN, MK/BM), blk, 0, stream>>>(enc, nullptr, ca_wv, ca_bv, Vc, MK, EE, EE, SS, BB, 1.f,    0);
    attn_kernel<<<dim3(BB*HH*TQ), blk, 0, stream>>>(Qc, Kc, Vc, mask, attO, SS);
    gemm_nt<0><<<dim3(EE/BN, MQ/BM), blk, 0, stream>>>(attO, nullptr, ca_wo, ca_bo, xproj, MQ, EE, EE, 1, BB, 1.f, 0);
    ln_kernel<1,0><<<dim3(MQ), blk, 0, stream>>>(hs, xproj, ln1_g, ln1_b, hs1);

    // ---- self-attention ----
    add_qp_kernel<<<dim3(MQ), blk, 0, stream>>>(hs1, qp, xqsa);
    gemm_nt<0><<<dim3(EE/BN, MQ/BM), blk, 0, stream>>>(xqsa, nullptr, sa_wq, sa_bq, Qs, MQ, EE, EE, 1, BB, qscale, 0);
    gemm_nt<0><<<dim3(EE/BN, MQ/BM), blk, 0, stream>>>(xqsa, nullptr, sa_wk, sa_bk, Ks, MQ, EE, EE, 1, BB, 1.f,    0);
    gemm_nt<0><<<dim3(EE/BN, MQ/BM), blk, 0, stream>>>(hs1,  nullptr, sa_wv, sa_bv, Vs, MQ, EE, EE, 1, BB, 1.f,    0);
    attn_kernel<<<dim3(BB*HH*TQ), blk, 0, stream>>>(Qs, Ks, Vs, nullptr, attO2, TQ);
    gemm_nt<0><<<dim3(EE/BN, MQ/BM), blk, 0, stream>>>(attO2, nullptr, sa_wo, sa_bo, xpro2, MQ, EE, EE, 1, BB, 1.f, 0);
    ln_kernel<0,0><<<dim3(MQ), blk, 0, stream>>>(hs1, xpro2, ln2_g, ln2_b, hs2);

    // ---- FFN ----
    gemm_nt<0><<<dim3(FF/BN, MQ/BM), blk, 0, stream>>>(hs2, nullptr, fc1_w, fc1_b, h1,   MQ, FF, EE, 1, BB, 1.f, 1);
    gemm_nt<0><<<dim3(EE/BN, MQ/BM), blk, 0, stream>>>(h1,  nullptr, fc2_w, fc2_b, xffn, MQ, EE, FF, 1, BB, 1.f, 0);
    ln_kernel<0,1><<<dim3(MQ), blk, 0, stream>>>(hs2, xffn, ln3_g, ln3_b, (float*)d_out);

    (void)in_sizes; (void)n_in; (void)out_size; (void)ws_size;
}

// Round 2
// 3312.898 us; speedup vs baseline: 1.5265x; 1.5265x over previous
//
#include <hip/hip_runtime.h>
#include <math.h>

#define TQ 100
#define SS 4096
#define BB 32
#define EE 256
#define HH 8
#define FF 2048
#define DHH 32
#define LNEPS 1e-5f

#define BM 64
#define BN 64
#define BKT 16
#define APAD 4

// C[m][n] = act((sum_k A(m,k) * W[n*K+k] + bias[n]) * scale)
// GATHER=1: A row m -> offset ((m%SD)*Bdim + m/SD)*K  (seq-first [SD,Bdim,K] -> [Bdim,SD,K])
// A2 (optional) is added elementwise to A1 (same layout).
template<int GATHER>
__global__ __launch_bounds__(256)
void gemm_nt(const float* __restrict__ A1, const float* __restrict__ A2,
             const float* __restrict__ W, const float* __restrict__ bias,
             float* __restrict__ C, int M, int N, int K,
             int SD, int Bdim, float scale, int relu)
{
    __shared__ float As[BKT][BM + APAD];
    __shared__ float Bs[BKT][BN + APAD];
    const int tid = threadIdx.x;
    const int tx = tid & 15, ty = tid >> 4;
    const int m0 = blockIdx.y * BM, n0 = blockIdx.x * BN;
    const int lr = tid >> 2;          // 0..63: row within tile
    const int lc = (tid & 3) << 2;    // 0,4,8,12: k offset (float4)

    long long arow;
    {
        int m = m0 + lr;
        if (GATHER) {
            int b = m / SD, s = m - b * SD;
            arow = ((long long)s * Bdim + b) * (long long)K;
        } else {
            arow = (long long)m * K;
        }
    }
    const long long wrow = (long long)(n0 + lr) * K;

    float acc[4][4] = {};

    for (int k0 = 0; k0 < K; k0 += BKT) {
        float4 av = *(const float4*)(A1 + arow + k0 + lc);
        if (A2) {
            float4 a2 = *(const float4*)(A2 + arow + k0 + lc);
            av.x += a2.x; av.y += a2.y; av.z += a2.z; av.w += a2.w;
        }
        float4 wv = *(const float4*)(W + wrow + k0 + lc);
        __syncthreads();
        As[lc+0][lr] = av.x; As[lc+1][lr] = av.y; As[lc+2][lr] = av.z; As[lc+3][lr] = av.w;
        Bs[lc+0][lr] = wv.x; Bs[lc+1][lr] = wv.y; Bs[lc+2][lr] = wv.z; Bs[lc+3][lr] = wv.w;
        __syncthreads();
        #pragma unroll
        for (int kk = 0; kk < BKT; ++kk) {
            float a4[4], b4[4];
            #pragma unroll
            for (int i = 0; i < 4; ++i) a4[i] = As[kk][ty*4 + i];
            #pragma unroll
            for (int j = 0; j < 4; ++j) b4[j] = Bs[kk][tx*4 + j];
            #pragma unroll
            for (int i = 0; i < 4; ++i)
                #pragma unroll
                for (int j = 0; j < 4; ++j)
                    acc[i][j] += a4[i] * b4[j];
        }
    }

    #pragma unroll
    for (int i = 0; i < 4; ++i) {
        int m = m0 + ty*4 + i;
        float vv[4];
        #pragma unroll
        for (int j = 0; j < 4; ++j) {
            float v = (acc[i][j] + bias[n0 + tx*4 + j]) * scale;
            if (relu) v = fmaxf(v, 0.f);
            vv[j] = v;
        }
        *(float4*)(C + (long long)m * N + n0 + tx*4) = make_float4(vv[0], vv[1], vv[2], vv[3]);
    }
}

// Flash attention: block = (b,h, qtile of 16 queries), 256 threads.
// Each query row owned by a 16-lane group: si = tid&15 handles s = j*16+si.
// K/V staged in LDS in SB=128-row tiles, online softmax in registers.
#define SB 128

__global__ __launch_bounds__(256)
void flash_attn(const float* __restrict__ Q, const float* __restrict__ K,
                const float* __restrict__ V, const float* __restrict__ mask,
                float* __restrict__ O, int Skv, int qblocks)
{
    __shared__ float Ks[SB][36];   // +4 pad: float4-aligned rows, 2-way max bank alias
    __shared__ float Vs[SB][36];
    const int tid = threadIdx.x;
    const int qi = tid >> 4, si = tid & 15;
    const int qt = blockIdx.x % qblocks;
    const int bh = blockIdx.x / qblocks;
    const int h = bh & (HH - 1), b = bh >> 3;
    int t = qt * 16 + qi;
    const bool valid_q = (t < TQ);
    if (!valid_q) t = TQ - 1;

    const long long qoff = ((long long)(b * TQ + t)) * EE + h * DHH;
    float4 q4[8];
    #pragma unroll
    for (int c = 0; c < 8; ++c) q4[c] = *(const float4*)(Q + qoff + c * 4);

    const float* mrow = mask ? (mask + ((long long)bh * TQ + t) * Skv) : nullptr;
    const long long kvbase = (long long)b * Skv * EE + h * DHH;

    float4 o4[8] = {};
    float m = -1e30f, l = 0.f;

    const int ldr = tid >> 3;        // 0..31 (row per 8-thread group)
    const int ldc = (tid & 7) * 4;   // float4 col offset

    for (int s0 = 0; s0 < Skv; s0 += SB) {
        __syncthreads();
        #pragma unroll
        for (int pass = 0; pass < 4; ++pass) {
            int r = ldr + pass * 32;
            int s = s0 + r;
            long long off = kvbase + (long long)(s < Skv ? s : Skv - 1) * EE + ldc;
            *(float4*)(&Ks[r][ldc]) = *(const float4*)(K + off);
            *(float4*)(&Vs[r][ldc]) = *(const float4*)(V + off);
        }
        __syncthreads();

        float sc[8];
        float tmax = -1e30f;
        #pragma unroll
        for (int j = 0; j < 8; ++j) {
            int s = j * 16 + si;
            float a = 0.f;
            const float4* kr = (const float4*)(&Ks[s][0]);
            #pragma unroll
            for (int c = 0; c < 8; ++c) {
                float4 kv = kr[c];
                a += q4[c].x * kv.x; a += q4[c].y * kv.y;
                a += q4[c].z * kv.z; a += q4[c].w * kv.w;
            }
            if (s0 + s < Skv) {
                if (mrow) a += mrow[s0 + s];
            } else {
                a = -1e30f;
            }
            sc[j] = a;
            tmax = fmaxf(tmax, a);
        }
        #pragma unroll
        for (int off = 1; off < 16; off <<= 1)
            tmax = fmaxf(tmax, __shfl_xor(tmax, off, 16));
        const float mn = fmaxf(m, tmax);
        const float corr = __expf(m - mn);
        m = mn;
        l *= corr;
        #pragma unroll
        for (int c = 0; c < 8; ++c) {
            o4[c].x *= corr; o4[c].y *= corr; o4[c].z *= corr; o4[c].w *= corr;
        }
        #pragma unroll
        for (int j = 0; j < 8; ++j) {
            float p = __expf(sc[j] - mn);
            sc[j] = p;
            l += p;
        }
        #pragma unroll
        for (int j = 0; j < 8; ++j) {
            const float p = sc[j];
            const float4* vr = (const float4*)(&Vs[j * 16 + si][0]);
            #pragma unroll
            for (int c = 0; c < 8; ++c) {
                float4 vv = vr[c];
                o4[c].x += p * vv.x; o4[c].y += p * vv.y;
                o4[c].z += p * vv.z; o4[c].w += p * vv.w;
            }
        }
    }

    // reduce across the 16 threads of each query
    #pragma unroll
    for (int off = 1; off < 16; off <<= 1) {
        l += __shfl_xor(l, off, 16);
        #pragma unroll
        for (int c = 0; c < 8; ++c) {
            o4[c].x += __shfl_xor(o4[c].x, off, 16);
            o4[c].y += __shfl_xor(o4[c].y, off, 16);
            o4[c].z += __shfl_xor(o4[c].z, off, 16);
            o4[c].w += __shfl_xor(o4[c].w, off, 16);
        }
    }
    if (valid_q && si < 8) {
        const float linv = 1.f / l;
        float4 ov = o4[si];
        ov.x *= linv; ov.y *= linv; ov.z *= linv; ov.w *= linv;
        *(float4*)(O + qoff + si * 4) = ov;
    }
}

// LayerNorm over E=256: out = LN(res + x) * gamma + beta.
template<int GATHER_RES, int OUT_T>
__global__ __launch_bounds__(256)
void ln_kernel(const float* __restrict__ res, const float* __restrict__ x,
               const float* __restrict__ gam, const float* __restrict__ bet,
               float* __restrict__ out)
{
    __shared__ float r1[4], r2[4];
    const int m = blockIdx.x;
    const int k = threadIdx.x;
    const int b = m / TQ, t = m - b * TQ;
    const long long roff = GATHER_RES ? ((long long)(t * BB + b)) * EE : (long long)m * EE;
    float v = res[roff + k] + x[(long long)m * EE + k];
    float s = v;
    #pragma unroll
    for (int off = 32; off; off >>= 1) s += __shfl_down(s, off);
    if ((k & 63) == 0) r1[k >> 6] = s;
    __syncthreads();
    const float mu = (r1[0] + r1[1] + r1[2] + r1[3]) * (1.0f / EE);
    const float d = v - mu;
    float s2 = d * d;
    #pragma unroll
    for (int off = 32; off; off >>= 1) s2 += __shfl_down(s2, off);
    if ((k & 63) == 0) r2[k >> 6] = s2;
    __syncthreads();
    const float var = (r2[0] + r2[1] + r2[2] + r2[3]) * (1.0f / EE);
    const float o = d * rsqrtf(var + LNEPS) * gam[k] + bet[k];
    const long long ooff = OUT_T ? ((long long)(t * BB + b)) * EE : (long long)m * EE;
    out[ooff + k] = o;
}

__global__ __launch_bounds__(256)
void add_qp_kernel(const float* __restrict__ a, const float* __restrict__ qp,
                   float* __restrict__ out)
{
    const int idx = blockIdx.x * 256 + threadIdx.x;
    const int m = idx >> 8;
    const int k = idx & 255;
    const int b = m / TQ, t = m - b * TQ;
    out[idx] = a[idx] + qp[((long long)(t * BB + b)) * EE + k];
}

extern "C" void kernel_launch(void* const* d_in, const int* in_sizes, int n_in,
                              void* d_out, int out_size, void* d_ws, size_t ws_size,
                              hipStream_t stream)
{
    const float* hs    = (const float*)d_in[0];
    const float* qp    = (const float*)d_in[1];
    const float* enc   = (const float*)d_in[2];
    const float* ep    = (const float*)d_in[3];
    const float* mask  = (const float*)d_in[4];
    const float* ca_wq = (const float*)d_in[5];  const float* ca_bq = (const float*)d_in[6];
    const float* ca_wk = (const float*)d_in[7];  const float* ca_bk = (const float*)d_in[8];
    const float* ca_wv = (const float*)d_in[9];  const float* ca_bv = (const float*)d_in[10];
    const float* ca_wo = (const float*)d_in[11]; const float* ca_bo = (const float*)d_in[12];
    const float* sa_wq = (const float*)d_in[13]; const float* sa_bq = (const float*)d_in[14];
    const float* sa_wk = (const float*)d_in[15]; const float* sa_bk = (const float*)d_in[16];
    const float* sa_wv = (const float*)d_in[17]; const float* sa_bv = (const float*)d_in[18];
    const float* sa_wo = (const float*)d_in[19]; const float* sa_bo = (const float*)d_in[20];
    const float* ln1_g = (const float*)d_in[21]; const float* ln1_b = (const float*)d_in[22];
    const float* ln2_g = (const float*)d_in[23]; const float* ln2_b = (const float*)d_in[24];
    const float* ln3_g = (const float*)d_in[25]; const float* ln3_b = (const float*)d_in[26];
    const float* fc1_w = (const float*)d_in[27]; const float* fc1_b = (const float*)d_in[28];
    const float* fc2_w = (const float*)d_in[29]; const float* fc2_b = (const float*)d_in[30];

    float* ws = (float*)d_ws;
    float* Kc    = ws; ws += (size_t)BB * SS * EE;   // 134 MB
    float* Vc    = ws; ws += (size_t)BB * SS * EE;   // 134 MB
    float* Qc    = ws; ws += (size_t)BB * TQ * EE;
    float* attO  = ws; ws += (size_t)BB * TQ * EE;
    float* xproj = ws; ws += (size_t)BB * TQ * EE;
    float* hs1   = ws; ws += (size_t)BB * TQ * EE;
    float* xqsa  = ws; ws += (size_t)BB * TQ * EE;
    float* Qs    = ws; ws += (size_t)BB * TQ * EE;
    float* Ks2   = ws; ws += (size_t)BB * TQ * EE;
    float* Vs2   = ws; ws += (size_t)BB * TQ * EE;
    float* attO2 = ws; ws += (size_t)BB * TQ * EE;
    float* xpro2 = ws; ws += (size_t)BB * TQ * EE;
    float* hs2   = ws; ws += (size_t)BB * TQ * EE;
    float* h1    = ws; ws += (size_t)BB * TQ * FF;   // 26 MB
    float* xffn  = ws; ws += (size_t)BB * TQ * EE;

    const float qscale = 0.17677669529663687f; // 32^-0.5
    dim3 blk(256);
    const int MQ = BB * TQ;   // 3200
    const int MK = BB * SS;   // 131072
    const int QBLK = (TQ + 15) / 16;  // 7

    // ---- cross-attention ----
    gemm_nt<1><<<dim3(EE/BN, MQ/BM), blk, 0, stream>>>(hs,  qp,      ca_wq, ca_bq, Qc, MQ, EE, EE, TQ, BB, qscale, 0);
    gemm_nt<1><<<dim3(EE/BN, MK/BM), blk, 0, stream>>>(enc, ep,      ca_wk, ca_bk, Kc, MK, EE, EE, SS, BB, 1.f,    0);
    gemm_nt<1><<<dim3(EE/BN, MK/BM), blk, 0, stream>>>(enc, nullptr, ca_wv, ca_bv, Vc, MK, EE, EE, SS, BB, 1.f,    0);
    flash_attn<<<dim3(BB*HH*QBLK), blk, 0, stream>>>(Qc, Kc, Vc, mask, attO, SS, QBLK);
    gemm_nt<0><<<dim3(EE/BN, MQ/BM), blk, 0, stream>>>(attO, nullptr, ca_wo, ca_bo, xproj, MQ, EE, EE, 1, BB, 1.f, 0);
    ln_kernel<1,0><<<dim3(MQ), blk, 0, stream>>>(hs, xproj, ln1_g, ln1_b, hs1);

    // ---- self-attention ----
    add_qp_kernel<<<dim3(MQ), blk, 0, stream>>>(hs1, qp, xqsa);
    gemm_nt<0><<<dim3(EE/BN, MQ/BM), blk, 0, stream>>>(xqsa, nullptr, sa_wq, sa_bq, Qs, MQ, EE, EE, 1, BB, qscale, 0);
    gemm_nt<0><<<dim3(EE/BN, MQ/BM), blk, 0, stream>>>(xqsa, nullptr, sa_wk, sa_bk, Ks2, MQ, EE, EE, 1, BB, 1.f,    0);
    gemm_nt<0><<<dim3(EE/BN, MQ/BM), blk, 0, stream>>>(hs1,  nullptr, sa_wv, sa_bv, Vs2, MQ, EE, EE, 1, BB, 1.f,    0);
    flash_attn<<<dim3(BB*HH*QBLK), blk, 0, stream>>>(Qs, Ks2, Vs2, nullptr, attO2, TQ, QBLK);
    gemm_nt<0><<<dim3(EE/BN, MQ/BM), blk, 0, stream>>>(attO2, nullptr, sa_wo, sa_bo, xpro2, MQ, EE, EE, 1, BB, 1.f, 0);
    ln_kernel<0,0><<<dim3(MQ), blk, 0, stream>>>(hs1, xpro2, ln2_g, ln2_b, hs2);

    // ---- FFN ----
    gemm_nt<0><<<dim3(FF/BN, MQ/BM), blk, 0, stream>>>(hs2, nullptr, fc1_w, fc1_b, h1,   MQ, FF, EE, 1, BB, 1.f, 1);
    gemm_nt<0><<<dim3(EE/BN, MQ/BM), blk, 0, stream>>>(h1,  nullptr, fc2_w, fc2_b, xffn, MQ, EE, FF, 1, BB, 1.f, 0);
    ln_kernel<0,1><<<dim3(MQ), blk, 0, stream>>>(hs2, xffn, ln3_g, ln3_b, (float*)d_out);

    (void)in_sizes; (void)n_in; (void)out_size; (void)ws_size;
}

// Round 3
// 989.102 us; speedup vs baseline: 5.1129x; 3.3494x over previous
//
#include <hip/hip_runtime.h>
#include <hip/hip_bf16.h>
#include <math.h>

#define TQ 100
#define SS 4096
#define BB 32
#define EE 256
#define HH 8
#define FF 2048
#define DHH 32
#define LNEPS 1e-5f

#define BM 64
#define BN 64
#define BKT 16
#define APAD 4

typedef __attribute__((ext_vector_type(8))) short bf16x8;
typedef __attribute__((ext_vector_type(4))) short bf16x4;
typedef __attribute__((ext_vector_type(4))) float f32x4;

__device__ inline unsigned short f2bfu(float f) {
    __hip_bfloat16 h = __float2bfloat16(f);
    return *reinterpret_cast<unsigned short*>(&h);
}

// C[m][n] = act((sum_k A(m,k) * W[n*K+k] + bias[n]) * scale)
// GATHER=1: A row m -> offset ((m%SD)*Bdim + m/SD)*K. OBF=1: store bf16.
template<int GATHER, int OBF>
__global__ __launch_bounds__(256)
void gemm_nt(const float* __restrict__ A1, const float* __restrict__ A2,
             const float* __restrict__ W, const float* __restrict__ bias,
             void* __restrict__ Cv, int M, int N, int K,
             int SD, int Bdim, float scale, int relu)
{
    __shared__ float As[BKT][BM + APAD];
    __shared__ float Bs[BKT][BN + APAD];
    const int tid = threadIdx.x;
    const int tx = tid & 15, ty = tid >> 4;
    const int m0 = blockIdx.y * BM, n0 = blockIdx.x * BN;
    const int lr = tid >> 2;
    const int lc = (tid & 3) << 2;

    long long arow;
    {
        int m = m0 + lr;
        if (GATHER) {
            int b = m / SD, s = m - b * SD;
            arow = ((long long)s * Bdim + b) * (long long)K;
        } else {
            arow = (long long)m * K;
        }
    }
    const long long wrow = (long long)(n0 + lr) * K;

    float acc[4][4] = {};

    for (int k0 = 0; k0 < K; k0 += BKT) {
        float4 av = *(const float4*)(A1 + arow + k0 + lc);
        if (A2) {
            float4 a2 = *(const float4*)(A2 + arow + k0 + lc);
            av.x += a2.x; av.y += a2.y; av.z += a2.z; av.w += a2.w;
        }
        float4 wv = *(const float4*)(W + wrow + k0 + lc);
        __syncthreads();
        As[lc+0][lr] = av.x; As[lc+1][lr] = av.y; As[lc+2][lr] = av.z; As[lc+3][lr] = av.w;
        Bs[lc+0][lr] = wv.x; Bs[lc+1][lr] = wv.y; Bs[lc+2][lr] = wv.z; Bs[lc+3][lr] = wv.w;
        __syncthreads();
        #pragma unroll
        for (int kk = 0; kk < BKT; ++kk) {
            float a4[4], b4[4];
            #pragma unroll
            for (int i = 0; i < 4; ++i) a4[i] = As[kk][ty*4 + i];
            #pragma unroll
            for (int j = 0; j < 4; ++j) b4[j] = Bs[kk][tx*4 + j];
            #pragma unroll
            for (int i = 0; i < 4; ++i)
                #pragma unroll
                for (int j = 0; j < 4; ++j)
                    acc[i][j] += a4[i] * b4[j];
        }
    }

    #pragma unroll
    for (int i = 0; i < 4; ++i) {
        int m = m0 + ty*4 + i;
        float vv[4];
        #pragma unroll
        for (int j = 0; j < 4; ++j) {
            float v = (acc[i][j] + bias[n0 + tx*4 + j]) * scale;
            if (relu) v = fmaxf(v, 0.f);
            vv[j] = v;
        }
        if (OBF) {
            ushort4 ov;
            ov.x = f2bfu(vv[0]); ov.y = f2bfu(vv[1]);
            ov.z = f2bfu(vv[2]); ov.w = f2bfu(vv[3]);
            *(ushort4*)((__hip_bfloat16*)Cv + (long long)m * N + n0 + tx*4) = ov;
        } else {
            *(float4*)((float*)Cv + (long long)m * N + n0 + tx*4) =
                make_float4(vv[0], vv[1], vv[2], vv[3]);
        }
    }
}

// Ct[b*EE + n][s] = sum_k X(b,s,k) * W[n][k] + bias[n]   (bf16 out, row stride SVT)
// GATHER=1: X row (b,s) at ((s*Bdim)+b)*EE (seq-first). Guards s < SD.
template<int GATHER>
__global__ __launch_bounds__(256)
void vt_gemm(const float* __restrict__ X, const float* __restrict__ W,
             const float* __restrict__ bias, __hip_bfloat16* __restrict__ Ct,
             int SD, int Bdim, int SVT)
{
    __shared__ float Ws[BKT][BM + APAD];
    __shared__ float Xs[BKT][BN + APAD];
    const int tid = threadIdx.x;
    const int tx = tid & 15, ty = tid >> 4;
    const int s0 = blockIdx.x * BN, n0 = blockIdx.y * BM;
    const int b  = blockIdx.z;
    const int lr = tid >> 2, lc = (tid & 3) << 2;

    const long long wrow = (long long)(n0 + lr) * EE;
    int srow = s0 + lr; if (srow >= SD) srow = SD - 1;
    long long xrow;
    if (GATHER) xrow = ((long long)srow * Bdim + b) * EE;
    else        xrow = ((long long)b * SD + srow) * EE;

    float acc[4][4] = {};
    for (int k0 = 0; k0 < EE; k0 += BKT) {
        float4 wv = *(const float4*)(W + wrow + k0 + lc);
        float4 xv = *(const float4*)(X + xrow + k0 + lc);
        __syncthreads();
        Ws[lc+0][lr] = wv.x; Ws[lc+1][lr] = wv.y; Ws[lc+2][lr] = wv.z; Ws[lc+3][lr] = wv.w;
        Xs[lc+0][lr] = xv.x; Xs[lc+1][lr] = xv.y; Xs[lc+2][lr] = xv.z; Xs[lc+3][lr] = xv.w;
        __syncthreads();
        #pragma unroll
        for (int kk = 0; kk < BKT; ++kk) {
            float a4[4], b4[4];
            #pragma unroll
            for (int i = 0; i < 4; ++i) a4[i] = Ws[kk][ty*4 + i];
            #pragma unroll
            for (int j = 0; j < 4; ++j) b4[j] = Xs[kk][tx*4 + j];
            #pragma unroll
            for (int i = 0; i < 4; ++i)
                #pragma unroll
                for (int j = 0; j < 4; ++j)
                    acc[i][j] += a4[i] * b4[j];
        }
    }

    #pragma unroll
    for (int i = 0; i < 4; ++i) {
        const int n = n0 + ty*4 + i;
        const float bi = bias[n];
        const int s = s0 + tx*4;
        __hip_bfloat16* dst = Ct + (long long)(b * EE + n) * SVT + s;
        if (s + 3 < SD) {
            ushort4 ov;
            ov.x = f2bfu(acc[i][0] + bi); ov.y = f2bfu(acc[i][1] + bi);
            ov.z = f2bfu(acc[i][2] + bi); ov.w = f2bfu(acc[i][3] + bi);
            *(ushort4*)dst = ov;
        } else {
            #pragma unroll
            for (int j = 0; j < 4; ++j)
                if (s + j < SD) dst[j] = __float2bfloat16(acc[i][j] + bi);
        }
    }
}

// MFMA flash attention. Block = 128 threads (2 waves), each wave owns 16 queries.
// Kg: bf16 [B*Skv][EE] (head cols h*32..). Vtg: bf16 [B*EE][SVT] (transposed).
// Qg: bf16 [B*TQ][EE], pre-scaled. O: fp32 [B*TQ][EE].
#define KVB 32
#define LDP 40   // padded LDS row stride in bf16 (80 B: 16B-aligned, 2-way max alias)

__global__ __launch_bounds__(128, 4)
void flash_mfma(const __hip_bfloat16* __restrict__ Qg,
                const __hip_bfloat16* __restrict__ Kg,
                const __hip_bfloat16* __restrict__ Vtg,
                const float* __restrict__ mask,
                float* __restrict__ O,
                int Skv, int SVT, int qblocks)
{
    __shared__ short Ks[2][KVB][LDP];
    __shared__ short Vs[2][KVB][LDP];   // row = d (0..31), col = s-local
    const int tid = threadIdx.x;
    const int l = tid & 63;
    const int g = l >> 4, q16 = l & 15;
    const int qb = blockIdx.x % qblocks;
    const int bh = blockIdx.x / qblocks;
    const int h = bh & (HH - 1), b = bh >> 3;
    const int q0 = qb * 32 + (tid >> 6) * 16;

    int qc = q0 + q16; if (qc >= TQ) qc = TQ - 1;
    const bf16x8 qfrag = *(const bf16x8*)(Qg + ((long long)(b * TQ + qc)) * EE + h * DHH + g * 8);

    const int srow = tid >> 2;          // 0..31
    const int sseg = (tid & 3) * 8;     // bf16 col offset within 32
    const long long kbase = ((long long)b * Skv) * EE + h * DHH;
    const long long vbase = ((long long)(b * EE + h * DHH)) * SVT;
    const float* mrowp = mask ? mask + ((long long)bh * TQ + qc) * Skv : nullptr;

    f32x4 oacc[2] = {{0.f,0.f,0.f,0.f},{0.f,0.f,0.f,0.f}};
    float mrun = -1e30f, lrun = 0.f;
    const f32x4 zero = {0.f,0.f,0.f,0.f};

    // prefetch tile 0
    int s_ld = srow; if (s_ld >= Skv) s_ld = Skv - 1;
    bf16x8 kreg = *(const bf16x8*)(Kg + kbase + (long long)s_ld * EE + sseg);
    bf16x8 vreg = *(const bf16x8*)(Vtg + vbase + (long long)srow * SVT + sseg);

    const int nround = (Skv + KVB - 1) / KVB;
    for (int r = 0; r < nround; ++r) {
        const int buf = r & 1;
        *(bf16x8*)&Ks[buf][srow][sseg] = kreg;
        *(bf16x8*)&Vs[buf][srow][sseg] = vreg;
        if (r + 1 < nround) {
            int sn = (r + 1) * KVB + srow; if (sn >= Skv) sn = Skv - 1;
            kreg = *(const bf16x8*)(Kg + kbase + (long long)sn * EE + sseg);
            vreg = *(const bf16x8*)(Vtg + vbase + (long long)srow * SVT + (r + 1) * KVB + sseg);
        }
        __syncthreads();

        const int s0 = r * KVB;
        // S^T tiles: A = K (m=s), B = Q (n=q). Lane holds s = s0+16t+4g+reg, q = q16.
        f32x4 sT[2];
        #pragma unroll
        for (int t = 0; t < 2; ++t) {
            bf16x8 kf = *(const bf16x8*)&Ks[buf][t * 16 + q16][g * 8];
            sT[t] = __builtin_amdgcn_mfma_f32_16x16x32_bf16(kf, qfrag, zero, 0, 0, 0);
        }
        float sc[8];
        if (mrowp) {
            #pragma unroll
            for (int t = 0; t < 2; ++t) {
                float4 mk = *(const float4*)(mrowp + s0 + t * 16 + g * 4);
                sc[t*4+0] = sT[t][0] + mk.x; sc[t*4+1] = sT[t][1] + mk.y;
                sc[t*4+2] = sT[t][2] + mk.z; sc[t*4+3] = sT[t][3] + mk.w;
            }
        } else {
            #pragma unroll
            for (int t = 0; t < 2; ++t)
                #pragma unroll
                for (int rg = 0; rg < 4; ++rg) {
                    int s = s0 + t * 16 + g * 4 + rg;
                    sc[t*4+rg] = (s < Skv) ? sT[t][rg] : -1e30f;
                }
        }
        // online softmax (per q = q16; row spread over lanes l^16, l^32)
        float tmax = sc[0];
        #pragma unroll
        for (int i = 1; i < 8; ++i) tmax = fmaxf(tmax, sc[i]);
        tmax = fmaxf(tmax, __shfl_xor(tmax, 16));
        tmax = fmaxf(tmax, __shfl_xor(tmax, 32));
        const float mn = fmaxf(mrun, tmax);
        const float corr = __expf(mrun - mn);
        mrun = mn;
        float ps = 0.f;
        bf16x8 pfrag;
        #pragma unroll
        for (int i = 0; i < 8; ++i) {
            float p = __expf(sc[i] - mn);
            ps += p;
            pfrag[i] = (short)f2bfu(p);
        }
        ps += __shfl_xor(ps, 16);
        ps += __shfl_xor(ps, 32);
        lrun = lrun * corr + ps;
        // rescale O: O rows q = 4g+reg need corr from lane (4g+reg)
        #pragma unroll
        for (int rg = 0; rg < 4; ++rg) {
            float c = __shfl(corr, g * 4 + rg);
            oacc[0][rg] *= c;
            oacc[1][rg] *= c;
        }
        // PV: A = P (m=q, slots s=16t+4g+rg), B = V^T (n=d, same slot map)
        #pragma unroll
        for (int T = 0; T < 2; ++T) {
            bf16x4 v0 = *(const bf16x4*)&Vs[buf][T * 16 + q16][g * 4];
            bf16x4 v1 = *(const bf16x4*)&Vs[buf][T * 16 + q16][16 + g * 4];
            bf16x8 vf;
            vf[0] = v0[0]; vf[1] = v0[1]; vf[2] = v0[2]; vf[3] = v0[3];
            vf[4] = v1[0]; vf[5] = v1[1]; vf[6] = v1[2]; vf[7] = v1[3];
            oacc[T] = __builtin_amdgcn_mfma_f32_16x16x32_bf16(pfrag, vf, oacc[T], 0, 0, 0);
        }
        __syncthreads();
    }

    float linv[4];
    #pragma unroll
    for (int rg = 0; rg < 4; ++rg)
        linv[rg] = 1.f / __shfl(lrun, g * 4 + rg);
    #pragma unroll
    for (int rg = 0; rg < 4; ++rg) {
        const int q = q0 + g * 4 + rg;
        if (q < TQ) {
            float* op = O + ((long long)(b * TQ + q)) * EE + h * DHH + q16;
            op[0]  = oacc[0][rg] * linv[rg];
            op[16] = oacc[1][rg] * linv[rg];
        }
    }
}

// LayerNorm over E=256: out = LN(res + x) * gamma + beta.
template<int GATHER_RES, int OUT_T>
__global__ __launch_bounds__(256)
void ln_kernel(const float* __restrict__ res, const float* __restrict__ x,
               const float* __restrict__ gam, const float* __restrict__ bet,
               float* __restrict__ out)
{
    __shared__ float r1[4], r2[4];
    const int m = blockIdx.x;
    const int k = threadIdx.x;
    const int b = m / TQ, t = m - b * TQ;
    const long long roff = GATHER_RES ? ((long long)(t * BB + b)) * EE : (long long)m * EE;
    float v = res[roff + k] + x[(long long)m * EE + k];
    float s = v;
    #pragma unroll
    for (int off = 32; off; off >>= 1) s += __shfl_down(s, off);
    if ((k & 63) == 0) r1[k >> 6] = s;
    __syncthreads();
    const float mu = (r1[0] + r1[1] + r1[2] + r1[3]) * (1.0f / EE);
    const float d = v - mu;
    float s2 = d * d;
    #pragma unroll
    for (int off = 32; off; off >>= 1) s2 += __shfl_down(s2, off);
    if ((k & 63) == 0) r2[k >> 6] = s2;
    __syncthreads();
    const float var = (r2[0] + r2[1] + r2[2] + r2[3]) * (1.0f / EE);
    const float o = d * rsqrtf(var + LNEPS) * gam[k] + bet[k];
    const long long ooff = OUT_T ? ((long long)(t * BB + b)) * EE : (long long)m * EE;
    out[ooff + k] = o;
}

__global__ __launch_bounds__(256)
void add_qp_kernel(const float* __restrict__ a, const float* __restrict__ qp,
                   float* __restrict__ out)
{
    const int idx = blockIdx.x * 256 + threadIdx.x;
    const int m = idx >> 8;
    const int k = idx & 255;
    const int b = m / TQ, t = m - b * TQ;
    out[idx] = a[idx] + qp[((long long)(t * BB + b)) * EE + k];
}

extern "C" void kernel_launch(void* const* d_in, const int* in_sizes, int n_in,
                              void* d_out, int out_size, void* d_ws, size_t ws_size,
                              hipStream_t stream)
{
    const float* hs    = (const float*)d_in[0];
    const float* qp    = (const float*)d_in[1];
    const float* enc   = (const float*)d_in[2];
    const float* ep    = (const float*)d_in[3];
    const float* mask  = (const float*)d_in[4];
    const float* ca_wq = (const float*)d_in[5];  const float* ca_bq = (const float*)d_in[6];
    const float* ca_wk = (const float*)d_in[7];  const float* ca_bk = (const float*)d_in[8];
    const float* ca_wv = (const float*)d_in[9];  const float* ca_bv = (const float*)d_in[10];
    const float* ca_wo = (const float*)d_in[11]; const float* ca_bo = (const float*)d_in[12];
    const float* sa_wq = (const float*)d_in[13]; const float* sa_bq = (const float*)d_in[14];
    const float* sa_wk = (const float*)d_in[15]; const float* sa_bk = (const float*)d_in[16];
    const float* sa_wv = (const float*)d_in[17]; const float* sa_bv = (const float*)d_in[18];
    const float* sa_wo = (const float*)d_in[19]; const float* sa_bo = (const float*)d_in[20];
    const float* ln1_g = (const float*)d_in[21]; const float* ln1_b = (const float*)d_in[22];
    const float* ln2_g = (const float*)d_in[23]; const float* ln2_b = (const float*)d_in[24];
    const float* ln3_g = (const float*)d_in[25]; const float* ln3_b = (const float*)d_in[26];
    const float* fc1_w = (const float*)d_in[27]; const float* fc1_b = (const float*)d_in[28];
    const float* fc2_w = (const float*)d_in[29]; const float* fc2_b = (const float*)d_in[30];

    const int MQ = BB * TQ;   // 3200
    const int MK = BB * SS;   // 131072
    const int SVT2 = 128;     // padded S for SA V^T

    size_t off = 0;
    char* base = (char*)d_ws;
    auto alloc = [&](size_t bytes) -> void* {
        void* p = base + off; off = (off + bytes + 255) & ~(size_t)255; return p;
    };
    __hip_bfloat16* Kc  = (__hip_bfloat16*)alloc((size_t)MK * EE * 2);
    __hip_bfloat16* Vt  = (__hip_bfloat16*)alloc((size_t)BB * EE * SS * 2);
    __hip_bfloat16* Qc  = (__hip_bfloat16*)alloc((size_t)MQ * EE * 2);
    __hip_bfloat16* Qs  = (__hip_bfloat16*)alloc((size_t)MQ * EE * 2);
    __hip_bfloat16* Ks2 = (__hip_bfloat16*)alloc((size_t)MQ * EE * 2);
    __hip_bfloat16* Vt2 = (__hip_bfloat16*)alloc((size_t)BB * EE * SVT2 * 2);
    float* attO  = (float*)alloc((size_t)MQ * EE * 4);
    float* xproj = (float*)alloc((size_t)MQ * EE * 4);
    float* hs1   = (float*)alloc((size_t)MQ * EE * 4);
    float* xqsa  = (float*)alloc((size_t)MQ * EE * 4);
    float* attO2 = (float*)alloc((size_t)MQ * EE * 4);
    float* xpro2 = (float*)alloc((size_t)MQ * EE * 4);
    float* hs2   = (float*)alloc((size_t)MQ * EE * 4);
    float* h1    = (float*)alloc((size_t)MQ * FF * 4);
    float* xffn  = (float*)alloc((size_t)MQ * EE * 4);

    const float qscale = 0.17677669529663687f; // 32^-0.5
    dim3 blk(256);
    const int QBLK = 4;  // 4 * 32 >= 100

    // ---- cross-attention ----
    gemm_nt<1,1><<<dim3(EE/BN, MQ/BM), blk, 0, stream>>>(hs,  qp, ca_wq, ca_bq, Qc, MQ, EE, EE, TQ, BB, qscale, 0);
    gemm_nt<1,1><<<dim3(EE/BN, MK/BM), blk, 0, stream>>>(enc, ep, ca_wk, ca_bk, Kc, MK, EE, EE, SS, BB, 1.f,    0);
    vt_gemm<1><<<dim3(SS/BN, EE/BM, BB), blk, 0, stream>>>(enc, ca_wv, ca_bv, Vt, SS, BB, SS);
    flash_mfma<<<dim3(BB*HH*QBLK), dim3(128), 0, stream>>>(Qc, Kc, Vt, mask, attO, SS, SS, QBLK);
    gemm_nt<0,0><<<dim3(EE/BN, MQ/BM), blk, 0, stream>>>(attO, nullptr, ca_wo, ca_bo, xproj, MQ, EE, EE, 1, BB, 1.f, 0);
    ln_kernel<1,0><<<dim3(MQ), blk, 0, stream>>>(hs, xproj, ln1_g, ln1_b, hs1);

    // ---- self-attention ----
    add_qp_kernel<<<dim3(MQ), blk, 0, stream>>>(hs1, qp, xqsa);
    gemm_nt<0,1><<<dim3(EE/BN, MQ/BM), blk, 0, stream>>>(xqsa, nullptr, sa_wq, sa_bq, Qs,  MQ, EE, EE, 1, BB, qscale, 0);
    gemm_nt<0,1><<<dim3(EE/BN, MQ/BM), blk, 0, stream>>>(xqsa, nullptr, sa_wk, sa_bk, Ks2, MQ, EE, EE, 1, BB, 1.f,    0);
    vt_gemm<0><<<dim3(2, EE/BM, BB), blk, 0, stream>>>(hs1, sa_wv, sa_bv, Vt2, TQ, BB, SVT2);
    flash_mfma<<<dim3(BB*HH*QBLK), dim3(128), 0, stream>>>(Qs, Ks2, Vt2, nullptr, attO2, TQ, SVT2, QBLK);
    gemm_nt<0,0><<<dim3(EE/BN, MQ/BM), blk, 0, stream>>>(attO2, nullptr, sa_wo, sa_bo, xpro2, MQ, EE, EE, 1, BB, 1.f, 0);
    ln_kernel<0,0><<<dim3(MQ), blk, 0, stream>>>(hs1, xpro2, ln2_g, ln2_b, hs2);

    // ---- FFN ----
    gemm_nt<0,0><<<dim3(FF/BN, MQ/BM), blk, 0, stream>>>(hs2, nullptr, fc1_w, fc1_b, h1,   MQ, FF, EE, 1, BB, 1.f, 1);
    gemm_nt<0,0><<<dim3(EE/BN, MQ/BM), blk, 0, stream>>>(h1,  nullptr, fc2_w, fc2_b, xffn, MQ, EE, FF, 1, BB, 1.f, 0);
    ln_kernel<0,1><<<dim3(MQ), blk, 0, stream>>>(hs2, xffn, ln3_g, ln3_b, (float*)d_out);

    (void)in_sizes; (void)n_in; (void)out_size; (void)ws_size;
}

// Round 4
// 618.001 us; speedup vs baseline: 8.1832x; 1.6005x over previous
//
#include <hip/hip_runtime.h>
#include <hip/hip_bf16.h>
#include <math.h>

#define TQ 100
#define SS 4096
#define BB 32
#define EE 256
#define HH 8
#define FF 2048
#define DHH 32
#define LNEPS 1e-5f

#define BM 64
#define BN 64
#define BKT 16
#define APAD 4

typedef __attribute__((ext_vector_type(8))) short bf16x8;
typedef __attribute__((ext_vector_type(4))) short bf16x4;
typedef __attribute__((ext_vector_type(4))) float f32x4;

__device__ inline unsigned short f2bfu(float f) {
    __hip_bfloat16 h = __float2bfloat16(f);
    return *reinterpret_cast<unsigned short*>(&h);
}

// ---------------- fp32 tiled GEMM (small matrices) ----------------
template<int GATHER, int OBF>
__global__ __launch_bounds__(256)
void gemm_nt(const float* __restrict__ A1, const float* __restrict__ A2,
             const float* __restrict__ W, const float* __restrict__ bias,
             void* __restrict__ Cv, int M, int N, int K,
             int SD, int Bdim, float scale, int relu)
{
    __shared__ float As[BKT][BM + APAD];
    __shared__ float Bs[BKT][BN + APAD];
    const int tid = threadIdx.x;
    const int tx = tid & 15, ty = tid >> 4;
    const int m0 = blockIdx.y * BM, n0 = blockIdx.x * BN;
    const int lr = tid >> 2;
    const int lc = (tid & 3) << 2;

    long long arow;
    {
        int m = m0 + lr;
        if (GATHER) {
            int b = m / SD, s = m - b * SD;
            arow = ((long long)s * Bdim + b) * (long long)K;
        } else {
            arow = (long long)m * K;
        }
    }
    const long long wrow = (long long)(n0 + lr) * K;

    float acc[4][4] = {};

    for (int k0 = 0; k0 < K; k0 += BKT) {
        float4 av = *(const float4*)(A1 + arow + k0 + lc);
        if (A2) {
            float4 a2 = *(const float4*)(A2 + arow + k0 + lc);
            av.x += a2.x; av.y += a2.y; av.z += a2.z; av.w += a2.w;
        }
        float4 wv = *(const float4*)(W + wrow + k0 + lc);
        __syncthreads();
        As[lc+0][lr] = av.x; As[lc+1][lr] = av.y; As[lc+2][lr] = av.z; As[lc+3][lr] = av.w;
        Bs[lc+0][lr] = wv.x; Bs[lc+1][lr] = wv.y; Bs[lc+2][lr] = wv.z; Bs[lc+3][lr] = wv.w;
        __syncthreads();
        #pragma unroll
        for (int kk = 0; kk < BKT; ++kk) {
            float a4[4], b4[4];
            #pragma unroll
            for (int i = 0; i < 4; ++i) a4[i] = As[kk][ty*4 + i];
            #pragma unroll
            for (int j = 0; j < 4; ++j) b4[j] = Bs[kk][tx*4 + j];
            #pragma unroll
            for (int i = 0; i < 4; ++i)
                #pragma unroll
                for (int j = 0; j < 4; ++j)
                    acc[i][j] += a4[i] * b4[j];
        }
    }

    #pragma unroll
    for (int i = 0; i < 4; ++i) {
        int m = m0 + ty*4 + i;
        float vv[4];
        #pragma unroll
        for (int j = 0; j < 4; ++j) {
            float v = (acc[i][j] + bias[n0 + tx*4 + j]) * scale;
            if (relu) v = fmaxf(v, 0.f);
            vv[j] = v;
        }
        if (OBF) {
            ushort4 ov;
            ov.x = f2bfu(vv[0]); ov.y = f2bfu(vv[1]);
            ov.z = f2bfu(vv[2]); ov.w = f2bfu(vv[3]);
            *(ushort4*)((__hip_bfloat16*)Cv + (long long)m * N + n0 + tx*4) = ov;
        } else {
            *(float4*)((float*)Cv + (long long)m * N + n0 + tx*4) =
                make_float4(vv[0], vv[1], vv[2], vv[3]);
        }
    }
}

// ---------------- small V^T fp32 GEMM (SA only) ----------------
template<int GATHER>
__global__ __launch_bounds__(256)
void vt_gemm(const float* __restrict__ X, const float* __restrict__ W,
             const float* __restrict__ bias, __hip_bfloat16* __restrict__ Ct,
             int SD, int Bdim, int SVT)
{
    __shared__ float Ws[BKT][BM + APAD];
    __shared__ float Xs[BKT][BN + APAD];
    const int tid = threadIdx.x;
    const int tx = tid & 15, ty = tid >> 4;
    const int s0 = blockIdx.x * BN, n0 = blockIdx.y * BM;
    const int b  = blockIdx.z;
    const int lr = tid >> 2, lc = (tid & 3) << 2;

    const long long wrow = (long long)(n0 + lr) * EE;
    int srow = s0 + lr; if (srow >= SD) srow = SD - 1;
    long long xrow;
    if (GATHER) xrow = ((long long)srow * Bdim + b) * EE;
    else        xrow = ((long long)b * SD + srow) * EE;

    float acc[4][4] = {};
    for (int k0 = 0; k0 < EE; k0 += BKT) {
        float4 wv = *(const float4*)(W + wrow + k0 + lc);
        float4 xv = *(const float4*)(X + xrow + k0 + lc);
        __syncthreads();
        Ws[lc+0][lr] = wv.x; Ws[lc+1][lr] = wv.y; Ws[lc+2][lr] = wv.z; Ws[lc+3][lr] = wv.w;
        Xs[lc+0][lr] = xv.x; Xs[lc+1][lr] = xv.y; Xs[lc+2][lr] = xv.z; Xs[lc+3][lr] = xv.w;
        __syncthreads();
        #pragma unroll
        for (int kk = 0; kk < BKT; ++kk) {
            float a4[4], b4[4];
            #pragma unroll
            for (int i = 0; i < 4; ++i) a4[i] = Ws[kk][ty*4 + i];
            #pragma unroll
            for (int j = 0; j < 4; ++j) b4[j] = Xs[kk][tx*4 + j];
            #pragma unroll
            for (int i = 0; i < 4; ++i)
                #pragma unroll
                for (int j = 0; j < 4; ++j)
                    acc[i][j] += a4[i] * b4[j];
        }
    }

    #pragma unroll
    for (int i = 0; i < 4; ++i) {
        const int n = n0 + ty*4 + i;
        const float bi = bias[n];
        const int s = s0 + tx*4;
        __hip_bfloat16* dst = Ct + (long long)(b * EE + n) * SVT + s;
        if (s + 3 < SD) {
            ushort4 ov;
            ov.x = f2bfu(acc[i][0] + bi); ov.y = f2bfu(acc[i][1] + bi);
            ov.z = f2bfu(acc[i][2] + bi); ov.w = f2bfu(acc[i][3] + bi);
            *(ushort4*)dst = ov;
        } else {
            #pragma unroll
            for (int j = 0; j < 4; ++j)
                if (s + j < SD) dst[j] = __float2bfloat16(acc[i][j] + bi);
        }
    }
}

// ---------------- weight fp32->bf16 convert ----------------
__global__ __launch_bounds__(256)
void cvt_w(const float* __restrict__ w, __hip_bfloat16* __restrict__ o, int n)
{
    int i = blockIdx.x * 256 + threadIdx.x;
    if (i * 4 < n) {
        float4 v = *(const float4*)(w + i * 4);
        ushort4 ov;
        ov.x = f2bfu(v.x); ov.y = f2bfu(v.y); ov.z = f2bfu(v.z); ov.w = f2bfu(v.w);
        *(ushort4*)((unsigned short*)o + i * 4) = ov;
    }
}

// ---------------- big MFMA projection GEMM ----------------
// M = BB*SS rows (m = b*SS + s). A fp32 seq-first gather [(s*BB+b)*EE], optional A2 added.
// W bf16 [256][256]. TRANS=0: out[m][256] bf16. TRANS=1: out[(b*EE+n)*ldo + s] bf16.
#define PBM 64
#define PBK 32
#define PLDP 40

template<int ADD, int TRANS>
__global__ __launch_bounds__(256)
void proj_gemm(const float* __restrict__ A1, const float* __restrict__ A2,
               const __hip_bfloat16* __restrict__ Wb, const float* __restrict__ bias,
               __hip_bfloat16* __restrict__ out, int ldo)
{
    __shared__ short As[PBM][PLDP];
    __shared__ short Bs[256][PLDP];
    const int tid = threadIdx.x;
    const int m0 = blockIdx.x * PBM;
    const int b = m0 >> 12;            // / SS
    const int s0 = m0 & (SS - 1);
    const int rr = tid >> 2;           // 0..63
    const int rc = (tid & 3) << 3;     // 0,8,16,24
    const long long abase = ((long long)(s0 + rr) * BB + b) * EE + rc;

    const int wv = tid >> 6, l = tid & 63;
    const int wm0 = (wv & 1) * 32, wn0 = (wv >> 1) * 128;
    const int lr16 = l & 15, lk8 = (l >> 4) * 8;

    f32x4 acc[2][8] = {};

    for (int k0 = 0; k0 < EE; k0 += PBK) {
        float4 a0 = *(const float4*)(A1 + abase + k0);
        float4 a1 = *(const float4*)(A1 + abase + k0 + 4);
        if (ADD) {
            float4 e0 = *(const float4*)(A2 + abase + k0);
            float4 e1 = *(const float4*)(A2 + abase + k0 + 4);
            a0.x += e0.x; a0.y += e0.y; a0.z += e0.z; a0.w += e0.w;
            a1.x += e1.x; a1.y += e1.y; a1.z += e1.z; a1.w += e1.w;
        }
        bf16x8 apack;
        apack[0] = (short)f2bfu(a0.x); apack[1] = (short)f2bfu(a0.y);
        apack[2] = (short)f2bfu(a0.z); apack[3] = (short)f2bfu(a0.w);
        apack[4] = (short)f2bfu(a1.x); apack[5] = (short)f2bfu(a1.y);
        apack[6] = (short)f2bfu(a1.z); apack[7] = (short)f2bfu(a1.w);

        bf16x8 wreg[4];
        #pragma unroll
        for (int it = 0; it < 4; ++it)
            wreg[it] = *(const bf16x8*)(Wb + (long long)(rr + it * 64) * EE + k0 + rc);

        __syncthreads();
        *(bf16x8*)&As[rr][rc] = apack;
        #pragma unroll
        for (int it = 0; it < 4; ++it)
            *(bf16x8*)&Bs[rr + it * 64][rc] = wreg[it];
        __syncthreads();

        bf16x8 af0 = *(const bf16x8*)&As[wm0 + lr16][lk8];
        bf16x8 af1 = *(const bf16x8*)&As[wm0 + 16 + lr16][lk8];
        #pragma unroll
        for (int j = 0; j < 8; ++j) {
            bf16x8 bfr = *(const bf16x8*)&Bs[wn0 + j * 16 + lr16][lk8];
            acc[0][j] = __builtin_amdgcn_mfma_f32_16x16x32_bf16(af0, bfr, acc[0][j], 0, 0, 0);
            acc[1][j] = __builtin_amdgcn_mfma_f32_16x16x32_bf16(af1, bfr, acc[1][j], 0, 0, 0);
        }
    }

    const int q4 = (l >> 4) * 4;
    #pragma unroll
    for (int i = 0; i < 2; ++i) {
        const int mrow = wm0 + i * 16 + q4;
        #pragma unroll
        for (int j = 0; j < 8; ++j) {
            const int n = wn0 + j * 16 + lr16;
            const float bi = bias[n];
            if (TRANS) {
                ushort4 pk;
                pk.x = f2bfu(acc[i][j][0] + bi);
                pk.y = f2bfu(acc[i][j][1] + bi);
                pk.z = f2bfu(acc[i][j][2] + bi);
                pk.w = f2bfu(acc[i][j][3] + bi);
                *(ushort4*)(out + (long long)(b * EE + n) * ldo + s0 + mrow) = pk;
            } else {
                #pragma unroll
                for (int r = 0; r < 4; ++r)
                    out[(long long)(m0 + mrow + r) * EE + n] = __float2bfloat16(acc[i][j][r] + bi);
            }
        }
    }
}

// ---------------- MFMA flash attention (verified R2) ----------------
#define KVB 32
#define LDP 40

__global__ __launch_bounds__(128, 4)
void flash_mfma(const __hip_bfloat16* __restrict__ Qg,
                const __hip_bfloat16* __restrict__ Kg,
                const __hip_bfloat16* __restrict__ Vtg,
                const float* __restrict__ mask,
                float* __restrict__ O,
                int Skv, int SVT, int qblocks)
{
    __shared__ short Ks[2][KVB][LDP];
    __shared__ short Vs[2][KVB][LDP];
    const int tid = threadIdx.x;
    const int l = tid & 63;
    const int g = l >> 4, q16 = l & 15;
    const int qb = blockIdx.x % qblocks;
    const int bh = blockIdx.x / qblocks;
    const int h = bh & (HH - 1), b = bh >> 3;
    const int q0 = qb * 32 + (tid >> 6) * 16;

    int qc = q0 + q16; if (qc >= TQ) qc = TQ - 1;
    const bf16x8 qfrag = *(const bf16x8*)(Qg + ((long long)(b * TQ + qc)) * EE + h * DHH + g * 8);

    const int srow = tid >> 2;
    const int sseg = (tid & 3) * 8;
    const long long kbase = ((long long)b * Skv) * EE + h * DHH;
    const long long vbase = ((long long)(b * EE + h * DHH)) * SVT;
    const float* mrowp = mask ? mask + ((long long)bh * TQ + qc) * Skv : nullptr;

    f32x4 oacc[2] = {{0.f,0.f,0.f,0.f},{0.f,0.f,0.f,0.f}};
    float mrun = -1e30f, lrun = 0.f;
    const f32x4 zero = {0.f,0.f,0.f,0.f};

    int s_ld = srow; if (s_ld >= Skv) s_ld = Skv - 1;
    bf16x8 kreg = *(const bf16x8*)(Kg + kbase + (long long)s_ld * EE + sseg);
    bf16x8 vreg = *(const bf16x8*)(Vtg + vbase + (long long)srow * SVT + sseg);

    const int nround = (Skv + KVB - 1) / KVB;
    for (int r = 0; r < nround; ++r) {
        const int buf = r & 1;
        *(bf16x8*)&Ks[buf][srow][sseg] = kreg;
        *(bf16x8*)&Vs[buf][srow][sseg] = vreg;
        if (r + 1 < nround) {
            int sn = (r + 1) * KVB + srow; if (sn >= Skv) sn = Skv - 1;
            kreg = *(const bf16x8*)(Kg + kbase + (long long)sn * EE + sseg);
            vreg = *(const bf16x8*)(Vtg + vbase + (long long)srow * SVT + (r + 1) * KVB + sseg);
        }
        __syncthreads();

        const int s0 = r * KVB;
        f32x4 sT[2];
        #pragma unroll
        for (int t = 0; t < 2; ++t) {
            bf16x8 kf = *(const bf16x8*)&Ks[buf][t * 16 + q16][g * 8];
            sT[t] = __builtin_amdgcn_mfma_f32_16x16x32_bf16(kf, qfrag, zero, 0, 0, 0);
        }
        float sc[8];
        if (mrowp) {
            #pragma unroll
            for (int t = 0; t < 2; ++t) {
                float4 mk = *(const float4*)(mrowp + s0 + t * 16 + g * 4);
                sc[t*4+0] = sT[t][0] + mk.x; sc[t*4+1] = sT[t][1] + mk.y;
                sc[t*4+2] = sT[t][2] + mk.z; sc[t*4+3] = sT[t][3] + mk.w;
            }
        } else {
            #pragma unroll
            for (int t = 0; t < 2; ++t)
                #pragma unroll
                for (int rg = 0; rg < 4; ++rg) {
                    int s = s0 + t * 16 + g * 4 + rg;
                    sc[t*4+rg] = (s < Skv) ? sT[t][rg] : -1e30f;
                }
        }
        float tmax = sc[0];
        #pragma unroll
        for (int i = 1; i < 8; ++i) tmax = fmaxf(tmax, sc[i]);
        tmax = fmaxf(tmax, __shfl_xor(tmax, 16));
        tmax = fmaxf(tmax, __shfl_xor(tmax, 32));
        const float mn = fmaxf(mrun, tmax);
        const float corr = __expf(mrun - mn);
        mrun = mn;
        float ps = 0.f;
        bf16x8 pfrag;
        #pragma unroll
        for (int i = 0; i < 8; ++i) {
            float p = __expf(sc[i] - mn);
            ps += p;
            pfrag[i] = (short)f2bfu(p);
        }
        ps += __shfl_xor(ps, 16);
        ps += __shfl_xor(ps, 32);
        lrun = lrun * corr + ps;
        #pragma unroll
        for (int rg = 0; rg < 4; ++rg) {
            float c = __shfl(corr, g * 4 + rg);
            oacc[0][rg] *= c;
            oacc[1][rg] *= c;
        }
        #pragma unroll
        for (int T = 0; T < 2; ++T) {
            bf16x4 v0 = *(const bf16x4*)&Vs[buf][T * 16 + q16][g * 4];
            bf16x4 v1 = *(const bf16x4*)&Vs[buf][T * 16 + q16][16 + g * 4];
            bf16x8 vf;
            vf[0] = v0[0]; vf[1] = v0[1]; vf[2] = v0[2]; vf[3] = v0[3];
            vf[4] = v1[0]; vf[5] = v1[1]; vf[6] = v1[2]; vf[7] = v1[3];
            oacc[T] = __builtin_amdgcn_mfma_f32_16x16x32_bf16(pfrag, vf, oacc[T], 0, 0, 0);
        }
        __syncthreads();
    }

    float linv[4];
    #pragma unroll
    for (int rg = 0; rg < 4; ++rg)
        linv[rg] = 1.f / __shfl(lrun, g * 4 + rg);
    #pragma unroll
    for (int rg = 0; rg < 4; ++rg) {
        const int q = q0 + g * 4 + rg;
        if (q < TQ) {
            float* op = O + ((long long)(b * TQ + q)) * EE + h * DHH + q16;
            op[0]  = oacc[0][rg] * linv[rg];
            op[16] = oacc[1][rg] * linv[rg];
        }
    }
}

// ---------------- LayerNorm ----------------
template<int GATHER_RES, int OUT_T>
__global__ __launch_bounds__(256)
void ln_kernel(const float* __restrict__ res, const float* __restrict__ x,
               const float* __restrict__ gam, const float* __restrict__ bet,
               float* __restrict__ out)
{
    __shared__ float r1[4], r2[4];
    const int m = blockIdx.x;
    const int k = threadIdx.x;
    const int b = m / TQ, t = m - b * TQ;
    const long long roff = GATHER_RES ? ((long long)(t * BB + b)) * EE : (long long)m * EE;
    float v = res[roff + k] + x[(long long)m * EE + k];
    float s = v;
    #pragma unroll
    for (int off = 32; off; off >>= 1) s += __shfl_down(s, off);
    if ((k & 63) == 0) r1[k >> 6] = s;
    __syncthreads();
    const float mu = (r1[0] + r1[1] + r1[2] + r1[3]) * (1.0f / EE);
    const float d = v - mu;
    float s2 = d * d;
    #pragma unroll
    for (int off = 32; off; off >>= 1) s2 += __shfl_down(s2, off);
    if ((k & 63) == 0) r2[k >> 6] = s2;
    __syncthreads();
    const float var = (r2[0] + r2[1] + r2[2] + r2[3]) * (1.0f / EE);
    const float o = d * rsqrtf(var + LNEPS) * gam[k] + bet[k];
    const long long ooff = OUT_T ? ((long long)(t * BB + b)) * EE : (long long)m * EE;
    out[ooff + k] = o;
}

__global__ __launch_bounds__(256)
void add_qp_kernel(const float* __restrict__ a, const float* __restrict__ qp,
                   float* __restrict__ out)
{
    const int idx = blockIdx.x * 256 + threadIdx.x;
    const int m = idx >> 8;
    const int k = idx & 255;
    const int b = m / TQ, t = m - b * TQ;
    out[idx] = a[idx] + qp[((long long)(t * BB + b)) * EE + k];
}

extern "C" void kernel_launch(void* const* d_in, const int* in_sizes, int n_in,
                              void* d_out, int out_size, void* d_ws, size_t ws_size,
                              hipStream_t stream)
{
    const float* hs    = (const float*)d_in[0];
    const float* qp    = (const float*)d_in[1];
    const float* enc   = (const float*)d_in[2];
    const float* ep    = (const float*)d_in[3];
    const float* mask  = (const float*)d_in[4];
    const float* ca_wq = (const float*)d_in[5];  const float* ca_bq = (const float*)d_in[6];
    const float* ca_wk = (const float*)d_in[7];  const float* ca_bk = (const float*)d_in[8];
    const float* ca_wv = (const float*)d_in[9];  const float* ca_bv = (const float*)d_in[10];
    const float* ca_wo = (const float*)d_in[11]; const float* ca_bo = (const float*)d_in[12];
    const float* sa_wq = (const float*)d_in[13]; const float* sa_bq = (const float*)d_in[14];
    const float* sa_wk = (const float*)d_in[15]; const float* sa_bk = (const float*)d_in[16];
    const float* sa_wv = (const float*)d_in[17]; const float* sa_bv = (const float*)d_in[18];
    const float* sa_wo = (const float*)d_in[19]; const float* sa_bo = (const float*)d_in[20];
    const float* ln1_g = (const float*)d_in[21]; const float* ln1_b = (const float*)d_in[22];
    const float* ln2_g = (const float*)d_in[23]; const float* ln2_b = (const float*)d_in[24];
    const float* ln3_g = (const float*)d_in[25]; const float* ln3_b = (const float*)d_in[26];
    const float* fc1_w = (const float*)d_in[27]; const float* fc1_b = (const float*)d_in[28];
    const float* fc2_w = (const float*)d_in[29]; const float* fc2_b = (const float*)d_in[30];

    const int MQ = BB * TQ;   // 3200
    const int MK = BB * SS;   // 131072
    const int SVT2 = 128;

    size_t off = 0;
    char* base = (char*)d_ws;
    auto alloc = [&](size_t bytes) -> void* {
        void* p = base + off; off = (off + bytes + 255) & ~(size_t)255; return p;
    };
    __hip_bfloat16* Kc  = (__hip_bfloat16*)alloc((size_t)MK * EE * 2);
    __hip_bfloat16* Vt  = (__hip_bfloat16*)alloc((size_t)BB * EE * SS * 2);
    __hip_bfloat16* Qc  = (__hip_bfloat16*)alloc((size_t)MQ * EE * 2);
    __hip_bfloat16* Qs  = (__hip_bfloat16*)alloc((size_t)MQ * EE * 2);
    __hip_bfloat16* Ks2 = (__hip_bfloat16*)alloc((size_t)MQ * EE * 2);
    __hip_bfloat16* Vt2 = (__hip_bfloat16*)alloc((size_t)BB * EE * SVT2 * 2);
    __hip_bfloat16* Wkb = (__hip_bfloat16*)alloc((size_t)EE * EE * 2);
    __hip_bfloat16* Wvb = (__hip_bfloat16*)alloc((size_t)EE * EE * 2);
    float* attO  = (float*)alloc((size_t)MQ * EE * 4);
    float* xproj = (float*)alloc((size_t)MQ * EE * 4);
    float* hs1   = (float*)alloc((size_t)MQ * EE * 4);
    float* xqsa  = (float*)alloc((size_t)MQ * EE * 4);
    float* attO2 = (float*)alloc((size_t)MQ * EE * 4);
    float* xpro2 = (float*)alloc((size_t)MQ * EE * 4);
    float* hs2   = (float*)alloc((size_t)MQ * EE * 4);
    float* h1    = (float*)alloc((size_t)MQ * FF * 4);
    float* xffn  = (float*)alloc((size_t)MQ * EE * 4);

    const float qscale = 0.17677669529663687f;
    dim3 blk(256);
    const int QBLK = 4;

    // weights -> bf16 (tiny)
    cvt_w<<<dim3(EE*EE/1024), blk, 0, stream>>>(ca_wk, Wkb, EE*EE);
    cvt_w<<<dim3(EE*EE/1024), blk, 0, stream>>>(ca_wv, Wvb, EE*EE);

    // ---- cross-attention ----
    gemm_nt<1,1><<<dim3(EE/BN, MQ/BM), blk, 0, stream>>>(hs,  qp, ca_wq, ca_bq, Qc, MQ, EE, EE, TQ, BB, qscale, 0);
    proj_gemm<1,0><<<dim3(MK/PBM), blk, 0, stream>>>(enc, ep,      Wkb, ca_bk, Kc, EE);
    proj_gemm<0,1><<<dim3(MK/PBM), blk, 0, stream>>>(enc, nullptr, Wvb, ca_bv, Vt, SS);
    flash_mfma<<<dim3(BB*HH*QBLK), dim3(128), 0, stream>>>(Qc, Kc, Vt, mask, attO, SS, SS, QBLK);
    gemm_nt<0,0><<<dim3(EE/BN, MQ/BM), blk, 0, stream>>>(attO, nullptr, ca_wo, ca_bo, xproj, MQ, EE, EE, 1, BB, 1.f, 0);
    ln_kernel<1,0><<<dim3(MQ), blk, 0, stream>>>(hs, xproj, ln1_g, ln1_b, hs1);

    // ---- self-attention ----
    add_qp_kernel<<<dim3(MQ), blk, 0, stream>>>(hs1, qp, xqsa);
    gemm_nt<0,1><<<dim3(EE/BN, MQ/BM), blk, 0, stream>>>(xqsa, nullptr, sa_wq, sa_bq, Qs,  MQ, EE, EE, 1, BB, qscale, 0);
    gemm_nt<0,1><<<dim3(EE/BN, MQ/BM), blk, 0, stream>>>(xqsa, nullptr, sa_wk, sa_bk, Ks2, MQ, EE, EE, 1, BB, 1.f,    0);
    vt_gemm<0><<<dim3(2, EE/BM, BB), blk, 0, stream>>>(hs1, sa_wv, sa_bv, Vt2, TQ, BB, SVT2);
    flash_mfma<<<dim3(BB*HH*QBLK), dim3(128), 0, stream>>>(Qs, Ks2, Vt2, nullptr, attO2, TQ, SVT2, QBLK);
    gemm_nt<0,0><<<dim3(EE/BN, MQ/BM), blk, 0, stream>>>(attO2, nullptr, sa_wo, sa_bo, xpro2, MQ, EE, EE, 1, BB, 1.f, 0);
    ln_kernel<0,0><<<dim3(MQ), blk, 0, stream>>>(hs1, xpro2, ln2_g, ln2_b, hs2);

    // ---- FFN ----
    gemm_nt<0,0><<<dim3(FF/BN, MQ/BM), blk, 0, stream>>>(hs2, nullptr, fc1_w, fc1_b, h1,   MQ, FF, EE, 1, BB, 1.f, 1);
    gemm_nt<0,0><<<dim3(EE/BN, MQ/BM), blk, 0, stream>>>(h1,  nullptr, fc2_w, fc2_b, xffn, MQ, EE, FF, 1, BB, 1.f, 0);
    ln_kernel<0,1><<<dim3(MQ), blk, 0, stream>>>(hs2, xffn, ln3_g, ln3_b, (float*)d_out);

    (void)in_sizes; (void)n_in; (void)out_size; (void)ws_size;
}

// Round 5
// 528.063 us; speedup vs baseline: 9.5769x; 1.1703x over previous
//
#include <hip/hip_runtime.h>
#include <hip/hip_bf16.h>
#include <math.h>

#define TQ 100
#define SS 4096
#define BB 32
#define EE 256
#define HH 8
#define FF 2048
#define DHH 32
#define LNEPS 1e-5f

typedef __attribute__((ext_vector_type(8))) short bf16x8;
typedef __attribute__((ext_vector_type(4))) short bf16x4;
typedef __attribute__((ext_vector_type(4))) float f32x4;

__device__ inline unsigned short f2bfu(float f) {
    __hip_bfloat16 h = __float2bfloat16(f);
    return *reinterpret_cast<unsigned short*>(&h);
}

#define PBM 64
#define PBK 32
#define PLDP 40
#define TLP 268   // epilogue tile row stride in shorts (536B: 8B-aligned, odd-ish dword stride)

// ---------------- weight fp32->bf16 convert ----------------
__global__ __launch_bounds__(256)
void cvt_w(const float* __restrict__ w, __hip_bfloat16* __restrict__ o, int n)
{
    int i = blockIdx.x * 256 + threadIdx.x;
    if (i * 4 < n) {
        float4 v = *(const float4*)(w + i * 4);
        ushort4 ov;
        ov.x = f2bfu(v.x); ov.y = f2bfu(v.y); ov.z = f2bfu(v.z); ov.w = f2bfu(v.w);
        *(ushort4*)((unsigned short*)o + i * 4) = ov;
    }
}

// ---------------- big MFMA projection GEMM (M = BB*SS) ----------------
// A fp32 seq-first gather [(s*BB+b)*EE], optional A2 added. W bf16 [256][256].
// TRANS=0: out[m][256] bf16.  TRANS=1: out[(b*EE+n)*ldo + s] bf16.
// Epilogue goes through LDS so every global store is wave-contiguous (>=64B sectors).
template<int ADD, int TRANS>
__global__ __launch_bounds__(256)
void proj_gemm(const float* __restrict__ A1, const float* __restrict__ A2,
               const __hip_bfloat16* __restrict__ Wb, const float* __restrict__ bias,
               __hip_bfloat16* __restrict__ out, int ldo)
{
    __shared__ short As[PBM][PLDP];
    __shared__ short BsRaw[256 * PLDP];          // 20 KB, reused by epilogue tile
    short (*Bs)[PLDP] = (short(*)[PLDP])BsRaw;
    short (*tile)[TLP] = (short(*)[TLP])BsRaw;   // 32 x 268 shorts = 16.75 KB

    const int tid = threadIdx.x;
    const int m0 = blockIdx.x * PBM;
    const int b = m0 >> 12;
    const int s0 = m0 & (SS - 1);
    const int rr = tid >> 2;
    const int rc = (tid & 3) << 3;
    const long long abase = ((long long)(s0 + rr) * BB + b) * EE + rc;

    const int wv = tid >> 6, l = tid & 63;
    const int wm0 = (wv & 1) * 32, wn0 = (wv >> 1) * 128;
    const int lr16 = l & 15, lk8 = (l >> 4) * 8;

    f32x4 acc[2][8] = {};

    for (int k0 = 0; k0 < EE; k0 += PBK) {
        float4 a0 = *(const float4*)(A1 + abase + k0);
        float4 a1 = *(const float4*)(A1 + abase + k0 + 4);
        if (ADD) {
            float4 e0 = *(const float4*)(A2 + abase + k0);
            float4 e1 = *(const float4*)(A2 + abase + k0 + 4);
            a0.x += e0.x; a0.y += e0.y; a0.z += e0.z; a0.w += e0.w;
            a1.x += e1.x; a1.y += e1.y; a1.z += e1.z; a1.w += e1.w;
        }
        bf16x8 apack;
        apack[0] = (short)f2bfu(a0.x); apack[1] = (short)f2bfu(a0.y);
        apack[2] = (short)f2bfu(a0.z); apack[3] = (short)f2bfu(a0.w);
        apack[4] = (short)f2bfu(a1.x); apack[5] = (short)f2bfu(a1.y);
        apack[6] = (short)f2bfu(a1.z); apack[7] = (short)f2bfu(a1.w);

        bf16x8 wreg[4];
        #pragma unroll
        for (int it = 0; it < 4; ++it)
            wreg[it] = *(const bf16x8*)(Wb + (long long)(rr + it * 64) * EE + k0 + rc);

        __syncthreads();
        *(bf16x8*)&As[rr][rc] = apack;
        #pragma unroll
        for (int it = 0; it < 4; ++it)
            *(bf16x8*)&Bs[rr + it * 64][rc] = wreg[it];
        __syncthreads();

        bf16x8 af0 = *(const bf16x8*)&As[wm0 + lr16][lk8];
        bf16x8 af1 = *(const bf16x8*)&As[wm0 + 16 + lr16][lk8];
        #pragma unroll
        for (int j = 0; j < 8; ++j) {
            bf16x8 bfr = *(const bf16x8*)&Bs[wn0 + j * 16 + lr16][lk8];
            acc[0][j] = __builtin_amdgcn_mfma_f32_16x16x32_bf16(af0, bfr, acc[0][j], 0, 0, 0);
            acc[1][j] = __builtin_amdgcn_mfma_f32_16x16x32_bf16(af1, bfr, acc[1][j], 0, 0, 0);
        }
    }

    // -------- LDS-staged epilogue, two half-passes of 32 rows --------
    const int q4 = (l >> 4) * 4;
    #pragma unroll
    for (int h = 0; h < 2; ++h) {
        __syncthreads();
        if (wm0 == h * 32) {
            #pragma unroll
            for (int i = 0; i < 2; ++i) {
                #pragma unroll
                for (int j = 0; j < 8; ++j) {
                    const int n = wn0 + j * 16 + lr16;
                    const float bi = bias[n];
                    #pragma unroll
                    for (int r = 0; r < 4; ++r)
                        tile[i * 16 + q4 + r][n] = (short)f2bfu(acc[i][j][r] + bi);
                }
            }
        }
        __syncthreads();
        if (TRANS == 0) {
            // 32 rows x 256 cols; each wave drains 8 rows, 64 lanes x 8B per row
            #pragma unroll
            for (int it = 0; it < 8; ++it) {
                const int r2 = wv * 8 + it;
                ushort4 v = *(const ushort4*)&tile[r2][l * 4];
                *(ushort4*)(out + (long long)(m0 + h * 32 + r2) * EE + l * 4) = v;
            }
        } else {
            // V^T: wave w covers n = w*64..w*64+63; per iter 2 n-rows x 32 s (64B each)
            #pragma unroll
            for (int nn = 0; nn < 32; ++nn) {
                const int n = wv * 64 + nn * 2 + (l >> 5);
                const int s = l & 31;
                unsigned short v = (unsigned short)tile[s][n];
                *(unsigned short*)((unsigned short*)out + (long long)(b * EE + n) * ldo + s0 + h * 32 + s) = v;
            }
        }
    }
}

// ---------------- general MFMA GEMM for M=3200 ----------------
// A1G: A1 rows gathered seq-first (t*BB+b). A2Q: add qp (gathered) to A. A1BF: A1 is bf16.
// OBF: bf16 out else fp32. RELU. out row stride = N. scale applied after bias.
template<int A1G, int A2Q, int A1BF, int OBF, int RELU>
__global__ __launch_bounds__(256)
void mfma_gemm(const void* __restrict__ A1v, const float* __restrict__ A2,
               const __hip_bfloat16* __restrict__ Wb, const float* __restrict__ bias,
               void* __restrict__ outv, int N, int K, float scale)
{
    __shared__ short As[PBM][PLDP];
    __shared__ short Bs[256][PLDP];
    const int tid = threadIdx.x;
    const int m0 = blockIdx.x * PBM;
    const int n0 = blockIdx.y * 256;
    const int rr = tid >> 2;
    const int rc = (tid & 3) << 3;
    const int row = m0 + rr;

    long long a2row = 0;
    if (A1G || A2Q) {
        int bq = row / TQ, tq = row - bq * TQ;
        a2row = ((long long)(tq * BB + bq)) * EE;
    }
    const long long a1row = A1G ? a2row : (long long)row * K;

    const int wv = tid >> 6, l = tid & 63;
    const int wm0 = (wv & 1) * 32, wn0 = (wv >> 1) * 128;
    const int lr16 = l & 15, lk8 = (l >> 4) * 8;

    f32x4 acc[2][8] = {};

    for (int k0 = 0; k0 < K; k0 += PBK) {
        bf16x8 apack;
        if (A1BF) {
            apack = *(const bf16x8*)((const __hip_bfloat16*)A1v + a1row + k0 + rc);
        } else {
            const float* A1 = (const float*)A1v;
            float4 a0 = *(const float4*)(A1 + a1row + k0 + rc);
            float4 a1 = *(const float4*)(A1 + a1row + k0 + rc + 4);
            if (A2Q) {
                float4 e0 = *(const float4*)(A2 + a2row + k0 + rc);
                float4 e1 = *(const float4*)(A2 + a2row + k0 + rc + 4);
                a0.x += e0.x; a0.y += e0.y; a0.z += e0.z; a0.w += e0.w;
                a1.x += e1.x; a1.y += e1.y; a1.z += e1.z; a1.w += e1.w;
            }
            apack[0] = (short)f2bfu(a0.x); apack[1] = (short)f2bfu(a0.y);
            apack[2] = (short)f2bfu(a0.z); apack[3] = (short)f2bfu(a0.w);
            apack[4] = (short)f2bfu(a1.x); apack[5] = (short)f2bfu(a1.y);
            apack[6] = (short)f2bfu(a1.z); apack[7] = (short)f2bfu(a1.w);
        }

        bf16x8 wreg[4];
        #pragma unroll
        for (int it = 0; it < 4; ++it)
            wreg[it] = *(const bf16x8*)(Wb + (long long)(n0 + rr + it * 64) * K + k0 + rc);

        __syncthreads();
        *(bf16x8*)&As[rr][rc] = apack;
        #pragma unroll
        for (int it = 0; it < 4; ++it)
            *(bf16x8*)&Bs[rr + it * 64][rc] = wreg[it];
        __syncthreads();

        bf16x8 af0 = *(const bf16x8*)&As[wm0 + lr16][lk8];
        bf16x8 af1 = *(const bf16x8*)&As[wm0 + 16 + lr16][lk8];
        #pragma unroll
        for (int j = 0; j < 8; ++j) {
            bf16x8 bfr = *(const bf16x8*)&Bs[wn0 + j * 16 + lr16][lk8];
            acc[0][j] = __builtin_amdgcn_mfma_f32_16x16x32_bf16(af0, bfr, acc[0][j], 0, 0, 0);
            acc[1][j] = __builtin_amdgcn_mfma_f32_16x16x32_bf16(af1, bfr, acc[1][j], 0, 0, 0);
        }
    }

    const int q4 = (l >> 4) * 4;
    #pragma unroll
    for (int i = 0; i < 2; ++i) {
        #pragma unroll
        for (int j = 0; j < 8; ++j) {
            const int n = wn0 + j * 16 + lr16;
            const float bi = bias[n0 + n];
            #pragma unroll
            for (int r = 0; r < 4; ++r) {
                float v = (acc[i][j][r] + bi) * scale;
                if (RELU) v = fmaxf(v, 0.f);
                const long long oidx = (long long)(m0 + wm0 + i * 16 + q4 + r) * N + n0 + n;
                if (OBF) ((__hip_bfloat16*)outv)[oidx] = __float2bfloat16(v);
                else     ((float*)outv)[oidx] = v;
            }
        }
    }
}

// ---------------- small V^T fp32 GEMM (SA only) ----------------
#define BM 64
#define BN 64
#define BKT 16
#define APAD 4
__global__ __launch_bounds__(256)
void vt_gemm(const float* __restrict__ X, const float* __restrict__ W,
             const float* __restrict__ bias, __hip_bfloat16* __restrict__ Ct,
             int SD, int SVT)
{
    __shared__ float Ws[BKT][BM + APAD];
    __shared__ float Xs[BKT][BN + APAD];
    const int tid = threadIdx.x;
    const int tx = tid & 15, ty = tid >> 4;
    const int s0 = blockIdx.x * BN, n0 = blockIdx.y * BM;
    const int b  = blockIdx.z;
    const int lr = tid >> 2, lc = (tid & 3) << 2;

    const long long wrow = (long long)(n0 + lr) * EE;
    int srow = s0 + lr; if (srow >= SD) srow = SD - 1;
    const long long xrow = ((long long)b * SD + srow) * EE;

    float acc[4][4] = {};
    for (int k0 = 0; k0 < EE; k0 += BKT) {
        float4 wv = *(const float4*)(W + wrow + k0 + lc);
        float4 xv = *(const float4*)(X + xrow + k0 + lc);
        __syncthreads();
        Ws[lc+0][lr] = wv.x; Ws[lc+1][lr] = wv.y; Ws[lc+2][lr] = wv.z; Ws[lc+3][lr] = wv.w;
        Xs[lc+0][lr] = xv.x; Xs[lc+1][lr] = xv.y; Xs[lc+2][lr] = xv.z; Xs[lc+3][lr] = xv.w;
        __syncthreads();
        #pragma unroll
        for (int kk = 0; kk < BKT; ++kk) {
            float a4[4], b4[4];
            #pragma unroll
            for (int i = 0; i < 4; ++i) a4[i] = Ws[kk][ty*4 + i];
            #pragma unroll
            for (int j = 0; j < 4; ++j) b4[j] = Xs[kk][tx*4 + j];
            #pragma unroll
            for (int i = 0; i < 4; ++i)
                #pragma unroll
                for (int j = 0; j < 4; ++j)
                    acc[i][j] += a4[i] * b4[j];
        }
    }

    #pragma unroll
    for (int i = 0; i < 4; ++i) {
        const int n = n0 + ty*4 + i;
        const float bi = bias[n];
        const int s = s0 + tx*4;
        __hip_bfloat16* dst = Ct + (long long)(b * EE + n) * SVT + s;
        if (s + 3 < SD) {
            ushort4 ov;
            ov.x = f2bfu(acc[i][0] + bi); ov.y = f2bfu(acc[i][1] + bi);
            ov.z = f2bfu(acc[i][2] + bi); ov.w = f2bfu(acc[i][3] + bi);
            *(ushort4*)dst = ov;
        } else {
            #pragma unroll
            for (int j = 0; j < 4; ++j)
                if (s + j < SD) dst[j] = __float2bfloat16(acc[i][j] + bi);
        }
    }
}

// ---------------- MFMA flash attention ----------------
#define KVB 32
#define LDP 40

__global__ __launch_bounds__(128, 4)
void flash_mfma(const __hip_bfloat16* __restrict__ Qg,
                const __hip_bfloat16* __restrict__ Kg,
                const __hip_bfloat16* __restrict__ Vtg,
                const float* __restrict__ mask,
                float* __restrict__ O,
                int Skv, int SVT, int qblocks)
{
    __shared__ short Ks[2][KVB][LDP];
    __shared__ short Vs[2][KVB][LDP];
    const int tid = threadIdx.x;
    const int l = tid & 63;
    const int g = l >> 4, q16 = l & 15;
    const int qb = blockIdx.x % qblocks;
    const int bh = blockIdx.x / qblocks;
    const int h = bh & (HH - 1), b = bh >> 3;
    const int q0 = qb * 32 + (tid >> 6) * 16;

    int qc = q0 + q16; if (qc >= TQ) qc = TQ - 1;
    const bf16x8 qfrag = *(const bf16x8*)(Qg + ((long long)(b * TQ + qc)) * EE + h * DHH + g * 8);

    const int srow = tid >> 2;
    const int sseg = (tid & 3) * 8;
    const long long kbase = ((long long)b * Skv) * EE + h * DHH;
    const long long vbase = ((long long)(b * EE + h * DHH)) * SVT;
    const float* mrowp = mask ? mask + ((long long)bh * TQ + qc) * Skv : nullptr;

    f32x4 oacc[2] = {{0.f,0.f,0.f,0.f},{0.f,0.f,0.f,0.f}};
    float mrun = -1e30f, lrun = 0.f;
    const f32x4 zero = {0.f,0.f,0.f,0.f};

    int s_ld = srow; if (s_ld >= Skv) s_ld = Skv - 1;
    bf16x8 kreg = *(const bf16x8*)(Kg + kbase + (long long)s_ld * EE + sseg);
    bf16x8 vreg = *(const bf16x8*)(Vtg + vbase + (long long)srow * SVT + sseg);

    const int nround = (Skv + KVB - 1) / KVB;
    for (int r = 0; r < nround; ++r) {
        const int buf = r & 1;
        *(bf16x8*)&Ks[buf][srow][sseg] = kreg;
        *(bf16x8*)&Vs[buf][srow][sseg] = vreg;
        if (r + 1 < nround) {
            int sn = (r + 1) * KVB + srow; if (sn >= Skv) sn = Skv - 1;
            kreg = *(const bf16x8*)(Kg + kbase + (long long)sn * EE + sseg);
            vreg = *(const bf16x8*)(Vtg + vbase + (long long)srow * SVT + (r + 1) * KVB + sseg);
        }
        __syncthreads();

        const int s0 = r * KVB;
        f32x4 sT[2];
        #pragma unroll
        for (int t = 0; t < 2; ++t) {
            bf16x8 kf = *(const bf16x8*)&Ks[buf][t * 16 + q16][g * 8];
            sT[t] = __builtin_amdgcn_mfma_f32_16x16x32_bf16(kf, qfrag, zero, 0, 0, 0);
        }
        float sc[8];
        if (mrowp) {
            #pragma unroll
            for (int t = 0; t < 2; ++t) {
                float4 mk = *(const float4*)(mrowp + s0 + t * 16 + g * 4);
                sc[t*4+0] = sT[t][0] + mk.x; sc[t*4+1] = sT[t][1] + mk.y;
                sc[t*4+2] = sT[t][2] + mk.z; sc[t*4+3] = sT[t][3] + mk.w;
            }
        } else {
            #pragma unroll
            for (int t = 0; t < 2; ++t)
                #pragma unroll
                for (int rg = 0; rg < 4; ++rg) {
                    int s = s0 + t * 16 + g * 4 + rg;
                    sc[t*4+rg] = (s < Skv) ? sT[t][rg] : -1e30f;
                }
        }
        float tmax = sc[0];
        #pragma unroll
        for (int i = 1; i < 8; ++i) tmax = fmaxf(tmax, sc[i]);
        tmax = fmaxf(tmax, __shfl_xor(tmax, 16));
        tmax = fmaxf(tmax, __shfl_xor(tmax, 32));
        const float mn = fmaxf(mrun, tmax);
        const float corr = __expf(mrun - mn);
        mrun = mn;
        float ps = 0.f;
        bf16x8 pfrag;
        #pragma unroll
        for (int i = 0; i < 8; ++i) {
            float p = __expf(sc[i] - mn);
            ps += p;
            pfrag[i] = (short)f2bfu(p);
        }
        ps += __shfl_xor(ps, 16);
        ps += __shfl_xor(ps, 32);
        lrun = lrun * corr + ps;
        #pragma unroll
        for (int rg = 0; rg < 4; ++rg) {
            float c = __shfl(corr, g * 4 + rg);
            oacc[0][rg] *= c;
            oacc[1][rg] *= c;
        }
        #pragma unroll
        for (int T = 0; T < 2; ++T) {
            bf16x4 v0 = *(const bf16x4*)&Vs[buf][T * 16 + q16][g * 4];
            bf16x4 v1 = *(const bf16x4*)&Vs[buf][T * 16 + q16][16 + g * 4];
            bf16x8 vf;
            vf[0] = v0[0]; vf[1] = v0[1]; vf[2] = v0[2]; vf[3] = v0[3];
            vf[4] = v1[0]; vf[5] = v1[1]; vf[6] = v1[2]; vf[7] = v1[3];
            oacc[T] = __builtin_amdgcn_mfma_f32_16x16x32_bf16(pfrag, vf, oacc[T], 0, 0, 0);
        }
        __syncthreads();
    }

    float linv[4];
    #pragma unroll
    for (int rg = 0; rg < 4; ++rg)
        linv[rg] = 1.f / __shfl(lrun, g * 4 + rg);
    #pragma unroll
    for (int rg = 0; rg < 4; ++rg) {
        const int q = q0 + g * 4 + rg;
        if (q < TQ) {
            float* op = O + ((long long)(b * TQ + q)) * EE + h * DHH + q16;
            op[0]  = oacc[0][rg] * linv[rg];
            op[16] = oacc[1][rg] * linv[rg];
        }
    }
}

// ---------------- LayerNorm ----------------
// OUT_BF: additionally write bf16 copy to outb.
template<int GATHER_RES, int OUT_T, int OUT_BF>
__global__ __launch_bounds__(256)
void ln_kernel(const float* __restrict__ res, const float* __restrict__ x,
               const float* __restrict__ gam, const float* __restrict__ bet,
               float* __restrict__ out, __hip_bfloat16* __restrict__ outb)
{
    __shared__ float r1[4], r2[4];
    const int m = blockIdx.x;
    const int k = threadIdx.x;
    const int b = m / TQ, t = m - b * TQ;
    const long long roff = GATHER_RES ? ((long long)(t * BB + b)) * EE : (long long)m * EE;
    float v = res[roff + k] + x[(long long)m * EE + k];
    float s = v;
    #pragma unroll
    for (int off = 32; off; off >>= 1) s += __shfl_down(s, off);
    if ((k & 63) == 0) r1[k >> 6] = s;
    __syncthreads();
    const float mu = (r1[0] + r1[1] + r1[2] + r1[3]) * (1.0f / EE);
    const float d = v - mu;
    float s2 = d * d;
    #pragma unroll
    for (int off = 32; off; off >>= 1) s2 += __shfl_down(s2, off);
    if ((k & 63) == 0) r2[k >> 6] = s2;
    __syncthreads();
    const float var = (r2[0] + r2[1] + r2[2] + r2[3]) * (1.0f / EE);
    const float o = d * rsqrtf(var + LNEPS) * gam[k] + bet[k];
    const long long ooff = OUT_T ? ((long long)(t * BB + b)) * EE : (long long)m * EE;
    out[ooff + k] = o;
    if (OUT_BF) outb[(long long)m * EE + k] = __float2bfloat16(o);
}

extern "C" void kernel_launch(void* const* d_in, const int* in_sizes, int n_in,
                              void* d_out, int out_size, void* d_ws, size_t ws_size,
                              hipStream_t stream)
{
    const float* hs    = (const float*)d_in[0];
    const float* qp    = (const float*)d_in[1];
    const float* enc   = (const float*)d_in[2];
    const float* ep    = (const float*)d_in[3];
    const float* mask  = (const float*)d_in[4];
    const float* ca_wq = (const float*)d_in[5];  const float* ca_bq = (const float*)d_in[6];
    const float* ca_wk = (const float*)d_in[7];  const float* ca_bk = (const float*)d_in[8];
    const float* ca_wv = (const float*)d_in[9];  const float* ca_bv = (const float*)d_in[10];
    const float* ca_wo = (const float*)d_in[11]; const float* ca_bo = (const float*)d_in[12];
    const float* sa_wq = (const float*)d_in[13]; const float* sa_bq = (const float*)d_in[14];
    const float* sa_wk = (const float*)d_in[15]; const float* sa_bk = (const float*)d_in[16];
    const float* sa_wv = (const float*)d_in[17]; const float* sa_bv = (const float*)d_in[18];
    const float* sa_wo = (const float*)d_in[19]; const float* sa_bo = (const float*)d_in[20];
    const float* ln1_g = (const float*)d_in[21]; const float* ln1_b = (const float*)d_in[22];
    const float* ln2_g = (const float*)d_in[23]; const float* ln2_b = (const float*)d_in[24];
    const float* ln3_g = (const float*)d_in[25]; const float* ln3_b = (const float*)d_in[26];
    const float* fc1_w = (const float*)d_in[27]; const float* fc1_b = (const float*)d_in[28];
    const float* fc2_w = (const float*)d_in[29]; const float* fc2_b = (const float*)d_in[30];

    const int MQ = BB * TQ;   // 3200
    const int MK = BB * SS;   // 131072
    const int SVT2 = 128;

    size_t off = 0;
    char* base = (char*)d_ws;
    auto alloc = [&](size_t bytes) -> void* {
        void* p = base + off; off = (off + bytes + 255) & ~(size_t)255; return p;
    };
    __hip_bfloat16* Kc  = (__hip_bfloat16*)alloc((size_t)MK * EE * 2);
    __hip_bfloat16* Vt  = (__hip_bfloat16*)alloc((size_t)BB * EE * SS * 2);
    __hip_bfloat16* Qc  = (__hip_bfloat16*)alloc((size_t)MQ * EE * 2);
    __hip_bfloat16* Qs  = (__hip_bfloat16*)alloc((size_t)MQ * EE * 2);
    __hip_bfloat16* Ks2 = (__hip_bfloat16*)alloc((size_t)MQ * EE * 2);
    __hip_bfloat16* Vt2 = (__hip_bfloat16*)alloc((size_t)BB * EE * SVT2 * 2);
    __hip_bfloat16* Wq1 = (__hip_bfloat16*)alloc((size_t)EE * EE * 2);
    __hip_bfloat16* Wkb = (__hip_bfloat16*)alloc((size_t)EE * EE * 2);
    __hip_bfloat16* Wvb = (__hip_bfloat16*)alloc((size_t)EE * EE * 2);
    __hip_bfloat16* Wo1 = (__hip_bfloat16*)alloc((size_t)EE * EE * 2);
    __hip_bfloat16* Wq2 = (__hip_bfloat16*)alloc((size_t)EE * EE * 2);
    __hip_bfloat16* Wk2 = (__hip_bfloat16*)alloc((size_t)EE * EE * 2);
    __hip_bfloat16* Wo2 = (__hip_bfloat16*)alloc((size_t)EE * EE * 2);
    __hip_bfloat16* Wf1 = (__hip_bfloat16*)alloc((size_t)FF * EE * 2);
    __hip_bfloat16* Wf2 = (__hip_bfloat16*)alloc((size_t)EE * FF * 2);
    __hip_bfloat16* hs2b= (__hip_bfloat16*)alloc((size_t)MQ * EE * 2);
    __hip_bfloat16* h1b = (__hip_bfloat16*)alloc((size_t)MQ * FF * 2);
    float* attO  = (float*)alloc((size_t)MQ * EE * 4);
    float* xproj = (float*)alloc((size_t)MQ * EE * 4);
    float* hs1   = (float*)alloc((size_t)MQ * EE * 4);
    float* attO2 = (float*)alloc((size_t)MQ * EE * 4);
    float* xpro2 = (float*)alloc((size_t)MQ * EE * 4);
    float* hs2   = (float*)alloc((size_t)MQ * EE * 4);
    float* xffn  = (float*)alloc((size_t)MQ * EE * 4);

    const float qscale = 0.17677669529663687f;
    dim3 blk(256);
    const int QBLK = 4;

    // weights -> bf16
    cvt_w<<<dim3(64,1,1),  blk, 0, stream>>>(ca_wq, Wq1, EE*EE);
    cvt_w<<<dim3(64,1,1),  blk, 0, stream>>>(ca_wk, Wkb, EE*EE);
    cvt_w<<<dim3(64,1,1),  blk, 0, stream>>>(ca_wv, Wvb, EE*EE);
    cvt_w<<<dim3(64,1,1),  blk, 0, stream>>>(ca_wo, Wo1, EE*EE);
    cvt_w<<<dim3(64,1,1),  blk, 0, stream>>>(sa_wq, Wq2, EE*EE);
    cvt_w<<<dim3(64,1,1),  blk, 0, stream>>>(sa_wk, Wk2, EE*EE);
    cvt_w<<<dim3(64,1,1),  blk, 0, stream>>>(sa_wo, Wo2, EE*EE);
    cvt_w<<<dim3(512,1,1), blk, 0, stream>>>(fc1_w, Wf1, FF*EE);
    cvt_w<<<dim3(512,1,1), blk, 0, stream>>>(fc2_w, Wf2, EE*FF);

    // ---- cross-attention ----
    mfma_gemm<1,1,0,1,0><<<dim3(MQ/64, 1), blk, 0, stream>>>(hs, qp, Wq1, ca_bq, Qc, EE, EE, qscale);
    proj_gemm<1,0><<<dim3(MK/PBM), blk, 0, stream>>>(enc, ep,      Wkb, ca_bk, Kc, EE);
    proj_gemm<0,1><<<dim3(MK/PBM), blk, 0, stream>>>(enc, nullptr, Wvb, ca_bv, Vt, SS);
    flash_mfma<<<dim3(BB*HH*QBLK), dim3(128), 0, stream>>>(Qc, Kc, Vt, mask, attO, SS, SS, QBLK);
    mfma_gemm<0,0,0,0,0><<<dim3(MQ/64, 1), blk, 0, stream>>>(attO, nullptr, Wo1, ca_bo, xproj, EE, EE, 1.f);
    ln_kernel<1,0,0><<<dim3(MQ), blk, 0, stream>>>(hs, xproj, ln1_g, ln1_b, hs1, nullptr);

    // ---- self-attention ----
    mfma_gemm<0,1,0,1,0><<<dim3(MQ/64, 1), blk, 0, stream>>>(hs1, qp, Wq2, sa_bq, Qs,  EE, EE, qscale);
    mfma_gemm<0,1,0,1,0><<<dim3(MQ/64, 1), blk, 0, stream>>>(hs1, qp, Wk2, sa_bk, Ks2, EE, EE, 1.f);
    vt_gemm<<<dim3(2, EE/BM, BB), blk, 0, stream>>>(hs1, sa_wv, sa_bv, Vt2, TQ, SVT2);
    flash_mfma<<<dim3(BB*HH*QBLK), dim3(128), 0, stream>>>(Qs, Ks2, Vt2, nullptr, attO2, TQ, SVT2, QBLK);
    mfma_gemm<0,0,0,0,0><<<dim3(MQ/64, 1), blk, 0, stream>>>(attO2, nullptr, Wo2, sa_bo, xpro2, EE, EE, 1.f);
    ln_kernel<0,0,1><<<dim3(MQ), blk, 0, stream>>>(hs1, xpro2, ln2_g, ln2_b, hs2, hs2b);

    // ---- FFN ----
    mfma_gemm<0,0,1,1,1><<<dim3(MQ/64, FF/256), blk, 0, stream>>>(hs2b, nullptr, Wf1, fc1_b, h1b, FF, EE, 1.f);
    mfma_gemm<0,0,1,0,0><<<dim3(MQ/64, 1), blk, 0, stream>>>(h1b, nullptr, Wf2, fc2_b, xffn, EE, FF, 1.f);
    ln_kernel<0,1,0><<<dim3(MQ), blk, 0, stream>>>(hs2, xffn, ln3_g, ln3_b, (float*)d_out, nullptr);

    (void)in_sizes; (void)n_in; (void)out_size; (void)ws_size;
}

// Round 6
// 513.566 us; speedup vs baseline: 9.8472x; 1.0282x over previous
//
#include <hip/hip_runtime.h>
#include <hip/hip_bf16.h>
#include <math.h>

#define TQ 100
#define SS 4096
#define BB 32
#define EE 256
#define HH 8
#define FF 2048
#define DHH 32
#define LNEPS 1e-5f

typedef __attribute__((ext_vector_type(8))) short bf16x8;
typedef __attribute__((ext_vector_type(4))) short bf16x4;
typedef __attribute__((ext_vector_type(4))) float f32x4;

__device__ inline unsigned short f2bfu(float f) {
    __hip_bfloat16 h = __float2bfloat16(f);
    return *reinterpret_cast<unsigned short*>(&h);
}

#define PBM 64
#define PBK 32
#define PLDP 40
#define TLP 268

// ---------------- fused weight fp32->bf16 convert (9 segments, 1 launch) ----------------
// segments 0..6: 65536 elems (E*E), segments 7..8: 524288 (F*E). Block-uniform pick.
__global__ __launch_bounds__(256)
void cvt_all(const float* s0, const float* s1, const float* s2, const float* s3,
             const float* s4, const float* s5, const float* s6, const float* s7,
             const float* s8,
             unsigned short* d0, unsigned short* d1, unsigned short* d2, unsigned short* d3,
             unsigned short* d4, unsigned short* d5, unsigned short* d6, unsigned short* d7,
             unsigned short* d8)
{
    const int bi = blockIdx.x;
    const float* s; unsigned short* d; int base;
    if (bi < 448) {
        const int seg = bi >> 6;
        base = (bi & 63) * 1024;
        switch (seg) {
            case 0: s = s0; d = d0; break;
            case 1: s = s1; d = d1; break;
            case 2: s = s2; d = d2; break;
            case 3: s = s3; d = d3; break;
            case 4: s = s4; d = d4; break;
            case 5: s = s5; d = d5; break;
            default: s = s6; d = d6; break;
        }
    } else {
        const int r = bi - 448;
        base = (r & 511) * 1024;
        if (r >> 9) { s = s8; d = d8; } else { s = s7; d = d7; }
    }
    const int i = base + threadIdx.x * 4;
    float4 v = *(const float4*)(s + i);
    ushort4 ov;
    ov.x = f2bfu(v.x); ov.y = f2bfu(v.y); ov.z = f2bfu(v.z); ov.w = f2bfu(v.w);
    *(ushort4*)(d + i) = ov;
}

// ---------------- fused K + V^T projection (M = BB*SS) ----------------
// K[m][n] = (enc+ep)@Wk^T + bk  (rows layout, m = b*SS+s)
// Vt[(b*EE+n)*SS + s] = enc@Wv^T + bv  (transposed layout)
__global__ __launch_bounds__(256)
void proj_kv(const float* __restrict__ enc, const float* __restrict__ ep,
             const __hip_bfloat16* __restrict__ Wk, const float* __restrict__ bk,
             const __hip_bfloat16* __restrict__ Wv, const float* __restrict__ bv,
             __hip_bfloat16* __restrict__ Kout, __hip_bfloat16* __restrict__ Vtout)
{
    __shared__ short Akv[PBM][PLDP];
    __shared__ short Av[PBM][PLDP];
    __shared__ short BkRaw[256 * PLDP];
    __shared__ short BvRaw[256 * PLDP];
    short (*Bk)[PLDP] = (short(*)[PLDP])BkRaw;
    short (*Bv)[PLDP] = (short(*)[PLDP])BvRaw;
    short (*tk)[TLP] = (short(*)[TLP])BkRaw;
    short (*tv)[TLP] = (short(*)[TLP])BvRaw;

    const int tid = threadIdx.x;
    const int m0 = blockIdx.x * PBM;
    const int b = m0 >> 12;
    const int s0 = m0 & (SS - 1);
    const int rr = tid >> 2;
    const int rc = (tid & 3) << 3;
    const long long abase = ((long long)(s0 + rr) * BB + b) * EE + rc;

    const int wv = tid >> 6, l = tid & 63;
    const int wm0 = (wv & 1) * 32, wn0 = (wv >> 1) * 128;
    const int lr16 = l & 15, lk8 = (l >> 4) * 8;

    f32x4 acck[2][8] = {};
    f32x4 accv[2][8] = {};

    for (int k0 = 0; k0 < EE; k0 += PBK) {
        float4 a0 = *(const float4*)(enc + abase + k0);
        float4 a1 = *(const float4*)(enc + abase + k0 + 4);
        float4 e0 = *(const float4*)(ep + abase + k0);
        float4 e1 = *(const float4*)(ep + abase + k0 + 4);
        bf16x8 pv, pkv;
        pv[0] = (short)f2bfu(a0.x); pv[1] = (short)f2bfu(a0.y);
        pv[2] = (short)f2bfu(a0.z); pv[3] = (short)f2bfu(a0.w);
        pv[4] = (short)f2bfu(a1.x); pv[5] = (short)f2bfu(a1.y);
        pv[6] = (short)f2bfu(a1.z); pv[7] = (short)f2bfu(a1.w);
        pkv[0] = (short)f2bfu(a0.x + e0.x); pkv[1] = (short)f2bfu(a0.y + e0.y);
        pkv[2] = (short)f2bfu(a0.z + e0.z); pkv[3] = (short)f2bfu(a0.w + e0.w);
        pkv[4] = (short)f2bfu(a1.x + e1.x); pkv[5] = (short)f2bfu(a1.y + e1.y);
        pkv[6] = (short)f2bfu(a1.z + e1.z); pkv[7] = (short)f2bfu(a1.w + e1.w);

        bf16x8 wkr[4], wvr[4];
        #pragma unroll
        for (int it = 0; it < 4; ++it) {
            wkr[it] = *(const bf16x8*)(Wk + (long long)(rr + it * 64) * EE + k0 + rc);
            wvr[it] = *(const bf16x8*)(Wv + (long long)(rr + it * 64) * EE + k0 + rc);
        }

        __syncthreads();
        *(bf16x8*)&Akv[rr][rc] = pkv;
        *(bf16x8*)&Av[rr][rc]  = pv;
        #pragma unroll
        for (int it = 0; it < 4; ++it) {
            *(bf16x8*)&Bk[rr + it * 64][rc] = wkr[it];
            *(bf16x8*)&Bv[rr + it * 64][rc] = wvr[it];
        }
        __syncthreads();

        bf16x8 ak0 = *(const bf16x8*)&Akv[wm0 + lr16][lk8];
        bf16x8 ak1 = *(const bf16x8*)&Akv[wm0 + 16 + lr16][lk8];
        bf16x8 av0 = *(const bf16x8*)&Av[wm0 + lr16][lk8];
        bf16x8 av1 = *(const bf16x8*)&Av[wm0 + 16 + lr16][lk8];
        #pragma unroll
        for (int j = 0; j < 8; ++j) {
            bf16x8 bk8 = *(const bf16x8*)&Bk[wn0 + j * 16 + lr16][lk8];
            bf16x8 bv8 = *(const bf16x8*)&Bv[wn0 + j * 16 + lr16][lk8];
            acck[0][j] = __builtin_amdgcn_mfma_f32_16x16x32_bf16(ak0, bk8, acck[0][j], 0, 0, 0);
            acck[1][j] = __builtin_amdgcn_mfma_f32_16x16x32_bf16(ak1, bk8, acck[1][j], 0, 0, 0);
            accv[0][j] = __builtin_amdgcn_mfma_f32_16x16x32_bf16(av0, bv8, accv[0][j], 0, 0, 0);
            accv[1][j] = __builtin_amdgcn_mfma_f32_16x16x32_bf16(av1, bv8, accv[1][j], 0, 0, 0);
        }
    }

    const int q4 = (l >> 4) * 4;
    #pragma unroll
    for (int h = 0; h < 2; ++h) {
        __syncthreads();
        if (wm0 == h * 32) {
            #pragma unroll
            for (int i = 0; i < 2; ++i) {
                #pragma unroll
                for (int j = 0; j < 8; ++j) {
                    const int n = wn0 + j * 16 + lr16;
                    const float bik = bk[n], biv = bv[n];
                    #pragma unroll
                    for (int r = 0; r < 4; ++r) {
                        tk[i * 16 + q4 + r][n] = (short)f2bfu(acck[i][j][r] + bik);
                        tv[i * 16 + q4 + r][n] = (short)f2bfu(accv[i][j][r] + biv);
                    }
                }
            }
        }
        __syncthreads();
        // drain K rows: 32 rows x 256 cols, wave drains 8 rows (64 lanes x 8B)
        #pragma unroll
        for (int it = 0; it < 8; ++it) {
            const int r2 = wv * 8 + it;
            ushort4 v = *(const ushort4*)&tk[r2][l * 4];
            *(ushort4*)(Kout + (long long)(m0 + h * 32 + r2) * EE + l * 4) = v;
        }
        // drain V^T: wave w covers n = w*64..+63; 2 n-rows x 32 s (64B) per iter
        #pragma unroll
        for (int nn = 0; nn < 32; ++nn) {
            const int n = wv * 64 + nn * 2 + (l >> 5);
            const int s = l & 31;
            unsigned short v = (unsigned short)tv[s][n];
            *((unsigned short*)Vtout + (long long)(b * EE + n) * SS + s0 + h * 32 + s) = v;
        }
    }
}

// ---------------- small MFMA GEMM: 32m x 128n tile, 128 threads ----------------
// A1G: A rows gathered seq-first (t*BB+b). A2Q: add qp (gathered). A1BF: A is bf16.
// OBF: bf16 out else fp32. RELU. scale applied after bias.
template<int A1G, int A2Q, int A1BF, int OBF, int RELU>
__global__ __launch_bounds__(128)
void mfma_gemm2(const void* __restrict__ A1v, const float* __restrict__ A2,
                const __hip_bfloat16* __restrict__ Wb, const float* __restrict__ bias,
                void* __restrict__ outv, int N, int K, float scale)
{
    __shared__ short As[32][PLDP];
    __shared__ short Bs[128][PLDP];
    const int tid = threadIdx.x;
    const int m0 = blockIdx.x * 32;
    const int n0 = blockIdx.y * 128;
    const int rr = tid >> 2;
    const int rc = (tid & 3) << 3;
    const int row = m0 + rr;

    long long a2row = 0;
    if (A1G || A2Q) {
        int bq = row / TQ, tq = row - bq * TQ;
        a2row = ((long long)(tq * BB + bq)) * EE;
    }
    const long long a1row = A1G ? a2row : (long long)row * K;

    const int wv = tid >> 6, l = tid & 63;
    const int wm0 = wv * 16;
    const int lr16 = l & 15, lk8 = (l >> 4) * 8;

    f32x4 acc[8] = {};

    for (int k0 = 0; k0 < K; k0 += PBK) {
        bf16x8 apack;
        if (A1BF) {
            apack = *(const bf16x8*)((const __hip_bfloat16*)A1v + a1row + k0 + rc);
        } else {
            const float* A1 = (const float*)A1v;
            float4 a0 = *(const float4*)(A1 + a1row + k0 + rc);
            float4 a1 = *(const float4*)(A1 + a1row + k0 + rc + 4);
            if (A2Q) {
                float4 e0 = *(const float4*)(A2 + a2row + k0 + rc);
                float4 e1 = *(const float4*)(A2 + a2row + k0 + rc + 4);
                a0.x += e0.x; a0.y += e0.y; a0.z += e0.z; a0.w += e0.w;
                a1.x += e1.x; a1.y += e1.y; a1.z += e1.z; a1.w += e1.w;
            }
            apack[0] = (short)f2bfu(a0.x); apack[1] = (short)f2bfu(a0.y);
            apack[2] = (short)f2bfu(a0.z); apack[3] = (short)f2bfu(a0.w);
            apack[4] = (short)f2bfu(a1.x); apack[5] = (short)f2bfu(a1.y);
            apack[6] = (short)f2bfu(a1.z); apack[7] = (short)f2bfu(a1.w);
        }

        bf16x8 wreg[4];
        #pragma unroll
        for (int it = 0; it < 4; ++it)
            wreg[it] = *(const bf16x8*)(Wb + (long long)(n0 + rr + it * 32) * K + k0 + rc);

        __syncthreads();
        *(bf16x8*)&As[rr][rc] = apack;
        #pragma unroll
        for (int it = 0; it < 4; ++it)
            *(bf16x8*)&Bs[rr + it * 32][rc] = wreg[it];
        __syncthreads();

        bf16x8 af = *(const bf16x8*)&As[wm0 + lr16][lk8];
        #pragma unroll
        for (int j = 0; j < 8; ++j) {
            bf16x8 bfr = *(const bf16x8*)&Bs[j * 16 + lr16][lk8];
            acc[j] = __builtin_amdgcn_mfma_f32_16x16x32_bf16(af, bfr, acc[j], 0, 0, 0);
        }
    }

    const int q4 = (l >> 4) * 4;
    #pragma unroll
    for (int j = 0; j < 8; ++j) {
        const int n = n0 + j * 16 + lr16;
        const float bi = bias[n];
        #pragma unroll
        for (int r = 0; r < 4; ++r) {
            float v = (acc[j][r] + bi) * scale;
            if (RELU) v = fmaxf(v, 0.f);
            const long long oidx = (long long)(m0 + wm0 + q4 + r) * N + n;
            if (OBF) ((__hip_bfloat16*)outv)[oidx] = __float2bfloat16(v);
            else     ((float*)outv)[oidx] = v;
        }
    }
}

// ---------------- small V^T fp32 GEMM (SA only) ----------------
#define BM 64
#define BN 64
#define BKT 16
#define APAD 4
__global__ __launch_bounds__(256)
void vt_gemm(const float* __restrict__ X, const float* __restrict__ W,
             const float* __restrict__ bias, __hip_bfloat16* __restrict__ Ct,
             int SD, int SVT)
{
    __shared__ float Ws[BKT][BM + APAD];
    __shared__ float Xs[BKT][BN + APAD];
    const int tid = threadIdx.x;
    const int tx = tid & 15, ty = tid >> 4;
    const int s0 = blockIdx.x * BN, n0 = blockIdx.y * BM;
    const int b  = blockIdx.z;
    const int lr = tid >> 2, lc = (tid & 3) << 2;

    const long long wrow = (long long)(n0 + lr) * EE;
    int srow = s0 + lr; if (srow >= SD) srow = SD - 1;
    const long long xrow = ((long long)b * SD + srow) * EE;

    float acc[4][4] = {};
    for (int k0 = 0; k0 < EE; k0 += BKT) {
        float4 wv = *(const float4*)(W + wrow + k0 + lc);
        float4 xv = *(const float4*)(X + xrow + k0 + lc);
        __syncthreads();
        Ws[lc+0][lr] = wv.x; Ws[lc+1][lr] = wv.y; Ws[lc+2][lr] = wv.z; Ws[lc+3][lr] = wv.w;
        Xs[lc+0][lr] = xv.x; Xs[lc+1][lr] = xv.y; Xs[lc+2][lr] = xv.z; Xs[lc+3][lr] = xv.w;
        __syncthreads();
        #pragma unroll
        for (int kk = 0; kk < BKT; ++kk) {
            float a4[4], b4[4];
            #pragma unroll
            for (int i = 0; i < 4; ++i) a4[i] = Ws[kk][ty*4 + i];
            #pragma unroll
            for (int j = 0; j < 4; ++j) b4[j] = Xs[kk][tx*4 + j];
            #pragma unroll
            for (int i = 0; i < 4; ++i)
                #pragma unroll
                for (int j = 0; j < 4; ++j)
                    acc[i][j] += a4[i] * b4[j];
        }
    }

    #pragma unroll
    for (int i = 0; i < 4; ++i) {
        const int n = n0 + ty*4 + i;
        const float bi = bias[n];
        const int s = s0 + tx*4;
        __hip_bfloat16* dst = Ct + (long long)(b * EE + n) * SVT + s;
        if (s + 3 < SD) {
            ushort4 ov;
            ov.x = f2bfu(acc[i][0] + bi); ov.y = f2bfu(acc[i][1] + bi);
            ov.z = f2bfu(acc[i][2] + bi); ov.w = f2bfu(acc[i][3] + bi);
            *(ushort4*)dst = ov;
        } else {
            #pragma unroll
            for (int j = 0; j < 4; ++j)
                if (s + j < SD) dst[j] = __float2bfloat16(acc[i][j] + bi);
        }
    }
}

// ---------------- MFMA flash attention (mask prefetched) ----------------
#define KVB 32
#define LDP 40

__global__ __launch_bounds__(128, 4)
void flash_mfma(const __hip_bfloat16* __restrict__ Qg,
                const __hip_bfloat16* __restrict__ Kg,
                const __hip_bfloat16* __restrict__ Vtg,
                const float* __restrict__ mask,
                float* __restrict__ O,
                int Skv, int SVT, int qblocks)
{
    __shared__ short Ks[2][KVB][LDP];
    __shared__ short Vs[2][KVB][LDP];
    const int tid = threadIdx.x;
    const int l = tid & 63;
    const int g = l >> 4, q16 = l & 15;
    const int qb = blockIdx.x % qblocks;
    const int bh = blockIdx.x / qblocks;
    const int h = bh & (HH - 1), b = bh >> 3;
    const int q0 = qb * 32 + (tid >> 6) * 16;

    int qc = q0 + q16; if (qc >= TQ) qc = TQ - 1;
    const bf16x8 qfrag = *(const bf16x8*)(Qg + ((long long)(b * TQ + qc)) * EE + h * DHH + g * 8);

    const int srow = tid >> 2;
    const int sseg = (tid & 3) * 8;
    const long long kbase = ((long long)b * Skv) * EE + h * DHH;
    const long long vbase = ((long long)(b * EE + h * DHH)) * SVT;
    const float* mrowp = mask ? mask + ((long long)bh * TQ + qc) * Skv : nullptr;

    f32x4 oacc[2] = {{0.f,0.f,0.f,0.f},{0.f,0.f,0.f,0.f}};
    float mrun = -1e30f, lrun = 0.f;
    const f32x4 zero = {0.f,0.f,0.f,0.f};

    int s_ld = srow; if (s_ld >= Skv) s_ld = Skv - 1;
    bf16x8 kreg = *(const bf16x8*)(Kg + kbase + (long long)s_ld * EE + sseg);
    bf16x8 vreg = *(const bf16x8*)(Vtg + vbase + (long long)srow * SVT + sseg);
    float4 mcur0, mcur1;
    if (mrowp) {
        mcur0 = *(const float4*)(mrowp + g * 4);
        mcur1 = *(const float4*)(mrowp + 16 + g * 4);
    }

    const int nround = (Skv + KVB - 1) / KVB;
    for (int r = 0; r < nround; ++r) {
        const int buf = r & 1;
        *(bf16x8*)&Ks[buf][srow][sseg] = kreg;
        *(bf16x8*)&Vs[buf][srow][sseg] = vreg;
        float4 mnx0, mnx1;
        if (r + 1 < nround) {
            int sn = (r + 1) * KVB + srow; if (sn >= Skv) sn = Skv - 1;
            kreg = *(const bf16x8*)(Kg + kbase + (long long)sn * EE + sseg);
            vreg = *(const bf16x8*)(Vtg + vbase + (long long)srow * SVT + (r + 1) * KVB + sseg);
            if (mrowp) {
                mnx0 = *(const float4*)(mrowp + (r + 1) * KVB + g * 4);
                mnx1 = *(const float4*)(mrowp + (r + 1) * KVB + 16 + g * 4);
            }
        }
        __syncthreads();

        const int s0 = r * KVB;
        f32x4 sT[2];
        #pragma unroll
        for (int t = 0; t < 2; ++t) {
            bf16x8 kf = *(const bf16x8*)&Ks[buf][t * 16 + q16][g * 8];
            sT[t] = __builtin_amdgcn_mfma_f32_16x16x32_bf16(kf, qfrag, zero, 0, 0, 0);
        }
        float sc[8];
        if (mrowp) {
            sc[0] = sT[0][0] + mcur0.x; sc[1] = sT[0][1] + mcur0.y;
            sc[2] = sT[0][2] + mcur0.z; sc[3] = sT[0][3] + mcur0.w;
            sc[4] = sT[1][0] + mcur1.x; sc[5] = sT[1][1] + mcur1.y;
            sc[6] = sT[1][2] + mcur1.z; sc[7] = sT[1][3] + mcur1.w;
        } else {
            #pragma unroll
            for (int t = 0; t < 2; ++t)
                #pragma unroll
                for (int rg = 0; rg < 4; ++rg) {
                    int s = s0 + t * 16 + g * 4 + rg;
                    sc[t*4+rg] = (s < Skv) ? sT[t][rg] : -1e30f;
                }
        }
        float tmax = sc[0];
        #pragma unroll
        for (int i = 1; i < 8; ++i) tmax = fmaxf(tmax, sc[i]);
        tmax = fmaxf(tmax, __shfl_xor(tmax, 16));
        tmax = fmaxf(tmax, __shfl_xor(tmax, 32));
        const float mn = fmaxf(mrun, tmax);
        const float corr = __expf(mrun - mn);
        mrun = mn;
        float ps = 0.f;
        bf16x8 pfrag;
        #pragma unroll
        for (int i = 0; i < 8; ++i) {
            float p = __expf(sc[i] - mn);
            ps += p;
            pfrag[i] = (short)f2bfu(p);
        }
        ps += __shfl_xor(ps, 16);
        ps += __shfl_xor(ps, 32);
        lrun = lrun * corr + ps;
        #pragma unroll
        for (int rg = 0; rg < 4; ++rg) {
            float c = __shfl(corr, g * 4 + rg);
            oacc[0][rg] *= c;
            oacc[1][rg] *= c;
        }
        #pragma unroll
        for (int T = 0; T < 2; ++T) {
            bf16x4 v0 = *(const bf16x4*)&Vs[buf][T * 16 + q16][g * 4];
            bf16x4 v1 = *(const bf16x4*)&Vs[buf][T * 16 + q16][16 + g * 4];
            bf16x8 vf;
            vf[0] = v0[0]; vf[1] = v0[1]; vf[2] = v0[2]; vf[3] = v0[3];
            vf[4] = v1[0]; vf[5] = v1[1]; vf[6] = v1[2]; vf[7] = v1[3];
            oacc[T] = __builtin_amdgcn_mfma_f32_16x16x32_bf16(pfrag, vf, oacc[T], 0, 0, 0);
        }
        mcur0 = mnx0; mcur1 = mnx1;
        __syncthreads();
    }

    float linv[4];
    #pragma unroll
    for (int rg = 0; rg < 4; ++rg)
        linv[rg] = 1.f / __shfl(lrun, g * 4 + rg);
    #pragma unroll
    for (int rg = 0; rg < 4; ++rg) {
        const int q = q0 + g * 4 + rg;
        if (q < TQ) {
            float* op = O + ((long long)(b * TQ + q)) * EE + h * DHH + q16;
            op[0]  = oacc[0][rg] * linv[rg];
            op[16] = oacc[1][rg] * linv[rg];
        }
    }
}

// ---------------- LayerNorm ----------------
template<int GATHER_RES, int OUT_T, int OUT_BF>
__global__ __launch_bounds__(256)
void ln_kernel(const float* __restrict__ res, const float* __restrict__ x,
               const float* __restrict__ gam, const float* __restrict__ bet,
               float* __restrict__ out, __hip_bfloat16* __restrict__ outb)
{
    __shared__ float r1[4], r2[4];
    const int m = blockIdx.x;
    const int k = threadIdx.x;
    const int b = m / TQ, t = m - b * TQ;
    const long long roff = GATHER_RES ? ((long long)(t * BB + b)) * EE : (long long)m * EE;
    float v = res[roff + k] + x[(long long)m * EE + k];
    float s = v;
    #pragma unroll
    for (int off = 32; off; off >>= 1) s += __shfl_down(s, off);
    if ((k & 63) == 0) r1[k >> 6] = s;
    __syncthreads();
    const float mu = (r1[0] + r1[1] + r1[2] + r1[3]) * (1.0f / EE);
    const float d = v - mu;
    float s2 = d * d;
    #pragma unroll
    for (int off = 32; off; off >>= 1) s2 += __shfl_down(s2, off);
    if ((k & 63) == 0) r2[k >> 6] = s2;
    __syncthreads();
    const float var = (r2[0] + r2[1] + r2[2] + r2[3]) * (1.0f / EE);
    const float o = d * rsqrtf(var + LNEPS) * gam[k] + bet[k];
    const long long ooff = OUT_T ? ((long long)(t * BB + b)) * EE : (long long)m * EE;
    out[ooff + k] = o;
    if (OUT_BF) outb[(long long)m * EE + k] = __float2bfloat16(o);
}

extern "C" void kernel_launch(void* const* d_in, const int* in_sizes, int n_in,
                              void* d_out, int out_size, void* d_ws, size_t ws_size,
                              hipStream_t stream)
{
    const float* hs    = (const float*)d_in[0];
    const float* qp    = (const float*)d_in[1];
    const float* enc   = (const float*)d_in[2];
    const float* ep    = (const float*)d_in[3];
    const float* mask  = (const float*)d_in[4];
    const float* ca_wq = (const float*)d_in[5];  const float* ca_bq = (const float*)d_in[6];
    const float* ca_wk = (const float*)d_in[7];  const float* ca_bk = (const float*)d_in[8];
    const float* ca_wv = (const float*)d_in[9];  const float* ca_bv = (const float*)d_in[10];
    const float* ca_wo = (const float*)d_in[11]; const float* ca_bo = (const float*)d_in[12];
    const float* sa_wq = (const float*)d_in[13]; const float* sa_bq = (const float*)d_in[14];
    const float* sa_wk = (const float*)d_in[15]; const float* sa_bk = (const float*)d_in[16];
    const float* sa_wv = (const float*)d_in[17]; const float* sa_bv = (const float*)d_in[18];
    const float* sa_wo = (const float*)d_in[19]; const float* sa_bo = (const float*)d_in[20];
    const float* ln1_g = (const float*)d_in[21]; const float* ln1_b = (const float*)d_in[22];
    const float* ln2_g = (const float*)d_in[23]; const float* ln2_b = (const float*)d_in[24];
    const float* ln3_g = (const float*)d_in[25]; const float* ln3_b = (const float*)d_in[26];
    const float* fc1_w = (const float*)d_in[27]; const float* fc1_b = (const float*)d_in[28];
    const float* fc2_w = (const float*)d_in[29]; const float* fc2_b = (const float*)d_in[30];

    const int MQ = BB * TQ;   // 3200
    const int MK = BB * SS;   // 131072
    const int SVT2 = 128;

    size_t off = 0;
    char* base = (char*)d_ws;
    auto alloc = [&](size_t bytes) -> void* {
        void* p = base + off; off = (off + bytes + 255) & ~(size_t)255; return p;
    };
    __hip_bfloat16* Kc  = (__hip_bfloat16*)alloc((size_t)MK * EE * 2);
    __hip_bfloat16* Vt  = (__hip_bfloat16*)alloc((size_t)BB * EE * SS * 2);
    __hip_bfloat16* Qc  = (__hip_bfloat16*)alloc((size_t)MQ * EE * 2);
    __hip_bfloat16* Qs  = (__hip_bfloat16*)alloc((size_t)MQ * EE * 2);
    __hip_bfloat16* Ks2 = (__hip_bfloat16*)alloc((size_t)MQ * EE * 2);
    __hip_bfloat16* Vt2 = (__hip_bfloat16*)alloc((size_t)BB * EE * SVT2 * 2);
    __hip_bfloat16* Wq1 = (__hip_bfloat16*)alloc((size_t)EE * EE * 2);
    __hip_bfloat16* Wkb = (__hip_bfloat16*)alloc((size_t)EE * EE * 2);
    __hip_bfloat16* Wvb = (__hip_bfloat16*)alloc((size_t)EE * EE * 2);
    __hip_bfloat16* Wo1 = (__hip_bfloat16*)alloc((size_t)EE * EE * 2);
    __hip_bfloat16* Wq2 = (__hip_bfloat16*)alloc((size_t)EE * EE * 2);
    __hip_bfloat16* Wk2 = (__hip_bfloat16*)alloc((size_t)EE * EE * 2);
    __hip_bfloat16* Wo2 = (__hip_bfloat16*)alloc((size_t)EE * EE * 2);
    __hip_bfloat16* Wf1 = (__hip_bfloat16*)alloc((size_t)FF * EE * 2);
    __hip_bfloat16* Wf2 = (__hip_bfloat16*)alloc((size_t)EE * FF * 2);
    __hip_bfloat16* hs2b= (__hip_bfloat16*)alloc((size_t)MQ * EE * 2);
    __hip_bfloat16* h1b = (__hip_bfloat16*)alloc((size_t)MQ * FF * 2);
    float* attO  = (float*)alloc((size_t)MQ * EE * 4);
    float* xproj = (float*)alloc((size_t)MQ * EE * 4);
    float* hs1   = (float*)alloc((size_t)MQ * EE * 4);
    float* attO2 = (float*)alloc((size_t)MQ * EE * 4);
    float* xpro2 = (float*)alloc((size_t)MQ * EE * 4);
    float* hs2   = (float*)alloc((size_t)MQ * EE * 4);
    float* xffn  = (float*)alloc((size_t)MQ * EE * 4);

    const float qscale = 0.17677669529663687f;
    dim3 blk(256);
    const int QBLK = 4;

    // all weights -> bf16 in one launch (7x65536 + 2x524288 elems)
    cvt_all<<<dim3(1472), blk, 0, stream>>>(
        ca_wq, ca_wk, ca_wv, ca_wo, sa_wq, sa_wk, sa_wo, fc1_w, fc2_w,
        (unsigned short*)Wq1, (unsigned short*)Wkb, (unsigned short*)Wvb,
        (unsigned short*)Wo1, (unsigned short*)Wq2, (unsigned short*)Wk2,
        (unsigned short*)Wo2, (unsigned short*)Wf1, (unsigned short*)Wf2);

    // ---- cross-attention ----
    mfma_gemm2<1,1,0,1,0><<<dim3(MQ/32, 2), dim3(128), 0, stream>>>(hs, qp, Wq1, ca_bq, Qc, EE, EE, qscale);
    proj_kv<<<dim3(MK/PBM), blk, 0, stream>>>(enc, ep, Wkb, ca_bk, Wvb, ca_bv, Kc, Vt);
    flash_mfma<<<dim3(BB*HH*QBLK), dim3(128), 0, stream>>>(Qc, Kc, Vt, mask, attO, SS, SS, QBLK);
    mfma_gemm2<0,0,0,0,0><<<dim3(MQ/32, 2), dim3(128), 0, stream>>>(attO, nullptr, Wo1, ca_bo, xproj, EE, EE, 1.f);
    ln_kernel<1,0,0><<<dim3(MQ), blk, 0, stream>>>(hs, xproj, ln1_g, ln1_b, hs1, nullptr);

    // ---- self-attention ----
    mfma_gemm2<0,1,0,1,0><<<dim3(MQ/32, 2), dim3(128), 0, stream>>>(hs1, qp, Wq2, sa_bq, Qs,  EE, EE, qscale);
    mfma_gemm2<0,1,0,1,0><<<dim3(MQ/32, 2), dim3(128), 0, stream>>>(hs1, qp, Wk2, sa_bk, Ks2, EE, EE, 1.f);
    vt_gemm<<<dim3(2, EE/BM, BB), blk, 0, stream>>>(hs1, sa_wv, sa_bv, Vt2, TQ, SVT2);
    flash_mfma<<<dim3(BB*HH*QBLK), dim3(128), 0, stream>>>(Qs, Ks2, Vt2, nullptr, attO2, TQ, SVT2, QBLK);
    mfma_gemm2<0,0,0,0,0><<<dim3(MQ/32, 2), dim3(128), 0, stream>>>(attO2, nullptr, Wo2, sa_bo, xpro2, EE, EE, 1.f);
    ln_kernel<0,0,1><<<dim3(MQ), blk, 0, stream>>>(hs1, xpro2, ln2_g, ln2_b, hs2, hs2b);

    // ---- FFN ----
    mfma_gemm2<0,0,1,1,1><<<dim3(MQ/32, FF/128), dim3(128), 0, stream>>>(hs2b, nullptr, Wf1, fc1_b, h1b, FF, EE, 1.f);
    mfma_gemm2<0,0,1,0,0><<<dim3(MQ/32, 2), dim3(128), 0, stream>>>(h1b, nullptr, Wf2, fc2_b, xffn, EE, FF, 1.f);
    ln_kernel<0,1,0><<<dim3(MQ), blk, 0, stream>>>(hs2, xffn, ln3_g, ln3_b, (float*)d_out, nullptr);

    (void)in_sizes; (void)n_in; (void)out_size; (void)ws_size;
}

// Round 7
// 432.838 us; speedup vs baseline: 11.6838x; 1.1865x over previous
//
#include <hip/hip_runtime.h>
#include <hip/hip_bf16.h>
#include <math.h>

#define TQ 100
#define SS 4096
#define BB 32
#define EE 256
#define HH 8
#define FF 2048
#define DHH 32
#define LNEPS 1e-5f

typedef __attribute__((ext_vector_type(8))) short bf16x8;
typedef __attribute__((ext_vector_type(4))) short bf16x4;
typedef __attribute__((ext_vector_type(4))) float f32x4;

__device__ inline unsigned short f2bfu(float f) {
    __hip_bfloat16 h = __float2bfloat16(f);
    return *reinterpret_cast<unsigned short*>(&h);
}

#define PBM 64
#define PBK 32
#define PLDP 40
#define TLP 268

// ---------------- fused weight fp32->bf16 convert (10 segments, 1 launch) ----------------
// segs 0..7: 65536 elems (E*E) -> 64 blocks each; segs 8..9: 524288 (F*E) -> 512 blocks each.
__global__ __launch_bounds__(256)
void cvt_all(const float* s0, const float* s1, const float* s2, const float* s3,
             const float* s4, const float* s5, const float* s6, const float* s7,
             const float* s8, const float* s9,
             unsigned short* d0, unsigned short* d1, unsigned short* d2, unsigned short* d3,
             unsigned short* d4, unsigned short* d5, unsigned short* d6, unsigned short* d7,
             unsigned short* d8, unsigned short* d9)
{
    const int bi = blockIdx.x;
    const float* s; unsigned short* d; int base;
    if (bi < 512) {
        const int seg = bi >> 6;
        base = (bi & 63) * 1024;
        switch (seg) {
            case 0: s = s0; d = d0; break;
            case 1: s = s1; d = d1; break;
            case 2: s = s2; d = d2; break;
            case 3: s = s3; d = d3; break;
            case 4: s = s4; d = d4; break;
            case 5: s = s5; d = d5; break;
            case 6: s = s6; d = d6; break;
            default: s = s7; d = d7; break;
        }
    } else {
        const int r = bi - 512;
        base = (r & 511) * 1024;
        if (r >> 9) { s = s9; d = d9; } else { s = s8; d = d8; }
    }
    const int i = base + threadIdx.x * 4;
    float4 v = *(const float4*)(s + i);
    ushort4 ov;
    ov.x = f2bfu(v.x); ov.y = f2bfu(v.y); ov.z = f2bfu(v.z); ov.w = f2bfu(v.w);
    *(ushort4*)(d + i) = ov;
}

// ---------------- fused K + V^T projection (M = BB*SS) ----------------
__global__ __launch_bounds__(256)
void proj_kv(const float* __restrict__ enc, const float* __restrict__ ep,
             const __hip_bfloat16* __restrict__ Wk, const float* __restrict__ bk,
             const __hip_bfloat16* __restrict__ Wv, const float* __restrict__ bv,
             __hip_bfloat16* __restrict__ Kout, __hip_bfloat16* __restrict__ Vtout)
{
    __shared__ short Akv[PBM][PLDP];
    __shared__ short Av[PBM][PLDP];
    __shared__ short BkRaw[256 * PLDP];
    __shared__ short BvRaw[256 * PLDP];
    short (*Bk)[PLDP] = (short(*)[PLDP])BkRaw;
    short (*Bv)[PLDP] = (short(*)[PLDP])BvRaw;
    short (*tk)[TLP] = (short(*)[TLP])BkRaw;
    short (*tv)[TLP] = (short(*)[TLP])BvRaw;

    const int tid = threadIdx.x;
    const int m0 = blockIdx.x * PBM;
    const int b = m0 >> 12;
    const int s0 = m0 & (SS - 1);
    const int rr = tid >> 2;
    const int rc = (tid & 3) << 3;
    const long long abase = ((long long)(s0 + rr) * BB + b) * EE + rc;

    const int wv = tid >> 6, l = tid & 63;
    const int wm0 = (wv & 1) * 32, wn0 = (wv >> 1) * 128;
    const int lr16 = l & 15, lk8 = (l >> 4) * 8;

    f32x4 acck[2][8] = {};
    f32x4 accv[2][8] = {};

    for (int k0 = 0; k0 < EE; k0 += PBK) {
        float4 a0 = *(const float4*)(enc + abase + k0);
        float4 a1 = *(const float4*)(enc + abase + k0 + 4);
        float4 e0 = *(const float4*)(ep + abase + k0);
        float4 e1 = *(const float4*)(ep + abase + k0 + 4);
        bf16x8 pv, pkv;
        pv[0] = (short)f2bfu(a0.x); pv[1] = (short)f2bfu(a0.y);
        pv[2] = (short)f2bfu(a0.z); pv[3] = (short)f2bfu(a0.w);
        pv[4] = (short)f2bfu(a1.x); pv[5] = (short)f2bfu(a1.y);
        pv[6] = (short)f2bfu(a1.z); pv[7] = (short)f2bfu(a1.w);
        pkv[0] = (short)f2bfu(a0.x + e0.x); pkv[1] = (short)f2bfu(a0.y + e0.y);
        pkv[2] = (short)f2bfu(a0.z + e0.z); pkv[3] = (short)f2bfu(a0.w + e0.w);
        pkv[4] = (short)f2bfu(a1.x + e1.x); pkv[5] = (short)f2bfu(a1.y + e1.y);
        pkv[6] = (short)f2bfu(a1.z + e1.z); pkv[7] = (short)f2bfu(a1.w + e1.w);

        bf16x8 wkr[4], wvr[4];
        #pragma unroll
        for (int it = 0; it < 4; ++it) {
            wkr[it] = *(const bf16x8*)(Wk + (long long)(rr + it * 64) * EE + k0 + rc);
            wvr[it] = *(const bf16x8*)(Wv + (long long)(rr + it * 64) * EE + k0 + rc);
        }

        __syncthreads();
        *(bf16x8*)&Akv[rr][rc] = pkv;
        *(bf16x8*)&Av[rr][rc]  = pv;
        #pragma unroll
        for (int it = 0; it < 4; ++it) {
            *(bf16x8*)&Bk[rr + it * 64][rc] = wkr[it];
            *(bf16x8*)&Bv[rr + it * 64][rc] = wvr[it];
        }
        __syncthreads();

        bf16x8 ak0 = *(const bf16x8*)&Akv[wm0 + lr16][lk8];
        bf16x8 ak1 = *(const bf16x8*)&Akv[wm0 + 16 + lr16][lk8];
        bf16x8 av0 = *(const bf16x8*)&Av[wm0 + lr16][lk8];
        bf16x8 av1 = *(const bf16x8*)&Av[wm0 + 16 + lr16][lk8];
        #pragma unroll
        for (int j = 0; j < 8; ++j) {
            bf16x8 bk8 = *(const bf16x8*)&Bk[wn0 + j * 16 + lr16][lk8];
            bf16x8 bv8 = *(const bf16x8*)&Bv[wn0 + j * 16 + lr16][lk8];
            acck[0][j] = __builtin_amdgcn_mfma_f32_16x16x32_bf16(ak0, bk8, acck[0][j], 0, 0, 0);
            acck[1][j] = __builtin_amdgcn_mfma_f32_16x16x32_bf16(ak1, bk8, acck[1][j], 0, 0, 0);
            accv[0][j] = __builtin_amdgcn_mfma_f32_16x16x32_bf16(av0, bv8, accv[0][j], 0, 0, 0);
            accv[1][j] = __builtin_amdgcn_mfma_f32_16x16x32_bf16(av1, bv8, accv[1][j], 0, 0, 0);
        }
    }

    const int q4 = (l >> 4) * 4;
    #pragma unroll
    for (int h = 0; h < 2; ++h) {
        __syncthreads();
        if (wm0 == h * 32) {
            #pragma unroll
            for (int i = 0; i < 2; ++i) {
                #pragma unroll
                for (int j = 0; j < 8; ++j) {
                    const int n = wn0 + j * 16 + lr16;
                    const float bik = bk[n], biv = bv[n];
                    #pragma unroll
                    for (int r = 0; r < 4; ++r) {
                        tk[i * 16 + q4 + r][n] = (short)f2bfu(acck[i][j][r] + bik);
                        tv[i * 16 + q4 + r][n] = (short)f2bfu(accv[i][j][r] + biv);
                    }
                }
            }
        }
        __syncthreads();
        #pragma unroll
        for (int it = 0; it < 8; ++it) {
            const int r2 = wv * 8 + it;
            ushort4 v = *(const ushort4*)&tk[r2][l * 4];
            *(ushort4*)(Kout + (long long)(m0 + h * 32 + r2) * EE + l * 4) = v;
        }
        #pragma unroll
        for (int nn = 0; nn < 32; ++nn) {
            const int n = wv * 64 + nn * 2 + (l >> 5);
            const int s = l & 31;
            unsigned short v = (unsigned short)tv[s][n];
            *((unsigned short*)Vtout + (long long)(b * EE + n) * SS + s0 + h * 32 + s) = v;
        }
    }
}

// ---------------- small MFMA GEMM: 32m x 128n tile, 128 threads ----------------
template<int A1G, int A2Q, int A1BF, int OBF, int RELU>
__global__ __launch_bounds__(128)
void mfma_gemm2(const void* __restrict__ A1v, const float* __restrict__ A2,
                const __hip_bfloat16* __restrict__ Wb, const float* __restrict__ bias,
                void* __restrict__ outv, int N, int K, float scale)
{
    __shared__ short As[32][PLDP];
    __shared__ short Bs[128][PLDP];
    const int tid = threadIdx.x;
    const int m0 = blockIdx.x * 32;
    const int n0 = blockIdx.y * 128;
    const int rr = tid >> 2;
    const int rc = (tid & 3) << 3;
    const int row = m0 + rr;

    long long a2row = 0;
    if (A1G || A2Q) {
        int bq = row / TQ, tq = row - bq * TQ;
        a2row = ((long long)(tq * BB + bq)) * EE;
    }
    const long long a1row = A1G ? a2row : (long long)row * K;

    const int wv = tid >> 6, l = tid & 63;
    const int wm0 = wv * 16;
    const int lr16 = l & 15, lk8 = (l >> 4) * 8;

    f32x4 acc[8] = {};

    for (int k0 = 0; k0 < K; k0 += PBK) {
        bf16x8 apack;
        if (A1BF) {
            apack = *(const bf16x8*)((const __hip_bfloat16*)A1v + a1row + k0 + rc);
        } else {
            const float* A1 = (const float*)A1v;
            float4 a0 = *(const float4*)(A1 + a1row + k0 + rc);
            float4 a1 = *(const float4*)(A1 + a1row + k0 + rc + 4);
            if (A2Q) {
                float4 e0 = *(const float4*)(A2 + a2row + k0 + rc);
                float4 e1 = *(const float4*)(A2 + a2row + k0 + rc + 4);
                a0.x += e0.x; a0.y += e0.y; a0.z += e0.z; a0.w += e0.w;
                a1.x += e1.x; a1.y += e1.y; a1.z += e1.z; a1.w += e1.w;
            }
            apack[0] = (short)f2bfu(a0.x); apack[1] = (short)f2bfu(a0.y);
            apack[2] = (short)f2bfu(a0.z); apack[3] = (short)f2bfu(a0.w);
            apack[4] = (short)f2bfu(a1.x); apack[5] = (short)f2bfu(a1.y);
            apack[6] = (short)f2bfu(a1.z); apack[7] = (short)f2bfu(a1.w);
        }

        bf16x8 wreg[4];
        #pragma unroll
        for (int it = 0; it < 4; ++it)
            wreg[it] = *(const bf16x8*)(Wb + (long long)(n0 + rr + it * 32) * K + k0 + rc);

        __syncthreads();
        *(bf16x8*)&As[rr][rc] = apack;
        #pragma unroll
        for (int it = 0; it < 4; ++it)
            *(bf16x8*)&Bs[rr + it * 32][rc] = wreg[it];
        __syncthreads();

        bf16x8 af = *(const bf16x8*)&As[wm0 + lr16][lk8];
        #pragma unroll
        for (int j = 0; j < 8; ++j) {
            bf16x8 bfr = *(const bf16x8*)&Bs[j * 16 + lr16][lk8];
            acc[j] = __builtin_amdgcn_mfma_f32_16x16x32_bf16(af, bfr, acc[j], 0, 0, 0);
        }
    }

    const int q4 = (l >> 4) * 4;
    #pragma unroll
    for (int j = 0; j < 8; ++j) {
        const int n = n0 + j * 16 + lr16;
        const float bi = bias[n];
        #pragma unroll
        for (int r = 0; r < 4; ++r) {
            float v = (acc[j][r] + bi) * scale;
            if (RELU) v = fmaxf(v, 0.f);
            const long long oidx = (long long)(m0 + wm0 + q4 + r) * N + n;
            if (OBF) ((__hip_bfloat16*)outv)[oidx] = __float2bfloat16(v);
            else     ((float*)outv)[oidx] = v;
        }
    }
}

// ---------------- fused SA QKV projection ----------------
// Qs = ((hs1+qp)@Wq^T + bq)*qscale ; Ks = (hs1+qp)@Wk^T + bk ; Vt[(b*EE+n)*SVT + t] = hs1@Wv^T + bv
__global__ __launch_bounds__(128)
void qkv_sa(const float* __restrict__ hs1, const float* __restrict__ qp,
            const __hip_bfloat16* __restrict__ Wq, const float* __restrict__ bq,
            const __hip_bfloat16* __restrict__ Wk, const float* __restrict__ bk,
            const __hip_bfloat16* __restrict__ Wv, const float* __restrict__ bv,
            __hip_bfloat16* __restrict__ Qs, __hip_bfloat16* __restrict__ Ks,
            __hip_bfloat16* __restrict__ Vt, int SVT, float qscale)
{
    __shared__ short Aq[32][PLDP];
    __shared__ short Av[32][PLDP];
    __shared__ short Bq[128][PLDP];
    __shared__ short Bk[128][PLDP];
    __shared__ short Bv[128][PLDP];
    const int tid = threadIdx.x;
    const int m0 = blockIdx.x * 32;
    const int n0 = blockIdx.y * 128;
    const int rr = tid >> 2;
    const int rc = (tid & 3) << 3;
    const int row = m0 + rr;
    const int bq_ = row / TQ, tq = row - bq_ * TQ;
    const long long a1row = (long long)row * EE;
    const long long a2row = ((long long)(tq * BB + bq_)) * EE;

    const int wv = tid >> 6, l = tid & 63;
    const int wm0 = wv * 16;
    const int lr16 = l & 15, lk8 = (l >> 4) * 8;

    f32x4 aq[8] = {}, ak[8] = {}, av[8] = {};

    for (int k0 = 0; k0 < EE; k0 += PBK) {
        float4 a0 = *(const float4*)(hs1 + a1row + k0 + rc);
        float4 a1 = *(const float4*)(hs1 + a1row + k0 + rc + 4);
        float4 e0 = *(const float4*)(qp + a2row + k0 + rc);
        float4 e1 = *(const float4*)(qp + a2row + k0 + rc + 4);
        bf16x8 pq, pv;
        pv[0] = (short)f2bfu(a0.x); pv[1] = (short)f2bfu(a0.y);
        pv[2] = (short)f2bfu(a0.z); pv[3] = (short)f2bfu(a0.w);
        pv[4] = (short)f2bfu(a1.x); pv[5] = (short)f2bfu(a1.y);
        pv[6] = (short)f2bfu(a1.z); pv[7] = (short)f2bfu(a1.w);
        pq[0] = (short)f2bfu(a0.x + e0.x); pq[1] = (short)f2bfu(a0.y + e0.y);
        pq[2] = (short)f2bfu(a0.z + e0.z); pq[3] = (short)f2bfu(a0.w + e0.w);
        pq[4] = (short)f2bfu(a1.x + e1.x); pq[5] = (short)f2bfu(a1.y + e1.y);
        pq[6] = (short)f2bfu(a1.z + e1.z); pq[7] = (short)f2bfu(a1.w + e1.w);

        bf16x8 wq8[4], wk8[4], wv8[4];
        #pragma unroll
        for (int it = 0; it < 4; ++it) {
            const long long wr = (long long)(n0 + rr + it * 32) * EE + k0 + rc;
            wq8[it] = *(const bf16x8*)(Wq + wr);
            wk8[it] = *(const bf16x8*)(Wk + wr);
            wv8[it] = *(const bf16x8*)(Wv + wr);
        }

        __syncthreads();
        *(bf16x8*)&Aq[rr][rc] = pq;
        *(bf16x8*)&Av[rr][rc] = pv;
        #pragma unroll
        for (int it = 0; it < 4; ++it) {
            *(bf16x8*)&Bq[rr + it * 32][rc] = wq8[it];
            *(bf16x8*)&Bk[rr + it * 32][rc] = wk8[it];
            *(bf16x8*)&Bv[rr + it * 32][rc] = wv8[it];
        }
        __syncthreads();

        bf16x8 afq = *(const bf16x8*)&Aq[wm0 + lr16][lk8];
        bf16x8 afv = *(const bf16x8*)&Av[wm0 + lr16][lk8];
        #pragma unroll
        for (int j = 0; j < 8; ++j) {
            bf16x8 b1 = *(const bf16x8*)&Bq[j * 16 + lr16][lk8];
            bf16x8 b2 = *(const bf16x8*)&Bk[j * 16 + lr16][lk8];
            bf16x8 b3 = *(const bf16x8*)&Bv[j * 16 + lr16][lk8];
            aq[j] = __builtin_amdgcn_mfma_f32_16x16x32_bf16(afq, b1, aq[j], 0, 0, 0);
            ak[j] = __builtin_amdgcn_mfma_f32_16x16x32_bf16(afq, b2, ak[j], 0, 0, 0);
            av[j] = __builtin_amdgcn_mfma_f32_16x16x32_bf16(afv, b3, av[j], 0, 0, 0);
        }
    }

    const int q4 = (l >> 4) * 4;
    #pragma unroll
    for (int j = 0; j < 8; ++j) {
        const int n = n0 + j * 16 + lr16;
        const float b1 = bq[n], b2 = bk[n], b3 = bv[n];
        #pragma unroll
        for (int r = 0; r < 4; ++r) {
            const int m = m0 + wm0 + q4 + r;
            Qs[(long long)m * EE + n] = __float2bfloat16((aq[j][r] + b1) * qscale);
            Ks[(long long)m * EE + n] = __float2bfloat16(ak[j][r] + b2);
            const int bb = m / TQ, tt = m - bb * TQ;
            Vt[(long long)(bb * EE + n) * SVT + tt] = __float2bfloat16(av[j][r] + b3);
        }
    }
}

// ---------------- MFMA flash attention: 4 waves, 64 q/block, XCD-chunked swizzle ----------------
#define KVB 32
#define LDP 40

__global__ __launch_bounds__(256, 2)
void flash_mfma(const __hip_bfloat16* __restrict__ Qg,
                const __hip_bfloat16* __restrict__ Kg,
                const __hip_bfloat16* __restrict__ Vtg,
                const float* __restrict__ mask,
                __hip_bfloat16* __restrict__ O,
                int Skv, int SVT)
{
    __shared__ short Ks[2][KVB][LDP];
    __shared__ short Vs[2][KVB][LDP];
    const int tid = threadIdx.x;
    const int l = tid & 63;
    const int g = l >> 4, q16 = l & 15;
    // bijective XCD-chunk swizzle: gridDim.x % 8 == 0
    const int chunk = gridDim.x >> 3;
    const int logical = (blockIdx.x & 7) * chunk + (blockIdx.x >> 3);
    const int qb = logical & 1;
    const int bh = logical >> 1;
    const int h = bh & (HH - 1), b = bh >> 3;
    const int q0 = qb * 64 + (tid >> 6) * 16;

    int qc = q0 + q16; if (qc >= TQ) qc = TQ - 1;
    const bf16x8 qfrag = *(const bf16x8*)(Qg + ((long long)(b * TQ + qc)) * EE + h * DHH + g * 8);

    const int srow = tid >> 3;          // 0..31
    const int sseg = (tid & 7) * 4;     // bf16x4 col offset within 32
    const long long kbase = ((long long)b * Skv) * EE + h * DHH;
    const long long vbase = ((long long)(b * EE + h * DHH)) * SVT;
    const float* mrowp = mask ? mask + ((long long)bh * TQ + qc) * Skv : nullptr;

    f32x4 oacc[2] = {{0.f,0.f,0.f,0.f},{0.f,0.f,0.f,0.f}};
    float mrun = -1e30f, lrun = 0.f;
    const f32x4 zero = {0.f,0.f,0.f,0.f};

    int s_ld = srow; if (s_ld >= Skv) s_ld = Skv - 1;
    bf16x4 kreg = *(const bf16x4*)(Kg + kbase + (long long)s_ld * EE + sseg);
    bf16x4 vreg = *(const bf16x4*)(Vtg + vbase + (long long)srow * SVT + sseg);
    float4 mcur0, mcur1;
    if (mrowp) {
        mcur0 = *(const float4*)(mrowp + g * 4);
        mcur1 = *(const float4*)(mrowp + 16 + g * 4);
    }

    const int nround = (Skv + KVB - 1) / KVB;
    for (int r = 0; r < nround; ++r) {
        const int buf = r & 1;
        *(bf16x4*)&Ks[buf][srow][sseg] = kreg;
        *(bf16x4*)&Vs[buf][srow][sseg] = vreg;
        float4 mnx0, mnx1;
        if (r + 1 < nround) {
            int sn = (r + 1) * KVB + srow; if (sn >= Skv) sn = Skv - 1;
            kreg = *(const bf16x4*)(Kg + kbase + (long long)sn * EE + sseg);
            vreg = *(const bf16x4*)(Vtg + vbase + (long long)srow * SVT + (r + 1) * KVB + sseg);
            if (mrowp) {
                mnx0 = *(const float4*)(mrowp + (r + 1) * KVB + g * 4);
                mnx1 = *(const float4*)(mrowp + (r + 1) * KVB + 16 + g * 4);
            }
        }
        __syncthreads();

        const int s0 = r * KVB;
        f32x4 sT[2];
        #pragma unroll
        for (int t = 0; t < 2; ++t) {
            bf16x8 kf = *(const bf16x8*)&Ks[buf][t * 16 + q16][g * 8];
            sT[t] = __builtin_amdgcn_mfma_f32_16x16x32_bf16(kf, qfrag, zero, 0, 0, 0);
        }
        float sc[8];
        if (mrowp) {
            sc[0] = sT[0][0] + mcur0.x; sc[1] = sT[0][1] + mcur0.y;
            sc[2] = sT[0][2] + mcur0.z; sc[3] = sT[0][3] + mcur0.w;
            sc[4] = sT[1][0] + mcur1.x; sc[5] = sT[1][1] + mcur1.y;
            sc[6] = sT[1][2] + mcur1.z; sc[7] = sT[1][3] + mcur1.w;
        } else {
            #pragma unroll
            for (int t = 0; t < 2; ++t)
                #pragma unroll
                for (int rg = 0; rg < 4; ++rg) {
                    int s = s0 + t * 16 + g * 4 + rg;
                    sc[t*4+rg] = (s < Skv) ? sT[t][rg] : -1e30f;
                }
        }
        float tmax = sc[0];
        #pragma unroll
        for (int i = 1; i < 8; ++i) tmax = fmaxf(tmax, sc[i]);
        tmax = fmaxf(tmax, __shfl_xor(tmax, 16));
        tmax = fmaxf(tmax, __shfl_xor(tmax, 32));
        const float mn = fmaxf(mrun, tmax);
        const float corr = __expf(mrun - mn);
        mrun = mn;
        float ps = 0.f;
        bf16x8 pfrag;
        #pragma unroll
        for (int i = 0; i < 8; ++i) {
            float p = __expf(sc[i] - mn);
            ps += p;
            pfrag[i] = (short)f2bfu(p);
        }
        ps += __shfl_xor(ps, 16);
        ps += __shfl_xor(ps, 32);
        lrun = lrun * corr + ps;
        #pragma unroll
        for (int rg = 0; rg < 4; ++rg) {
            float c = __shfl(corr, g * 4 + rg);
            oacc[0][rg] *= c;
            oacc[1][rg] *= c;
        }
        #pragma unroll
        for (int T = 0; T < 2; ++T) {
            bf16x4 v0 = *(const bf16x4*)&Vs[buf][T * 16 + q16][g * 4];
            bf16x4 v1 = *(const bf16x4*)&Vs[buf][T * 16 + q16][16 + g * 4];
            bf16x8 vf;
            vf[0] = v0[0]; vf[1] = v0[1]; vf[2] = v0[2]; vf[3] = v0[3];
            vf[4] = v1[0]; vf[5] = v1[1]; vf[6] = v1[2]; vf[7] = v1[3];
            oacc[T] = __builtin_amdgcn_mfma_f32_16x16x32_bf16(pfrag, vf, oacc[T], 0, 0, 0);
        }
        mcur0 = mnx0; mcur1 = mnx1;
        __syncthreads();
    }

    float linv[4];
    #pragma unroll
    for (int rg = 0; rg < 4; ++rg)
        linv[rg] = 1.f / __shfl(lrun, g * 4 + rg);
    #pragma unroll
    for (int rg = 0; rg < 4; ++rg) {
        const int q = q0 + g * 4 + rg;
        if (q < TQ) {
            __hip_bfloat16* op = O + ((long long)(b * TQ + q)) * EE + h * DHH + q16;
            op[0]  = __float2bfloat16(oacc[0][rg] * linv[rg]);
            op[16] = __float2bfloat16(oacc[1][rg] * linv[rg]);
        }
    }
}

// ---------------- LayerNorm ----------------
template<int GATHER_RES, int OUT_T, int OUT_BF>
__global__ __launch_bounds__(256)
void ln_kernel(const float* __restrict__ res, const float* __restrict__ x,
               const float* __restrict__ gam, const float* __restrict__ bet,
               float* __restrict__ out, __hip_bfloat16* __restrict__ outb)
{
    __shared__ float r1[4], r2[4];
    const int m = blockIdx.x;
    const int k = threadIdx.x;
    const int b = m / TQ, t = m - b * TQ;
    const long long roff = GATHER_RES ? ((long long)(t * BB + b)) * EE : (long long)m * EE;
    float v = res[roff + k] + x[(long long)m * EE + k];
    float s = v;
    #pragma unroll
    for (int off = 32; off; off >>= 1) s += __shfl_down(s, off);
    if ((k & 63) == 0) r1[k >> 6] = s;
    __syncthreads();
    const float mu = (r1[0] + r1[1] + r1[2] + r1[3]) * (1.0f / EE);
    const float d = v - mu;
    float s2 = d * d;
    #pragma unroll
    for (int off = 32; off; off >>= 1) s2 += __shfl_down(s2, off);
    if ((k & 63) == 0) r2[k >> 6] = s2;
    __syncthreads();
    const float var = (r2[0] + r2[1] + r2[2] + r2[3]) * (1.0f / EE);
    const float o = d * rsqrtf(var + LNEPS) * gam[k] + bet[k];
    const long long ooff = OUT_T ? ((long long)(t * BB + b)) * EE : (long long)m * EE;
    out[ooff + k] = o;
    if (OUT_BF) outb[(long long)m * EE + k] = __float2bfloat16(o);
}

extern "C" void kernel_launch(void* const* d_in, const int* in_sizes, int n_in,
                              void* d_out, int out_size, void* d_ws, size_t ws_size,
                              hipStream_t stream)
{
    const float* hs    = (const float*)d_in[0];
    const float* qp    = (const float*)d_in[1];
    const float* enc   = (const float*)d_in[2];
    const float* ep    = (const float*)d_in[3];
    const float* mask  = (const float*)d_in[4];
    const float* ca_wq = (const float*)d_in[5];  const float* ca_bq = (const float*)d_in[6];
    const float* ca_wk = (const float*)d_in[7];  const float* ca_bk = (const float*)d_in[8];
    const float* ca_wv = (const float*)d_in[9];  const float* ca_bv = (const float*)d_in[10];
    const float* ca_wo = (const float*)d_in[11]; const float* ca_bo = (const float*)d_in[12];
    const float* sa_wq = (const float*)d_in[13]; const float* sa_bq = (const float*)d_in[14];
    const float* sa_wk = (const float*)d_in[15]; const float* sa_bk = (const float*)d_in[16];
    const float* sa_wv = (const float*)d_in[17]; const float* sa_bv = (const float*)d_in[18];
    const float* sa_wo = (const float*)d_in[19]; const float* sa_bo = (const float*)d_in[20];
    const float* ln1_g = (const float*)d_in[21]; const float* ln1_b = (const float*)d_in[22];
    const float* ln2_g = (const float*)d_in[23]; const float* ln2_b = (const float*)d_in[24];
    const float* ln3_g = (const float*)d_in[25]; const float* ln3_b = (const float*)d_in[26];
    const float* fc1_w = (const float*)d_in[27]; const float* fc1_b = (const float*)d_in[28];
    const float* fc2_w = (const float*)d_in[29]; const float* fc2_b = (const float*)d_in[30];

    const int MQ = BB * TQ;   // 3200
    const int MK = BB * SS;   // 131072
    const int SVT2 = 128;

    size_t off = 0;
    char* base = (char*)d_ws;
    auto alloc = [&](size_t bytes) -> void* {
        void* p = base + off; off = (off + bytes + 255) & ~(size_t)255; return p;
    };
    __hip_bfloat16* Kc  = (__hip_bfloat16*)alloc((size_t)MK * EE * 2);
    __hip_bfloat16* Vt  = (__hip_bfloat16*)alloc((size_t)BB * EE * SS * 2);
    __hip_bfloat16* Qc  = (__hip_bfloat16*)alloc((size_t)MQ * EE * 2);
    __hip_bfloat16* Qs  = (__hip_bfloat16*)alloc((size_t)MQ * EE * 2);
    __hip_bfloat16* Ks2 = (__hip_bfloat16*)alloc((size_t)MQ * EE * 2);
    __hip_bfloat16* Vt2 = (__hip_bfloat16*)alloc((size_t)BB * EE * SVT2 * 2);
    __hip_bfloat16* Wq1 = (__hip_bfloat16*)alloc((size_t)EE * EE * 2);
    __hip_bfloat16* Wkb = (__hip_bfloat16*)alloc((size_t)EE * EE * 2);
    __hip_bfloat16* Wvb = (__hip_bfloat16*)alloc((size_t)EE * EE * 2);
    __hip_bfloat16* Wo1 = (__hip_bfloat16*)alloc((size_t)EE * EE * 2);
    __hip_bfloat16* Wq2 = (__hip_bfloat16*)alloc((size_t)EE * EE * 2);
    __hip_bfloat16* Wk2 = (__hip_bfloat16*)alloc((size_t)EE * EE * 2);
    __hip_bfloat16* Wv2 = (__hip_bfloat16*)alloc((size_t)EE * EE * 2);
    __hip_bfloat16* Wo2 = (__hip_bfloat16*)alloc((size_t)EE * EE * 2);
    __hip_bfloat16* Wf1 = (__hip_bfloat16*)alloc((size_t)FF * EE * 2);
    __hip_bfloat16* Wf2 = (__hip_bfloat16*)alloc((size_t)EE * FF * 2);
    __hip_bfloat16* hs2b= (__hip_bfloat16*)alloc((size_t)MQ * EE * 2);
    __hip_bfloat16* h1b = (__hip_bfloat16*)alloc((size_t)MQ * FF * 2);
    __hip_bfloat16* attO  = (__hip_bfloat16*)alloc((size_t)MQ * EE * 2);
    __hip_bfloat16* attO2 = (__hip_bfloat16*)alloc((size_t)MQ * EE * 2);
    float* xproj = (float*)alloc((size_t)MQ * EE * 4);
    float* hs1   = (float*)alloc((size_t)MQ * EE * 4);
    float* xpro2 = (float*)alloc((size_t)MQ * EE * 4);
    float* hs2   = (float*)alloc((size_t)MQ * EE * 4);
    float* xffn  = (float*)alloc((size_t)MQ * EE * 4);

    const float qscale = 0.17677669529663687f;
    dim3 blk(256);

    // all weights -> bf16 in one launch (8x65536 + 2x524288 elems)
    cvt_all<<<dim3(1536), blk, 0, stream>>>(
        ca_wq, ca_wk, ca_wv, ca_wo, sa_wq, sa_wk, sa_wv, sa_wo, fc1_w, fc2_w,
        (unsigned short*)Wq1, (unsigned short*)Wkb, (unsigned short*)Wvb,
        (unsigned short*)Wo1, (unsigned short*)Wq2, (unsigned short*)Wk2,
        (unsigned short*)Wv2, (unsigned short*)Wo2, (unsigned short*)Wf1,
        (unsigned short*)Wf2);

    // ---- cross-attention ----
    mfma_gemm2<1,1,0,1,0><<<dim3(MQ/32, 2), dim3(128), 0, stream>>>(hs, qp, Wq1, ca_bq, Qc, EE, EE, qscale);
    proj_kv<<<dim3(MK/PBM), blk, 0, stream>>>(enc, ep, Wkb, ca_bk, Wvb, ca_bv, Kc, Vt);
    flash_mfma<<<dim3(BB*HH*2), dim3(256), 0, stream>>>(Qc, Kc, Vt, mask, attO, SS, SS);
    mfma_gemm2<0,0,1,0,0><<<dim3(MQ/32, 2), dim3(128), 0, stream>>>(attO, nullptr, Wo1, ca_bo, xproj, EE, EE, 1.f);
    ln_kernel<1,0,0><<<dim3(MQ), blk, 0, stream>>>(hs, xproj, ln1_g, ln1_b, hs1, nullptr);

    // ---- self-attention ----
    qkv_sa<<<dim3(MQ/32, 2), dim3(128), 0, stream>>>(hs1, qp, Wq2, sa_bq, Wk2, sa_bk, Wv2, sa_bv,
                                                     Qs, Ks2, Vt2, SVT2, qscale);
    flash_mfma<<<dim3(BB*HH*2), dim3(256), 0, stream>>>(Qs, Ks2, Vt2, nullptr, attO2, TQ, SVT2);
    mfma_gemm2<0,0,1,0,0><<<dim3(MQ/32, 2), dim3(128), 0, stream>>>(attO2, nullptr, Wo2, sa_bo, xpro2, EE, EE, 1.f);
    ln_kernel<0,0,1><<<dim3(MQ), blk, 0, stream>>>(hs1, xpro2, ln2_g, ln2_b, hs2, hs2b);

    // ---- FFN ----
    mfma_gemm2<0,0,1,1,1><<<dim3(MQ/32, FF/128), dim3(128), 0, stream>>>(hs2b, nullptr, Wf1, fc1_b, h1b, FF, EE, 1.f);
    mfma_gemm2<0,0,1,0,0><<<dim3(MQ/32, 2), dim3(128), 0, stream>>>(h1b, nullptr, Wf2, fc2_b, xffn, EE, FF, 1.f);
    ln_kernel<0,1,0><<<dim3(MQ), blk, 0, stream>>>(hs2, xffn, ln3_g, ln3_b, (float*)d_out, nullptr);

    (void)in_sizes; (void)n_in; (void)out_size; (void)ws_size;
}

// Round 8
// 378.073 us; speedup vs baseline: 13.3763x; 1.1449x over previous
//
#include <hip/hip_runtime.h>
#include <hip/hip_bf16.h>
#include <math.h>

#define TQ 100
#define SS 4096
#define BB 32
#define EE 256
#define HH 8
#define FF 2048
#define DHH 32
#define LNEPS 1e-5f

typedef __attribute__((ext_vector_type(8))) short bf16x8;
typedef __attribute__((ext_vector_type(4))) short bf16x4;
typedef __attribute__((ext_vector_type(4))) float f32x4;

__device__ inline unsigned short f2bfu(float f) {
    __hip_bfloat16 h = __float2bfloat16(f);
    return *reinterpret_cast<unsigned short*>(&h);
}

#define PBM 64
#define PBK 32
#define PLDP 40
#define TLP 268

// ---------------- fused weight fp32->bf16 convert (10 segments, 1 launch) ----------------
__global__ __launch_bounds__(256)
void cvt_all(const float* s0, const float* s1, const float* s2, const float* s3,
             const float* s4, const float* s5, const float* s6, const float* s7,
             const float* s8, const float* s9,
             unsigned short* d0, unsigned short* d1, unsigned short* d2, unsigned short* d3,
             unsigned short* d4, unsigned short* d5, unsigned short* d6, unsigned short* d7,
             unsigned short* d8, unsigned short* d9)
{
    const int bi = blockIdx.x;
    const float* s; unsigned short* d; int base;
    if (bi < 512) {
        const int seg = bi >> 6;
        base = (bi & 63) * 1024;
        switch (seg) {
            case 0: s = s0; d = d0; break;
            case 1: s = s1; d = d1; break;
            case 2: s = s2; d = d2; break;
            case 3: s = s3; d = d3; break;
            case 4: s = s4; d = d4; break;
            case 5: s = s5; d = d5; break;
            case 6: s = s6; d = d6; break;
            default: s = s7; d = d7; break;
        }
    } else {
        const int r = bi - 512;
        base = (r & 511) * 1024;
        if (r >> 9) { s = s9; d = d9; } else { s = s8; d = d8; }
    }
    const int i = base + threadIdx.x * 4;
    float4 v = *(const float4*)(s + i);
    ushort4 ov;
    ov.x = f2bfu(v.x); ov.y = f2bfu(v.y); ov.z = f2bfu(v.z); ov.w = f2bfu(v.w);
    *(ushort4*)(d + i) = ov;
}

// ---------------- fused K + V^T projection, 8 waves, wave-specialized K|V ----------------
// waves 0-3: K = (enc+ep)@Wk^T + bk  -> rows layout
// waves 4-7: V = enc@Wv^T + bv       -> V^T layout
__global__ __launch_bounds__(512, 4)
void proj_kv(const float* __restrict__ enc, const float* __restrict__ ep,
             const __hip_bfloat16* __restrict__ Wk, const float* __restrict__ bk,
             const __hip_bfloat16* __restrict__ Wv, const float* __restrict__ bv,
             __hip_bfloat16* __restrict__ Kout, __hip_bfloat16* __restrict__ Vtout)
{
    __shared__ short Akv[PBM][PLDP];
    __shared__ short Av[PBM][PLDP];
    __shared__ short BkRaw[256 * PLDP];
    __shared__ short BvRaw[256 * PLDP];
    short (*Bk)[PLDP] = (short(*)[PLDP])BkRaw;
    short (*Bv)[PLDP] = (short(*)[PLDP])BvRaw;
    short (*tk)[TLP] = (short(*)[TLP])BkRaw;
    short (*tv)[TLP] = (short(*)[TLP])BvRaw;

    const int tid = threadIdx.x;
    const int m0 = blockIdx.x * PBM;
    const int b = m0 >> 12;
    const int s0 = m0 & (SS - 1);

    // A staging: 1 float4 per stream per thread (64 rows x 32 k)
    const int arr = tid >> 3;           // 0..63
    const int arc = (tid & 7) << 2;     // 0..28
    const long long abase = ((long long)(s0 + arr) * BB + b) * EE + arc;
    // W staging: 32B per matrix per thread (256 rows x 32 k)
    const int wr = tid >> 1;            // 0..255
    const int wc = (tid & 1) << 4;      // 0 or 16
    const long long wbase = (long long)wr * EE + wc;

    const int w = tid >> 6, l = tid & 63;
    const int mat = w >> 2;             // 0 = K, 1 = V
    const int wm0 = (w & 1) * 32;
    const int wn0 = ((w >> 1) & 1) * 128;
    const int lr16 = l & 15, lk8 = (l >> 4) * 8;

    f32x4 acc[2][8] = {};

    // prefetch A slice k0=0
    float4 a0 = *(const float4*)(enc + abase);
    float4 e0 = *(const float4*)(ep + abase);

    for (int k0 = 0; k0 < EE; k0 += PBK) {
        // W slice (L2-resident after first block)
        bf16x8 wk8a = *(const bf16x8*)(Wk + wbase + k0);
        bf16x8 wk8b = *(const bf16x8*)(Wk + wbase + k0 + 8);
        bf16x8 wv8a = *(const bf16x8*)(Wv + wbase + k0);
        bf16x8 wv8b = *(const bf16x8*)(Wv + wbase + k0 + 8);

        bf16x4 pv, pkv;
        pv[0] = (short)f2bfu(a0.x); pv[1] = (short)f2bfu(a0.y);
        pv[2] = (short)f2bfu(a0.z); pv[3] = (short)f2bfu(a0.w);
        pkv[0] = (short)f2bfu(a0.x + e0.x); pkv[1] = (short)f2bfu(a0.y + e0.y);
        pkv[2] = (short)f2bfu(a0.z + e0.z); pkv[3] = (short)f2bfu(a0.w + e0.w);

        __syncthreads();
        *(bf16x4*)&Akv[arr][arc] = pkv;
        *(bf16x4*)&Av[arr][arc]  = pv;
        *(bf16x8*)&Bk[wr][wc]     = wk8a;
        *(bf16x8*)&Bk[wr][wc + 8] = wk8b;
        *(bf16x8*)&Bv[wr][wc]     = wv8a;
        *(bf16x8*)&Bv[wr][wc + 8] = wv8b;
        __syncthreads();

        // prefetch next A slice while MFMAs run
        if (k0 + PBK < EE) {
            a0 = *(const float4*)(enc + abase + k0 + PBK);
            e0 = *(const float4*)(ep + abase + k0 + PBK);
        }

        const short (*Am)[PLDP] = mat ? Av : Akv;
        const short (*Bm)[PLDP] = mat ? Bv : Bk;
        bf16x8 af0 = *(const bf16x8*)&Am[wm0 + lr16][lk8];
        bf16x8 af1 = *(const bf16x8*)&Am[wm0 + 16 + lr16][lk8];
        #pragma unroll
        for (int j = 0; j < 8; ++j) {
            bf16x8 b8 = *(const bf16x8*)&Bm[wn0 + j * 16 + lr16][lk8];
            acc[0][j] = __builtin_amdgcn_mfma_f32_16x16x32_bf16(af0, b8, acc[0][j], 0, 0, 0);
            acc[1][j] = __builtin_amdgcn_mfma_f32_16x16x32_bf16(af1, b8, acc[1][j], 0, 0, 0);
        }
    }

    const float* bias = mat ? bv : bk;
    const int q4 = (l >> 4) * 4;
    #pragma unroll
    for (int h = 0; h < 2; ++h) {
        __syncthreads();
        if (wm0 == h * 32) {
            short (*tile)[TLP] = mat ? tv : tk;
            #pragma unroll
            for (int i = 0; i < 2; ++i) {
                #pragma unroll
                for (int j = 0; j < 8; ++j) {
                    const int n = wn0 + j * 16 + lr16;
                    const float bi = bias[n];
                    #pragma unroll
                    for (int r = 0; r < 4; ++r)
                        tile[i * 16 + q4 + r][n] = (short)f2bfu(acc[i][j][r] + bi);
                }
            }
        }
        __syncthreads();
        // drain K rows: 32 rows x 256 cols, wave w -> rows 4w..4w+3 (64 lanes x 8B)
        #pragma unroll
        for (int it = 0; it < 4; ++it) {
            const int r2 = w * 4 + it;
            ushort4 v = *(const ushort4*)&tk[r2][l * 4];
            *(ushort4*)(Kout + (long long)(m0 + h * 32 + r2) * EE + l * 4) = v;
        }
        // drain V^T: wave w -> n = w*32..+31; per iter 2 n-rows x 32 s (64B per n-row)
        #pragma unroll
        for (int nn = 0; nn < 16; ++nn) {
            const int n = w * 32 + nn * 2 + (l >> 5);
            const int s = l & 31;
            unsigned short v = (unsigned short)tv[s][n];
            *((unsigned short*)Vtout + (long long)(b * EE + n) * SS + s0 + h * 32 + s) = v;
        }
    }
}

// ---------------- small MFMA GEMM: 32m x 128n tile, 128 threads ----------------
template<int A1G, int A2Q, int A1BF, int OBF, int RELU>
__global__ __launch_bounds__(128)
void mfma_gemm2(const void* __restrict__ A1v, const float* __restrict__ A2,
                const __hip_bfloat16* __restrict__ Wb, const float* __restrict__ bias,
                void* __restrict__ outv, int N, int K, float scale)
{
    __shared__ short As[32][PLDP];
    __shared__ short Bs[128][PLDP];
    const int tid = threadIdx.x;
    const int m0 = blockIdx.x * 32;
    const int n0 = blockIdx.y * 128;
    const int rr = tid >> 2;
    const int rc = (tid & 3) << 3;
    const int row = m0 + rr;

    long long a2row = 0;
    if (A1G || A2Q) {
        int bq = row / TQ, tq = row - bq * TQ;
        a2row = ((long long)(tq * BB + bq)) * EE;
    }
    const long long a1row = A1G ? a2row : (long long)row * K;

    const int wv = tid >> 6, l = tid & 63;
    const int wm0 = wv * 16;
    const int lr16 = l & 15, lk8 = (l >> 4) * 8;

    f32x4 acc[8] = {};

    for (int k0 = 0; k0 < K; k0 += PBK) {
        bf16x8 apack;
        if (A1BF) {
            apack = *(const bf16x8*)((const __hip_bfloat16*)A1v + a1row + k0 + rc);
        } else {
            const float* A1 = (const float*)A1v;
            float4 a0 = *(const float4*)(A1 + a1row + k0 + rc);
            float4 a1 = *(const float4*)(A1 + a1row + k0 + rc + 4);
            if (A2Q) {
                float4 e0 = *(const float4*)(A2 + a2row + k0 + rc);
                float4 e1 = *(const float4*)(A2 + a2row + k0 + rc + 4);
                a0.x += e0.x; a0.y += e0.y; a0.z += e0.z; a0.w += e0.w;
                a1.x += e1.x; a1.y += e1.y; a1.z += e1.z; a1.w += e1.w;
            }
            apack[0] = (short)f2bfu(a0.x); apack[1] = (short)f2bfu(a0.y);
            apack[2] = (short)f2bfu(a0.z); apack[3] = (short)f2bfu(a0.w);
            apack[4] = (short)f2bfu(a1.x); apack[5] = (short)f2bfu(a1.y);
            apack[6] = (short)f2bfu(a1.z); apack[7] = (short)f2bfu(a1.w);
        }

        bf16x8 wreg[4];
        #pragma unroll
        for (int it = 0; it < 4; ++it)
            wreg[it] = *(const bf16x8*)(Wb + (long long)(n0 + rr + it * 32) * K + k0 + rc);

        __syncthreads();
        *(bf16x8*)&As[rr][rc] = apack;
        #pragma unroll
        for (int it = 0; it < 4; ++it)
            *(bf16x8*)&Bs[rr + it * 32][rc] = wreg[it];
        __syncthreads();

        bf16x8 af = *(const bf16x8*)&As[wm0 + lr16][lk8];
        #pragma unroll
        for (int j = 0; j < 8; ++j) {
            bf16x8 bfr = *(const bf16x8*)&Bs[j * 16 + lr16][lk8];
            acc[j] = __builtin_amdgcn_mfma_f32_16x16x32_bf16(af, bfr, acc[j], 0, 0, 0);
        }
    }

    const int q4 = (l >> 4) * 4;
    #pragma unroll
    for (int j = 0; j < 8; ++j) {
        const int n = n0 + j * 16 + lr16;
        const float bi = bias[n];
        #pragma unroll
        for (int r = 0; r < 4; ++r) {
            float v = (acc[j][r] + bi) * scale;
            if (RELU) v = fmaxf(v, 0.f);
            const long long oidx = (long long)(m0 + wm0 + q4 + r) * N + n;
            if (OBF) ((__hip_bfloat16*)outv)[oidx] = __float2bfloat16(v);
            else     ((float*)outv)[oidx] = v;
        }
    }
}

// ---------------- fused SA QKV projection ----------------
__global__ __launch_bounds__(128)
void qkv_sa(const float* __restrict__ hs1, const float* __restrict__ qp,
            const __hip_bfloat16* __restrict__ Wq, const float* __restrict__ bq,
            const __hip_bfloat16* __restrict__ Wk, const float* __restrict__ bk,
            const __hip_bfloat16* __restrict__ Wv, const float* __restrict__ bv,
            __hip_bfloat16* __restrict__ Qs, __hip_bfloat16* __restrict__ Ks,
            __hip_bfloat16* __restrict__ Vt, int SVT, float qscale)
{
    __shared__ short Aq[32][PLDP];
    __shared__ short Av[32][PLDP];
    __shared__ short Bq[128][PLDP];
    __shared__ short Bk[128][PLDP];
    __shared__ short Bv[128][PLDP];
    const int tid = threadIdx.x;
    const int m0 = blockIdx.x * 32;
    const int n0 = blockIdx.y * 128;
    const int rr = tid >> 2;
    const int rc = (tid & 3) << 3;
    const int row = m0 + rr;
    const int bq_ = row / TQ, tq = row - bq_ * TQ;
    const long long a1row = (long long)row * EE;
    const long long a2row = ((long long)(tq * BB + bq_)) * EE;

    const int wv = tid >> 6, l = tid & 63;
    const int wm0 = wv * 16;
    const int lr16 = l & 15, lk8 = (l >> 4) * 8;

    f32x4 aq[8] = {}, ak[8] = {}, av[8] = {};

    for (int k0 = 0; k0 < EE; k0 += PBK) {
        float4 a0 = *(const float4*)(hs1 + a1row + k0 + rc);
        float4 a1 = *(const float4*)(hs1 + a1row + k0 + rc + 4);
        float4 e0 = *(const float4*)(qp + a2row + k0 + rc);
        float4 e1 = *(const float4*)(qp + a2row + k0 + rc + 4);
        bf16x8 pq, pv;
        pv[0] = (short)f2bfu(a0.x); pv[1] = (short)f2bfu(a0.y);
        pv[2] = (short)f2bfu(a0.z); pv[3] = (short)f2bfu(a0.w);
        pv[4] = (short)f2bfu(a1.x); pv[5] = (short)f2bfu(a1.y);
        pv[6] = (short)f2bfu(a1.z); pv[7] = (short)f2bfu(a1.w);
        pq[0] = (short)f2bfu(a0.x + e0.x); pq[1] = (short)f2bfu(a0.y + e0.y);
        pq[2] = (short)f2bfu(a0.z + e0.z); pq[3] = (short)f2bfu(a0.w + e0.w);
        pq[4] = (short)f2bfu(a1.x + e1.x); pq[5] = (short)f2bfu(a1.y + e1.y);
        pq[6] = (short)f2bfu(a1.z + e1.z); pq[7] = (short)f2bfu(a1.w + e1.w);

        bf16x8 wq8[4], wk8[4], wv8[4];
        #pragma unroll
        for (int it = 0; it < 4; ++it) {
            const long long wr = (long long)(n0 + rr + it * 32) * EE + k0 + rc;
            wq8[it] = *(const bf16x8*)(Wq + wr);
            wk8[it] = *(const bf16x8*)(Wk + wr);
            wv8[it] = *(const bf16x8*)(Wv + wr);
        }

        __syncthreads();
        *(bf16x8*)&Aq[rr][rc] = pq;
        *(bf16x8*)&Av[rr][rc] = pv;
        #pragma unroll
        for (int it = 0; it < 4; ++it) {
            *(bf16x8*)&Bq[rr + it * 32][rc] = wq8[it];
            *(bf16x8*)&Bk[rr + it * 32][rc] = wk8[it];
            *(bf16x8*)&Bv[rr + it * 32][rc] = wv8[it];
        }
        __syncthreads();

        bf16x8 afq = *(const bf16x8*)&Aq[wm0 + lr16][lk8];
        bf16x8 afv = *(const bf16x8*)&Av[wm0 + lr16][lk8];
        #pragma unroll
        for (int j = 0; j < 8; ++j) {
            bf16x8 b1 = *(const bf16x8*)&Bq[j * 16 + lr16][lk8];
            bf16x8 b2 = *(const bf16x8*)&Bk[j * 16 + lr16][lk8];
            bf16x8 b3 = *(const bf16x8*)&Bv[j * 16 + lr16][lk8];
            aq[j] = __builtin_amdgcn_mfma_f32_16x16x32_bf16(afq, b1, aq[j], 0, 0, 0);
            ak[j] = __builtin_amdgcn_mfma_f32_16x16x32_bf16(afq, b2, ak[j], 0, 0, 0);
            av[j] = __builtin_amdgcn_mfma_f32_16x16x32_bf16(afv, b3, av[j], 0, 0, 0);
        }
    }

    const int q4 = (l >> 4) * 4;
    #pragma unroll
    for (int j = 0; j < 8; ++j) {
        const int n = n0 + j * 16 + lr16;
        const float b1 = bq[n], b2 = bk[n], b3 = bv[n];
        #pragma unroll
        for (int r = 0; r < 4; ++r) {
            const int m = m0 + wm0 + q4 + r;
            Qs[(long long)m * EE + n] = __float2bfloat16((aq[j][r] + b1) * qscale);
            Ks[(long long)m * EE + n] = __float2bfloat16(ak[j][r] + b2);
            const int bb = m / TQ, tt = m - bb * TQ;
            Vt[(long long)(bb * EE + n) * SVT + tt] = __float2bfloat16(av[j][r] + b3);
        }
    }
}

// ---------------- MFMA flash attention: 4 waves, 64 q/block, XCD-chunked swizzle ----------------
#define KVB 32
#define LDP 40

__global__ __launch_bounds__(256, 2)
void flash_mfma(const __hip_bfloat16* __restrict__ Qg,
                const __hip_bfloat16* __restrict__ Kg,
                const __hip_bfloat16* __restrict__ Vtg,
                const float* __restrict__ mask,
                __hip_bfloat16* __restrict__ O,
                int Skv, int SVT)
{
    __shared__ short Ks[2][KVB][LDP];
    __shared__ short Vs[2][KVB][LDP];
    const int tid = threadIdx.x;
    const int l = tid & 63;
    const int g = l >> 4, q16 = l & 15;
    const int chunk = gridDim.x >> 3;
    const int logical = (blockIdx.x & 7) * chunk + (blockIdx.x >> 3);
    const int qb = logical & 1;
    const int bh = logical >> 1;
    const int h = bh & (HH - 1), b = bh >> 3;
    const int q0 = qb * 64 + (tid >> 6) * 16;

    int qc = q0 + q16; if (qc >= TQ) qc = TQ - 1;
    const bf16x8 qfrag = *(const bf16x8*)(Qg + ((long long)(b * TQ + qc)) * EE + h * DHH + g * 8);

    const int srow = tid >> 3;
    const int sseg = (tid & 7) * 4;
    const long long kbase = ((long long)b * Skv) * EE + h * DHH;
    const long long vbase = ((long long)(b * EE + h * DHH)) * SVT;
    const float* mrowp = mask ? mask + ((long long)bh * TQ + qc) * Skv : nullptr;

    f32x4 oacc[2] = {{0.f,0.f,0.f,0.f},{0.f,0.f,0.f,0.f}};
    float mrun = -1e30f, lrun = 0.f;
    const f32x4 zero = {0.f,0.f,0.f,0.f};

    int s_ld = srow; if (s_ld >= Skv) s_ld = Skv - 1;
    bf16x4 kreg = *(const bf16x4*)(Kg + kbase + (long long)s_ld * EE + sseg);
    bf16x4 vreg = *(const bf16x4*)(Vtg + vbase + (long long)srow * SVT + sseg);
    float4 mcur0, mcur1;
    if (mrowp) {
        mcur0 = *(const float4*)(mrowp + g * 4);
        mcur1 = *(const float4*)(mrowp + 16 + g * 4);
    }

    const int nround = (Skv + KVB - 1) / KVB;
    for (int r = 0; r < nround; ++r) {
        const int buf = r & 1;
        *(bf16x4*)&Ks[buf][srow][sseg] = kreg;
        *(bf16x4*)&Vs[buf][srow][sseg] = vreg;
        float4 mnx0, mnx1;
        if (r + 1 < nround) {
            int sn = (r + 1) * KVB + srow; if (sn >= Skv) sn = Skv - 1;
            kreg = *(const bf16x4*)(Kg + kbase + (long long)sn * EE + sseg);
            vreg = *(const bf16x4*)(Vtg + vbase + (long long)srow * SVT + (r + 1) * KVB + sseg);
            if (mrowp) {
                mnx0 = *(const float4*)(mrowp + (r + 1) * KVB + g * 4);
                mnx1 = *(const float4*)(mrowp + (r + 1) * KVB + 16 + g * 4);
            }
        }
        __syncthreads();

        const int s0 = r * KVB;
        f32x4 sT[2];
        #pragma unroll
        for (int t = 0; t < 2; ++t) {
            bf16x8 kf = *(const bf16x8*)&Ks[buf][t * 16 + q16][g * 8];
            sT[t] = __builtin_amdgcn_mfma_f32_16x16x32_bf16(kf, qfrag, zero, 0, 0, 0);
        }
        float sc[8];
        if (mrowp) {
            sc[0] = sT[0][0] + mcur0.x; sc[1] = sT[0][1] + mcur0.y;
            sc[2] = sT[0][2] + mcur0.z; sc[3] = sT[0][3] + mcur0.w;
            sc[4] = sT[1][0] + mcur1.x; sc[5] = sT[1][1] + mcur1.y;
            sc[6] = sT[1][2] + mcur1.z; sc[7] = sT[1][3] + mcur1.w;
        } else {
            #pragma unroll
            for (int t = 0; t < 2; ++t)
                #pragma unroll
                for (int rg = 0; rg < 4; ++rg) {
                    int s = s0 + t * 16 + g * 4 + rg;
                    sc[t*4+rg] = (s < Skv) ? sT[t][rg] : -1e30f;
                }
        }
        float tmax = sc[0];
        #pragma unroll
        for (int i = 1; i < 8; ++i) tmax = fmaxf(tmax, sc[i]);
        tmax = fmaxf(tmax, __shfl_xor(tmax, 16));
        tmax = fmaxf(tmax, __shfl_xor(tmax, 32));
        const float mn = fmaxf(mrun, tmax);
        const float corr = __expf(mrun - mn);
        mrun = mn;
        float ps = 0.f;
        bf16x8 pfrag;
        #pragma unroll
        for (int i = 0; i < 8; ++i) {
            float p = __expf(sc[i] - mn);
            ps += p;
            pfrag[i] = (short)f2bfu(p);
        }
        ps += __shfl_xor(ps, 16);
        ps += __shfl_xor(ps, 32);
        lrun = lrun * corr + ps;
        #pragma unroll
        for (int rg = 0; rg < 4; ++rg) {
            float c = __shfl(corr, g * 4 + rg);
            oacc[0][rg] *= c;
            oacc[1][rg] *= c;
        }
        #pragma unroll
        for (int T = 0; T < 2; ++T) {
            bf16x4 v0 = *(const bf16x4*)&Vs[buf][T * 16 + q16][g * 4];
            bf16x4 v1 = *(const bf16x4*)&Vs[buf][T * 16 + q16][16 + g * 4];
            bf16x8 vf;
            vf[0] = v0[0]; vf[1] = v0[1]; vf[2] = v0[2]; vf[3] = v0[3];
            vf[4] = v1[0]; vf[5] = v1[1]; vf[6] = v1[2]; vf[7] = v1[3];
            oacc[T] = __builtin_amdgcn_mfma_f32_16x16x32_bf16(pfrag, vf, oacc[T], 0, 0, 0);
        }
        mcur0 = mnx0; mcur1 = mnx1;
        __syncthreads();
    }

    float linv[4];
    #pragma unroll
    for (int rg = 0; rg < 4; ++rg)
        linv[rg] = 1.f / __shfl(lrun, g * 4 + rg);
    #pragma unroll
    for (int rg = 0; rg < 4; ++rg) {
        const int q = q0 + g * 4 + rg;
        if (q < TQ) {
            __hip_bfloat16* op = O + ((long long)(b * TQ + q)) * EE + h * DHH + q16;
            op[0]  = __float2bfloat16(oacc[0][rg] * linv[rg]);
            op[16] = __float2bfloat16(oacc[1][rg] * linv[rg]);
        }
    }
}

// ---------------- LayerNorm ----------------
template<int GATHER_RES, int OUT_T, int OUT_BF>
__global__ __launch_bounds__(256)
void ln_kernel(const float* __restrict__ res, const float* __restrict__ x,
               const float* __restrict__ gam, const float* __restrict__ bet,
               float* __restrict__ out, __hip_bfloat16* __restrict__ outb)
{
    __shared__ float r1[4], r2[4];
    const int m = blockIdx.x;
    const int k = threadIdx.x;
    const int b = m / TQ, t = m - b * TQ;
    const long long roff = GATHER_RES ? ((long long)(t * BB + b)) * EE : (long long)m * EE;
    float v = res[roff + k] + x[(long long)m * EE + k];
    float s = v;
    #pragma unroll
    for (int off = 32; off; off >>= 1) s += __shfl_down(s, off);
    if ((k & 63) == 0) r1[k >> 6] = s;
    __syncthreads();
    const float mu = (r1[0] + r1[1] + r1[2] + r1[3]) * (1.0f / EE);
    const float d = v - mu;
    float s2 = d * d;
    #pragma unroll
    for (int off = 32; off; off >>= 1) s2 += __shfl_down(s2, off);
    if ((k & 63) == 0) r2[k >> 6] = s2;
    __syncthreads();
    const float var = (r2[0] + r2[1] + r2[2] + r2[3]) * (1.0f / EE);
    const float o = d * rsqrtf(var + LNEPS) * gam[k] + bet[k];
    const long long ooff = OUT_T ? ((long long)(t * BB + b)) * EE : (long long)m * EE;
    out[ooff + k] = o;
    if (OUT_BF) outb[(long long)m * EE + k] = __float2bfloat16(o);
}

extern "C" void kernel_launch(void* const* d_in, const int* in_sizes, int n_in,
                              void* d_out, int out_size, void* d_ws, size_t ws_size,
                              hipStream_t stream)
{
    const float* hs    = (const float*)d_in[0];
    const float* qp    = (const float*)d_in[1];
    const float* enc   = (const float*)d_in[2];
    const float* ep    = (const float*)d_in[3];
    const float* mask  = (const float*)d_in[4];
    const float* ca_wq = (const float*)d_in[5];  const float* ca_bq = (const float*)d_in[6];
    const float* ca_wk = (const float*)d_in[7];  const float* ca_bk = (const float*)d_in[8];
    const float* ca_wv = (const float*)d_in[9];  const float* ca_bv = (const float*)d_in[10];
    const float* ca_wo = (const float*)d_in[11]; const float* ca_bo = (const float*)d_in[12];
    const float* sa_wq = (const float*)d_in[13]; const float* sa_bq = (const float*)d_in[14];
    const float* sa_wk = (const float*)d_in[15]; const float* sa_bk = (const float*)d_in[16];
    const float* sa_wv = (const float*)d_in[17]; const float* sa_bv = (const float*)d_in[18];
    const float* sa_wo = (const float*)d_in[19]; const float* sa_bo = (const float*)d_in[20];
    const float* ln1_g = (const float*)d_in[21]; const float* ln1_b = (const float*)d_in[22];
    const float* ln2_g = (const float*)d_in[23]; const float* ln2_b = (const float*)d_in[24];
    const float* ln3_g = (const float*)d_in[25]; const float* ln3_b = (const float*)d_in[26];
    const float* fc1_w = (const float*)d_in[27]; const float* fc1_b = (const float*)d_in[28];
    const float* fc2_w = (const float*)d_in[29]; const float* fc2_b = (const float*)d_in[30];

    const int MQ = BB * TQ;   // 3200
    const int MK = BB * SS;   // 131072
    const int SVT2 = 128;

    size_t off = 0;
    char* base = (char*)d_ws;
    auto alloc = [&](size_t bytes) -> void* {
        void* p = base + off; off = (off + bytes + 255) & ~(size_t)255; return p;
    };
    __hip_bfloat16* Kc  = (__hip_bfloat16*)alloc((size_t)MK * EE * 2);
    __hip_bfloat16* Vt  = (__hip_bfloat16*)alloc((size_t)BB * EE * SS * 2);
    __hip_bfloat16* Qc  = (__hip_bfloat16*)alloc((size_t)MQ * EE * 2);
    __hip_bfloat16* Qs  = (__hip_bfloat16*)alloc((size_t)MQ * EE * 2);
    __hip_bfloat16* Ks2 = (__hip_bfloat16*)alloc((size_t)MQ * EE * 2);
    __hip_bfloat16* Vt2 = (__hip_bfloat16*)alloc((size_t)BB * EE * SVT2 * 2);
    __hip_bfloat16* Wq1 = (__hip_bfloat16*)alloc((size_t)EE * EE * 2);
    __hip_bfloat16* Wkb = (__hip_bfloat16*)alloc((size_t)EE * EE * 2);
    __hip_bfloat16* Wvb = (__hip_bfloat16*)alloc((size_t)EE * EE * 2);
    __hip_bfloat16* Wo1 = (__hip_bfloat16*)alloc((size_t)EE * EE * 2);
    __hip_bfloat16* Wq2 = (__hip_bfloat16*)alloc((size_t)EE * EE * 2);
    __hip_bfloat16* Wk2 = (__hip_bfloat16*)alloc((size_t)EE * EE * 2);
    __hip_bfloat16* Wv2 = (__hip_bfloat16*)alloc((size_t)EE * EE * 2);
    __hip_bfloat16* Wo2 = (__hip_bfloat16*)alloc((size_t)EE * EE * 2);
    __hip_bfloat16* Wf1 = (__hip_bfloat16*)alloc((size_t)FF * EE * 2);
    __hip_bfloat16* Wf2 = (__hip_bfloat16*)alloc((size_t)EE * FF * 2);
    __hip_bfloat16* hs2b= (__hip_bfloat16*)alloc((size_t)MQ * EE * 2);
    __hip_bfloat16* h1b = (__hip_bfloat16*)alloc((size_t)MQ * FF * 2);
    __hip_bfloat16* attO  = (__hip_bfloat16*)alloc((size_t)MQ * EE * 2);
    __hip_bfloat16* attO2 = (__hip_bfloat16*)alloc((size_t)MQ * EE * 2);
    float* xproj = (float*)alloc((size_t)MQ * EE * 4);
    float* hs1   = (float*)alloc((size_t)MQ * EE * 4);
    float* xpro2 = (float*)alloc((size_t)MQ * EE * 4);
    float* hs2   = (float*)alloc((size_t)MQ * EE * 4);
    float* xffn  = (float*)alloc((size_t)MQ * EE * 4);

    const float qscale = 0.17677669529663687f;
    dim3 blk(256);

    cvt_all<<<dim3(1536), blk, 0, stream>>>(
        ca_wq, ca_wk, ca_wv, ca_wo, sa_wq, sa_wk, sa_wv, sa_wo, fc1_w, fc2_w,
        (unsigned short*)Wq1, (unsigned short*)Wkb, (unsigned short*)Wvb,
        (unsigned short*)Wo1, (unsigned short*)Wq2, (unsigned short*)Wk2,
        (unsigned short*)Wv2, (unsigned short*)Wo2, (unsigned short*)Wf1,
        (unsigned short*)Wf2);

    // ---- cross-attention ----
    mfma_gemm2<1,1,0,1,0><<<dim3(MQ/32, 2), dim3(128), 0, stream>>>(hs, qp, Wq1, ca_bq, Qc, EE, EE, qscale);
    proj_kv<<<dim3(MK/PBM), dim3(512), 0, stream>>>(enc, ep, Wkb, ca_bk, Wvb, ca_bv, Kc, Vt);
    flash_mfma<<<dim3(BB*HH*2), dim3(256), 0, stream>>>(Qc, Kc, Vt, mask, attO, SS, SS);
    mfma_gemm2<0,0,1,0,0><<<dim3(MQ/32, 2), dim3(128), 0, stream>>>(attO, nullptr, Wo1, ca_bo, xproj, EE, EE, 1.f);
    ln_kernel<1,0,0><<<dim3(MQ), blk, 0, stream>>>(hs, xproj, ln1_g, ln1_b, hs1, nullptr);

    // ---- self-attention ----
    qkv_sa<<<dim3(MQ/32, 2), dim3(128), 0, stream>>>(hs1, qp, Wq2, sa_bq, Wk2, sa_bk, Wv2, sa_bv,
                                                     Qs, Ks2, Vt2, SVT2, qscale);
    flash_mfma<<<dim3(BB*HH*2), dim3(256), 0, stream>>>(Qs, Ks2, Vt2, nullptr, attO2, TQ, SVT2);
    mfma_gemm2<0,0,1,0,0><<<dim3(MQ/32, 2), dim3(128), 0, stream>>>(attO2, nullptr, Wo2, sa_bo, xpro2, EE, EE, 1.f);
    ln_kernel<0,0,1><<<dim3(MQ), blk, 0, stream>>>(hs1, xpro2, ln2_g, ln2_b, hs2, hs2b);

    // ---- FFN ----
    mfma_gemm2<0,0,1,1,1><<<dim3(MQ/32, FF/128), dim3(128), 0, stream>>>(hs2b, nullptr, Wf1, fc1_b, h1b, FF, EE, 1.f);
    mfma_gemm2<0,0,1,0,0><<<dim3(MQ/32, 2), dim3(128), 0, stream>>>(h1b, nullptr, Wf2, fc2_b, xffn, EE, FF, 1.f);
    ln_kernel<0,1,0><<<dim3(MQ), blk, 0, stream>>>(hs2, xffn, ln3_g, ln3_b, (float*)d_out, nullptr);

    (void)in_sizes; (void)n_in; (void)out_size; (void)ws_size;
}